// Round 1
// baseline (116337.256 us; speedup 1.0000x reference)
//
#include <hip/hip_runtime.h>
#include <math.h>
#include <stdint.h>

// Problem constants
#define NBATCH 16
#define NK     32
#define NTDS   768      // 3*DS
#define NMM    676      // BM*BM
#define NBM    26
#define NBB    832      // B = K*BM
#define NOCC2  128
#define NPAIR  496      // K*(K-1)/2
#define FSCALE 1.0e-4f
#define A0C    0.5291772f

// ---------------- workspace layout (in floats) ----------------
#define OFF_ACOPY 0ull
#define SZ_ACOPY  (16ull*832*832)
#define OFF_X     (OFF_ACOPY + SZ_ACOPY)
#define SZ_X      (16ull*32*768)
#define OFF_S     (OFF_X + SZ_X)
#define SZ_S      (16ull*768)
#define OFF_D     (OFF_S + SZ_S)
#define OFF_SUB   (OFF_D   + 16ull*832)
#define OFF_TAU   (OFF_SUB + 16ull*832)
#define OFF_EIG   (OFF_TAU + 16ull*832)
#define OFF_UTRI  (OFF_EIG + 16ull*832)
#define SZ_UTRI   (16ull*128*832)
#define OFF_UOCC  (OFF_UTRI + SZ_UTRI)
#define OFF_C     OFF_UTRI   /* C overlays Utri (dead after backxform) */
// total = 14,942,208 floats = ~59.8 MB

__device__ __forceinline__ void pair_decode(int t, int& k, int& l) {
  int kk = (int)((1.0f + sqrtf(1.0f + 8.0f*(float)t)) * 0.5f);
  while (kk*(kk-1)/2 > t) --kk;
  while ((kk+1)*kk/2 <= t) ++kk;
  k = kk; l = t - kk*(kk-1)/2;
}

// ---------------- x = mu @ transfer_W + b ----------------
__global__ __launch_bounds__(256) void k_x(const float* __restrict__ mu,
                                           const float* __restrict__ tW,
                                           const float* __restrict__ tb,
                                           float* __restrict__ x) {
  const int k = blockIdx.x, n = blockIdx.y, tid = threadIdx.x;
  __shared__ float mus[384];
  const float* mub = mu + (size_t)(n*NK + k)*384;
  for (int i = tid; i < 384; i += 256) mus[i] = mub[i];
  __syncthreads();
  float* xb = x + (size_t)(n*NK + k)*NTDS;
  for (int oo = tid; oo < NTDS; oo += 256) {
    const int d = oo >> 8, i = oo & 255;
    float acc = tb[i];
    const float* mrow = &mus[d*128];
    for (int a = 0; a < 128; ++a) acc += mrow[a]*tW[a*256 + i];
    xb[oo] = acc;
  }
}

// ---------------- S[n][dd] = sum_k x[n][k][dd] ----------------
__global__ __launch_bounds__(256) void k_S(const float* __restrict__ x, float* __restrict__ S) {
  const int n = blockIdx.x, tid = threadIdx.x;
  for (int dd = tid; dd < NTDS; dd += 256) {
    float s = 0.f;
    for (int k = 0; k < NK; ++k) s += x[(size_t)(n*NK + k)*NTDS + dd];
    S[n*NTDS + dd] = s;
  }
}

// ---------------- diagonal blocks ----------------
__global__ __launch_bounds__(256) void k_diag(const float* __restrict__ x, const float* __restrict__ S,
                                              const float* __restrict__ Won, const float* __restrict__ bon,
                                              const float* __restrict__ hnew, const float* __restrict__ Foff,
                                              float* __restrict__ Fout, float* __restrict__ Acopy) {
  const int k = blockIdx.x, n = blockIdx.y, tid = threadIdx.x;
  __shared__ float q[NTDS];
  __shared__ float M[NMM];
  const float* xb = x + (size_t)(n*NK + k)*NTDS;
  const float* Sb = S + n*NTDS;
  for (int i = tid; i < NTDS; i += 256) q[i] = xb[i]*Sb[i];
  __syncthreads();
  for (int m = tid; m < NMM; m += 256) {
    float acc = 32.0f * bon[m];
    for (int dd = 0; dd < NTDS; ++dd) acc += q[dd]*Won[(size_t)dd*NMM + m];
    M[m] = acc;
  }
  __syncthreads();
  const float* hb = hnew + (size_t)n*NBB*NBB;
  float* Fb = Fout + (size_t)n*NBB*NBB;
  float* Ab = Acopy + (size_t)n*NBB*NBB;
  for (int m = tid; m < NMM; m += 256) {
    const int a = m/26, b = m - a*26;
    const float val = 0.5f*(M[m] + M[b*26 + a]);
    const int P = k*26 + a, Q = k*26 + b;
    const size_t idx = (size_t)P*NBB + Q;
    const float fo = Foff[idx];
    const float hv = hb[idx];
    const float Fv = (fabsf(hv) > 1e-7f) ? (val*FSCALE + fo) : fo;
    Fb[idx] = Fv; Ab[idx] = Fv;
  }
}

// ---------------- off-diagonal blocks: GEMM over pairs ----------------
__global__ __launch_bounds__(256) void k_off(const float* __restrict__ x,
                                             const float* __restrict__ Woff, const float* __restrict__ boff,
                                             const float* __restrict__ hnew, const float* __restrict__ Foff,
                                             float* __restrict__ Fout, float* __restrict__ Acopy) {
  const int ct = blockIdx.x, pt = blockIdx.y, n = blockIdx.z;
  const int tid = threadIdx.x;
  __shared__ __align__(16) float At[32*65];
  __shared__ __align__(16) float Bt[64*128];
  __shared__ int klk[32], kll[32];
  if (tid < 32) {
    int pr = pt*32 + tid, kk = 1, ll = 0;
    if (pr < NPAIR) pair_decode(pr, kk, ll);
    klk[tid] = kk; kll[tid] = ll;
  }
  __syncthreads();
  const int ty = tid >> 5, tx = tid & 31;
  const int r0 = ty*4, c0 = tx*4;
  float acc[4][4] = {};
  for (int dd0 = 0; dd0 < NTDS; dd0 += 64) {
    for (int idx = tid; idx < 2048; idx += 256) {
      const int r = idx >> 6, c = idx & 63;
      const int pr = pt*32 + r;
      float v = 0.f;
      if (pr < NPAIR) {
        const int kk = klk[r], ll = kll[r];
        v = x[(size_t)(n*NK + kk)*NTDS + dd0 + c] * x[(size_t)(n*NK + ll)*NTDS + dd0 + c];
      }
      At[r*65 + c] = v;
    }
    for (int idx = tid; idx < 8192; idx += 256) {
      const int r = idx >> 7, c = idx & 127;
      const int col = ct*128 + c;
      Bt[idx] = (col < NMM) ? Woff[(size_t)(dd0 + r)*NMM + col] : 0.f;
    }
    __syncthreads();
    for (int kk = 0; kk < 64; ++kk) {
      float av[4];
      av[0] = At[(r0+0)*65 + kk];
      av[1] = At[(r0+1)*65 + kk];
      av[2] = At[(r0+2)*65 + kk];
      av[3] = At[(r0+3)*65 + kk];
      const float4 b4 = *(const float4*)&Bt[kk*128 + c0];
      const float bb[4] = {b4.x, b4.y, b4.z, b4.w};
      #pragma unroll
      for (int qq = 0; qq < 4; ++qq)
        #pragma unroll
        for (int pp = 0; pp < 4; ++pp)
          acc[qq][pp] += av[qq]*bb[pp];
    }
    __syncthreads();
  }
  const float* hb = hnew + (size_t)n*NBB*NBB;
  float* Fb = Fout + (size_t)n*NBB*NBB;
  float* Ab = Acopy + (size_t)n*NBB*NBB;
  for (int qq = 0; qq < 4; ++qq) {
    const int pr = pt*32 + r0 + qq;
    if (pr >= NPAIR) continue;
    const int kk = klk[r0+qq], ll = kll[r0+qq];
    for (int pp = 0; pp < 4; ++pp) {
      const int m = ct*128 + c0 + pp;
      if (m >= NMM) continue;
      const float val = acc[qq][pp] + boff[m];
      const int a = m/26, b = m - a*26;
      const int P = kk*26 + a, Q = ll*26 + b;
      const size_t i1 = (size_t)P*NBB + Q;
      const float fo1 = Foff[i1], hv1 = hb[i1];
      const float Fv1 = (fabsf(hv1) > 1e-7f) ? (val*FSCALE + fo1) : fo1;
      Fb[i1] = Fv1; Ab[i1] = Fv1;
      const size_t i2 = (size_t)Q*NBB + P;
      const float fo2 = Foff[i2], hv2 = hb[i2];
      const float Fv2 = (fabsf(hv2) > 1e-7f) ? (val*FSCALE + fo2) : fo2;
      Fb[i2] = Fv2; Ab[i2] = Fv2;
    }
  }
}

// ---------------- Householder tridiagonalization (one WG per matrix) ----------------
__global__ __launch_bounds__(1024) void k_tridiag(float* __restrict__ Acopy, float* __restrict__ dA,
                                                  float* __restrict__ subA, float* __restrict__ tauA) {
  const int n = blockIdx.x;
  float* A = Acopy + (size_t)n*NBB*NBB;
  __shared__ float v[NBB];
  __shared__ float w[NBB];
  __shared__ float red[16];
  __shared__ float s_tau, s_scale, s_dot;
  const int tid = threadIdx.x;
  const int lane = tid & 63;
  const int wv = tid >> 6;

  for (int k = 0; k < NBB-2; ++k) {
    const int m = NBB-1-k;
    // phase 1: ||A[k+2.., k]||^2
    float part = 0.f;
    for (int i = k+2+tid; i < NBB; i += 1024) {
      const float a = A[(size_t)i*NBB + k];
      part += a*a;
    }
    #pragma unroll
    for (int off = 32; off > 0; off >>= 1) part += __shfl_down(part, off);
    if (lane == 0) red[wv] = part;
    __syncthreads();
    if (tid == 0) {
      float xn2 = 0.f;
      #pragma unroll
      for (int t = 0; t < 16; ++t) xn2 += red[t];
      const float alpha = A[(size_t)(k+1)*NBB + k];
      float tau, scale, beta;
      if (xn2 < 1e-26f) {
        beta = alpha; tau = 0.f; scale = 0.f;
      } else {
        beta  = -copysignf(sqrtf(alpha*alpha + xn2), alpha);
        tau   = (beta - alpha) / beta;
        scale = 1.0f / (alpha - beta);
      }
      s_tau = tau; s_scale = scale;
      subA[n*NBB + k + 1] = beta;
      tauA[n*NBB + k] = tau;
    }
    __syncthreads();
    const float tau = s_tau;
    const float scale = s_scale;
    // phase 2: build v, store into column k
    for (int i = k+1+tid; i < NBB; i += 1024) {
      const float val = (i == k+1) ? 1.0f : A[(size_t)i*NBB + k]*scale;
      v[i-(k+1)] = val;
      A[(size_t)i*NBB + k] = val;
    }
    __syncthreads();
    if (tau != 0.f) {
      // phase 3: w_raw = A_trail * v
      for (int r = k+1+wv; r < NBB; r += 16) {
        const float* Ar = A + (size_t)r*NBB;
        float acc = 0.f;
        for (int c = k+1+lane; c < NBB; c += 64) acc += Ar[c]*v[c-(k+1)];
        #pragma unroll
        for (int off = 32; off > 0; off >>= 1) acc += __shfl_down(acc, off);
        if (lane == 0) w[r-(k+1)] = acc;
      }
      __syncthreads();
      // phase 4: dot = v^T (A v)
      part = 0.f;
      for (int i = tid; i < m; i += 1024) part += v[i]*w[i];
      #pragma unroll
      for (int off = 32; off > 0; off >>= 1) part += __shfl_down(part, off);
      if (lane == 0) red[wv] = part;
      __syncthreads();
      if (tid == 0) {
        float dt = 0.f;
        #pragma unroll
        for (int t = 0; t < 16; ++t) dt += red[t];
        s_dot = dt;
      }
      __syncthreads();
      const float kc = 0.5f*tau*tau*s_dot;
      for (int i = tid; i < m; i += 1024) w[i] = tau*w[i] - kc*v[i];
      __syncthreads();
      // phase 5: A_trail -= v w^T + w v^T
      for (int r = k+1+wv; r < NBB; r += 16) {
        const float vr = v[r-(k+1)];
        const float wr = w[r-(k+1)];
        float* Ar = A + (size_t)r*NBB;
        for (int c = k+1+lane; c < NBB; c += 64) {
          const int ci = c-(k+1);
          Ar[c] -= vr*w[ci] + wr*v[ci];
        }
      }
      __syncthreads();
    }
  }
  for (int i = tid; i < NBB; i += 1024) dA[n*NBB + i] = A[(size_t)i*NBB + i];
  if (tid == 0) {
    subA[n*NBB + NBB-1] = A[(size_t)(NBB-1)*NBB + NBB-2];
    subA[n*NBB + 0] = 0.f;
    tauA[n*NBB + NBB-2] = 0.f;
    tauA[n*NBB + NBB-1] = 0.f;
  }
}

// ---------------- all eigenvalues via bisection (Sturm counts) ----------------
__global__ __launch_bounds__(256) void k_bisect(const float* __restrict__ dA, const float* __restrict__ subA,
                                                float* __restrict__ eig, float* __restrict__ e_out) {
  const int n = blockIdx.y;
  const int i = blockIdx.x*256 + threadIdx.x;
  __shared__ float ds[NBB], ss[NBB];
  const float* dg = dA + n*NBB;
  const float* sg = subA + n*NBB;
  for (int j = threadIdx.x; j < NBB; j += 256) { ds[j] = dg[j]; ss[j] = sg[j]; }
  __syncthreads();
  if (i >= NBB) return;
  float lo = 1e30f, hi = -1e30f;
  for (int j = 0; j < NBB; ++j) {
    const float r = fabsf(ss[j]) + ((j+1 < NBB) ? fabsf(ss[j+1]) : 0.f);
    lo = fminf(lo, ds[j]-r); hi = fmaxf(hi, ds[j]+r);
  }
  const float pad = 1e-3f*(hi-lo) + 1e-3f;
  lo -= pad; hi += pad;
  for (int it = 0; it < 38; ++it) {
    const float mid = 0.5f*(lo+hi);
    int cnt = 0;
    float qv = ds[0]-mid;
    if (qv < 0.f) cnt++;
    for (int j = 1; j < NBB; ++j) {
      const float e = ss[j];
      if (fabsf(qv) < 1e-20f) qv = -1e-20f;
      qv = ds[j]-mid - e*e/qv;
      if (qv < 0.f) cnt++;
    }
    if (cnt > i) hi = mid; else lo = mid;
  }
  const float lam = 0.5f*(lo+hi);
  eig[n*NBB + i] = lam;
  e_out[n*NBB + i] = lam;
}

// ---------------- inverse iteration on T for the 128 lowest ----------------
__global__ __launch_bounds__(64) void k_invit(const float* __restrict__ dA, const float* __restrict__ subA,
                                              const float* __restrict__ eig, float* __restrict__ Utri) {
  const int i = blockIdx.x, n = blockIdx.y;
  const int lane = threadIdx.x;
  __shared__ float ds[NBB], ss[NBB], ud[NBB], u1[NBB], u2[NBB], yv[NBB], xv[NBB];
  const float* dg = dA + n*NBB;
  const float* sg = subA + n*NBB;
  for (int j = lane; j < NBB; j += 64) { ds[j] = dg[j]; ss[j] = sg[j]; }
  const float lam = eig[n*NBB + i];
  for (int j = lane; j < NBB; j += 64) {
    uint32_t s = (uint32_t)(j*2654435761u) ^ (uint32_t)(i*40503u + 977u) ^ (uint32_t)(n*9973u);
    s ^= s >> 16; s *= 0x7feb352dU; s ^= s >> 15; s *= 0x846ca68bU; s ^= s >> 16;
    yv[j] = 0.5f + (float)(s & 0xFFFF) * (1.0f/65536.0f);
  }
  __syncthreads();
  const float PIV = 3e-6f;
  for (int pass = 0; pass < 2; ++pass) {
    if (lane == 0) {
      // pivoted LU elimination of (T - lam I), rhs carried in-place in yv
      float cd = ds[0] - lam;
      float cu = ss[1];
      float cy = yv[0];
      for (int j = 0; j < NBB-1; ++j) {
        const float bl = ss[j+1];
        const float bd = ds[j+1] - lam;
        const float bu = (j+2 < NBB) ? ss[j+2] : 0.f;
        const float yb = yv[j+1];
        float tud, tu1, tu2, tm, ncd, ncu, ny;
        if (fabsf(bl) > fabsf(cd)) {        // swap rows
          tud = bl; tu1 = bd; tu2 = bu;
          if (fabsf(tud) < PIV) tud = (tud < 0.f) ? -PIV : PIV;
          tm  = cd / tud;
          ncd = cu - tm*bd;
          ncu = -tm*bu;
          ny  = cy - tm*yb;
          yv[j] = yb;
        } else {
          tud = cd; tu1 = cu; tu2 = 0.f;
          if (fabsf(tud) < PIV) tud = (tud < 0.f) ? -PIV : PIV;
          tm  = bl / tud;
          ncd = bd - tm*cu;
          ncu = bu;
          ny  = yb - tm*cy;
          yv[j] = cy;
        }
        ud[j] = tud; u1[j] = tu1; u2[j] = tu2;
        cd = ncd; cu = ncu; cy = ny;
      }
      if (fabsf(cd) < PIV) cd = (cd < 0.f) ? -PIV : PIV;
      ud[NBB-1] = cd; u1[NBB-1] = 0.f; u2[NBB-1] = 0.f; yv[NBB-1] = cy;
      // back substitution
      float x2 = yv[NBB-1]/ud[NBB-1];
      xv[NBB-1] = x2;
      float x1 = (yv[NBB-2] - u1[NBB-2]*x2)/ud[NBB-2];
      xv[NBB-2] = x1;
      for (int j = NBB-3; j >= 0; --j) {
        const float xj = (yv[j] - u1[j]*x1 - u2[j]*x2)/ud[j];
        xv[j] = xj;
        x2 = x1; x1 = xj;
      }
    }
    __syncthreads();
    float p2 = 0.f;
    for (int j = lane; j < NBB; j += 64) { const float t = xv[j]; p2 += t*t; }
    #pragma unroll
    for (int off = 32; off > 0; off >>= 1) p2 += __shfl_xor(p2, off);
    const float rin = rsqrtf(p2);
    if (pass == 0) {
      for (int j = lane; j < NBB; j += 64) yv[j] = xv[j]*rin;
      __syncthreads();
    } else {
      float* Ub = Utri + ((size_t)n*NOCC2 + i)*NBB;
      for (int j = lane; j < NBB; j += 64) Ub[j] = xv[j]*rin;
    }
  }
}

// ---------------- back-transform: Uocc = H0...H829 * Utri (U register-resident) ----------------
#define RPT 208
__global__ __launch_bounds__(512, 2) void k_backxform(const float* __restrict__ Acopy,
                                                      const float* __restrict__ tauA,
                                                      const float* __restrict__ Utri,
                                                      float* __restrict__ Uocc) {
  const int n = blockIdx.x;
  const int tid = threadIdx.x;
  const int j = tid & 127, g = tid >> 7;    // 4 row-groups x 208 rows
  __shared__ float vlds[NBB];
  __shared__ float sred[4*128];
  const float* A = Acopy + (size_t)n*NBB*NBB;
  float U[RPT];
  const float* Ut = Utri + ((size_t)n*NOCC2 + j)*NBB + g*RPT;
  #pragma unroll
  for (int rr = 0; rr < RPT; ++rr) U[rr] = Ut[rr];
  const int rbase = g*RPT;
  for (int k = NBB-3; k >= 0; --k) {
    const float tau = tauA[n*NBB + k];
    if (tau == 0.f) continue;
    const int m = NBB-1-k;
    for (int idx = tid; idx < m; idx += 512) vlds[idx] = A[(size_t)(k+1+idx)*NBB + k];
    __syncthreads();
    float part = 0.f;
    #pragma unroll
    for (int rr = 0; rr < RPT; ++rr) {
      const int r = rbase + rr;
      if (r > k) part += U[rr]*vlds[r-k-1];
    }
    sred[g*128 + j] = part;
    __syncthreads();
    const float s = tau*(sred[j] + sred[128+j] + sred[256+j] + sred[384+j]);
    #pragma unroll
    for (int rr = 0; rr < RPT; ++rr) {
      const int r = rbase + rr;
      if (r > k) U[rr] -= s*vlds[r-k-1];
    }
    __syncthreads();
  }
  float* Ub = Uocc + (size_t)n*NBB*NOCC2;
  #pragma unroll
  for (int rr = 0; rr < RPT; ++rr) Ub[(size_t)(rbase+rr)*NOCC2 + j] = U[rr];
}

// ---------------- C = h_new * Uocc  (832x832 @ 832x128 per batch) ----------------
__global__ __launch_bounds__(256) void k_gemmC(const float* __restrict__ h,
                                               const float* __restrict__ Uocc,
                                               float* __restrict__ C) {
  const int rt = blockIdx.x, n = blockIdx.y;
  const int tid = threadIdx.x;
  __shared__ __align__(16) float hT[64*33];
  __shared__ __align__(16) float Ut[32*128];
  const int ty = tid >> 5, tx = tid & 31;
  float acc[8][4] = {};
  const float* hb = h + (size_t)n*NBB*NBB + (size_t)rt*64*NBB;
  const float* Ub = Uocc + (size_t)n*NBB*NOCC2;
  for (int k0 = 0; k0 < NBB; k0 += 32) {
    for (int idx = tid; idx < 64*32; idx += 256) {
      const int r = idx >> 5, c = idx & 31;
      hT[r*33 + c] = hb[(size_t)r*NBB + k0 + c];
    }
    for (int idx = tid; idx < 32*128; idx += 256) {
      const int r = idx >> 7, c = idx & 127;
      Ut[idx] = Ub[(size_t)(k0 + r)*NOCC2 + c];
    }
    __syncthreads();
    for (int kk = 0; kk < 32; ++kk) {
      const float4 b4 = *(const float4*)&Ut[kk*128 + tx*4];
      #pragma unroll
      for (int q = 0; q < 8; ++q) {
        const float a = hT[(ty*8 + q)*33 + kk];
        acc[q][0] += a*b4.x; acc[q][1] += a*b4.y; acc[q][2] += a*b4.z; acc[q][3] += a*b4.w;
      }
    }
    __syncthreads();
  }
  float* Cb = C + (size_t)n*NBB*NOCC2;
  #pragma unroll
  for (int q = 0; q < 8; ++q)
    #pragma unroll
    for (int p = 0; p < 4; ++p)
      Cb[(size_t)(rt*64 + ty*8 + q)*NOCC2 + tx*4 + p] = acc[q][p];
}

// ---------------- E = sum(e_occ) + Tr(Uocc^T h Uocc) + nuc ----------------
__global__ __launch_bounds__(256) void k_final(const float* __restrict__ eig,
                                               const float* __restrict__ Uocc, const float* __restrict__ C,
                                               const float* __restrict__ pos, const int* __restrict__ numbers,
                                               float* __restrict__ E_out) {
  const int n = blockIdx.x, tid = threadIdx.x;
  __shared__ float rb[256];
  float local = 0.f;
  for (int i = tid; i < NOCC2; i += 256) local += eig[n*NBB + i];
  const float* Ub = Uocc + (size_t)n*NBB*NOCC2;
  const float* Cb = C + (size_t)n*NBB*NOCC2;
  for (int idx = tid; idx < NBB*NOCC2; idx += 256) local += Ub[idx]*Cb[idx];
  float ln = 0.f;
  for (int t = tid; t < NPAIR; t += 256) {
    int kk, ll;
    pair_decode(t, kk, ll);
    const float dx = pos[(n*NK + kk)*3 + 0] - pos[(n*NK + ll)*3 + 0];
    const float dy = pos[(n*NK + kk)*3 + 1] - pos[(n*NK + ll)*3 + 1];
    const float dz = pos[(n*NK + kk)*3 + 2] - pos[(n*NK + ll)*3 + 2];
    const float d2 = dx*dx + dy*dy + dz*dz;
    const float Z = (float)(numbers[kk]*numbers[ll]);
    ln += Z / sqrtf(d2);
  }
  local += ln * A0C;
  rb[tid] = local;
  __syncthreads();
  for (int s = 128; s > 0; s >>= 1) {
    if (tid < s) rb[tid] += rb[tid + s];
    __syncthreads();
  }
  if (tid == 0) E_out[n] = rb[0];
}

extern "C" void kernel_launch(void* const* d_in, const int* in_sizes, int n_in,
                              void* d_out, int out_size, void* d_ws, size_t ws_size,
                              hipStream_t stream) {
  (void)in_sizes; (void)n_in; (void)out_size; (void)ws_size;
  const float* mu      = (const float*)d_in[0];
  const float* hnew    = (const float*)d_in[1];
  const float* pos     = (const float*)d_in[2];
  const float* Foff    = (const float*)d_in[3];
  const float* tW      = (const float*)d_in[4];
  const float* tb      = (const float*)d_in[5];
  const float* Won     = (const float*)d_in[6];
  const float* bon     = (const float*)d_in[7];
  const float* Woff    = (const float*)d_in[8];
  const float* boff    = (const float*)d_in[9];
  const int*   numbers = (const int*)d_in[10];

  float* out   = (float*)d_out;
  float* Fout  = out;                               // [16][832][832]
  float* e_out = out + (size_t)NBATCH*NBB*NBB;      // [16][832]
  float* E_out = e_out + (size_t)NBATCH*NBB;        // [16]

  float* ws    = (float*)d_ws;
  float* Acopy = ws + OFF_ACOPY;
  float* xbuf  = ws + OFF_X;
  float* Sbuf  = ws + OFF_S;
  float* dA    = ws + OFF_D;
  float* subA  = ws + OFF_SUB;
  float* tauA  = ws + OFF_TAU;
  float* eig   = ws + OFF_EIG;
  float* Utri  = ws + OFF_UTRI;
  float* Uocc  = ws + OFF_UOCC;
  float* Cbuf  = ws + OFF_C;    // overlays Utri

  k_x<<<dim3(NK, NBATCH), dim3(256), 0, stream>>>(mu, tW, tb, xbuf);
  k_S<<<dim3(NBATCH), dim3(256), 0, stream>>>(xbuf, Sbuf);
  k_diag<<<dim3(NK, NBATCH), dim3(256), 0, stream>>>(xbuf, Sbuf, Won, bon, hnew, Foff, Fout, Acopy);
  k_off<<<dim3(6, 16, NBATCH), dim3(256), 0, stream>>>(xbuf, Woff, boff, hnew, Foff, Fout, Acopy);
  k_tridiag<<<dim3(NBATCH), dim3(1024), 0, stream>>>(Acopy, dA, subA, tauA);
  k_bisect<<<dim3(4, NBATCH), dim3(256), 0, stream>>>(dA, subA, eig, e_out);
  k_invit<<<dim3(NOCC2, NBATCH), dim3(64), 0, stream>>>(dA, subA, eig, Utri);
  k_backxform<<<dim3(NBATCH), dim3(512), 0, stream>>>(Acopy, tauA, Utri, Uocc);
  k_gemmC<<<dim3(13, NBATCH), dim3(256), 0, stream>>>(hnew, Uocc, Cbuf);
  k_final<<<dim3(NBATCH), dim3(256), 0, stream>>>(eig, Uocc, Cbuf, pos, numbers, E_out);
}

// Round 2
// 100832.410 us; speedup vs baseline: 1.1538x; 1.1538x over previous
//
#include <hip/hip_runtime.h>
#include <math.h>
#include <stdint.h>

// Problem constants
#define NBATCH 16
#define NK     32
#define NTDS   768      // 3*DS
#define NMM    676      // BM*BM
#define NBM    26
#define NBB    832      // B = K*BM
#define NOCC2  128
#define NPAIR  496      // K*(K-1)/2
#define FSCALE 1.0e-4f
#define A0C    0.5291772f

// ---------------- workspace layout (in floats) ----------------
#define OFF_ACOPY 0ull
#define SZ_ACOPY  (16ull*832*832)
#define OFF_X     (OFF_ACOPY + SZ_ACOPY)
#define SZ_X      (16ull*32*768)
#define OFF_S     (OFF_X + SZ_X)
#define SZ_S      (16ull*768)
#define OFF_D     (OFF_S + SZ_S)
#define OFF_SUB   (OFF_D   + 16ull*832)
#define OFF_TAU   (OFF_SUB + 16ull*832)
#define OFF_EIG   (OFF_TAU + 16ull*832)
#define OFF_UTRI  (OFF_EIG + 16ull*832)
#define SZ_UTRI   (16ull*128*832)
#define OFF_UOCC  (OFF_UTRI + SZ_UTRI)
#define OFF_C     OFF_UTRI   /* C overlays Utri (dead after backxform) */
// tridiag scratch overlays the Utri region (Utri written only later by k_invit)
#define OFF_WBUF  OFF_UTRI                  /* 16*832 floats  */
#define OFF_REDW  (OFF_UTRI + 16ull*832)    /* 16*32 floats   */
#define OFF_BAR   (OFF_REDW + 16ull*32)     /* 16 ints        */

#define GW  16   // workgroups per matrix
#define TPW 256  // threads per workgroup

__device__ __forceinline__ void pair_decode(int t, int& k, int& l) {
  int kk = (int)((1.0f + sqrtf(1.0f + 8.0f*(float)t)) * 0.5f);
  while (kk*(kk-1)/2 > t) --kk;
  while ((kk+1)*kk/2 <= t) ++kk;
  k = kk; l = t - kk*(kk-1)/2;
}

// ---------------- x = mu @ transfer_W + b ----------------
__global__ __launch_bounds__(256) void k_x(const float* __restrict__ mu,
                                           const float* __restrict__ tW,
                                           const float* __restrict__ tb,
                                           float* __restrict__ x) {
  const int k = blockIdx.x, n = blockIdx.y, tid = threadIdx.x;
  __shared__ float mus[384];
  const float* mub = mu + (size_t)(n*NK + k)*384;
  for (int i = tid; i < 384; i += 256) mus[i] = mub[i];
  __syncthreads();
  float* xb = x + (size_t)(n*NK + k)*NTDS;
  for (int oo = tid; oo < NTDS; oo += 256) {
    const int d = oo >> 8, i = oo & 255;
    float acc = tb[i];
    const float* mrow = &mus[d*128];
    for (int a = 0; a < 128; ++a) acc += mrow[a]*tW[a*256 + i];
    xb[oo] = acc;
  }
}

// ---------------- S[n][dd] = sum_k x[n][k][dd] ----------------
__global__ __launch_bounds__(256) void k_S(const float* __restrict__ x, float* __restrict__ S) {
  const int n = blockIdx.x, tid = threadIdx.x;
  for (int dd = tid; dd < NTDS; dd += 256) {
    float s = 0.f;
    for (int k = 0; k < NK; ++k) s += x[(size_t)(n*NK + k)*NTDS + dd];
    S[n*NTDS + dd] = s;
  }
}

// ---------------- diagonal blocks ----------------
__global__ __launch_bounds__(256) void k_diag(const float* __restrict__ x, const float* __restrict__ S,
                                              const float* __restrict__ Won, const float* __restrict__ bon,
                                              const float* __restrict__ hnew, const float* __restrict__ Foff,
                                              float* __restrict__ Fout, float* __restrict__ Acopy) {
  const int k = blockIdx.x, n = blockIdx.y, tid = threadIdx.x;
  __shared__ float q[NTDS];
  __shared__ float M[NMM];
  const float* xb = x + (size_t)(n*NK + k)*NTDS;
  const float* Sb = S + n*NTDS;
  for (int i = tid; i < NTDS; i += 256) q[i] = xb[i]*Sb[i];
  __syncthreads();
  for (int m = tid; m < NMM; m += 256) {
    float acc = 32.0f * bon[m];
    for (int dd = 0; dd < NTDS; ++dd) acc += q[dd]*Won[(size_t)dd*NMM + m];
    M[m] = acc;
  }
  __syncthreads();
  const float* hb = hnew + (size_t)n*NBB*NBB;
  float* Fb = Fout + (size_t)n*NBB*NBB;
  float* Ab = Acopy + (size_t)n*NBB*NBB;
  for (int m = tid; m < NMM; m += 256) {
    const int a = m/26, b = m - a*26;
    const float val = 0.5f*(M[m] + M[b*26 + a]);
    const int P = k*26 + a, Q = k*26 + b;
    const size_t idx = (size_t)P*NBB + Q;
    const float fo = Foff[idx];
    const float hv = hb[idx];
    const float Fv = (fabsf(hv) > 1e-7f) ? (val*FSCALE + fo) : fo;
    Fb[idx] = Fv; Ab[idx] = Fv;
  }
}

// ---------------- off-diagonal blocks: GEMM over pairs ----------------
__global__ __launch_bounds__(256) void k_off(const float* __restrict__ x,
                                             const float* __restrict__ Woff, const float* __restrict__ boff,
                                             const float* __restrict__ hnew, const float* __restrict__ Foff,
                                             float* __restrict__ Fout, float* __restrict__ Acopy) {
  const int ct = blockIdx.x, pt = blockIdx.y, n = blockIdx.z;
  const int tid = threadIdx.x;
  __shared__ __align__(16) float At[32*65];
  __shared__ __align__(16) float Bt[64*128];
  __shared__ int klk[32], kll[32];
  if (tid < 32) {
    int pr = pt*32 + tid, kk = 1, ll = 0;
    if (pr < NPAIR) pair_decode(pr, kk, ll);
    klk[tid] = kk; kll[tid] = ll;
  }
  __syncthreads();
  const int ty = tid >> 5, tx = tid & 31;
  const int r0 = ty*4, c0 = tx*4;
  float acc[4][4] = {};
  for (int dd0 = 0; dd0 < NTDS; dd0 += 64) {
    for (int idx = tid; idx < 2048; idx += 256) {
      const int r = idx >> 6, c = idx & 63;
      const int pr = pt*32 + r;
      float v = 0.f;
      if (pr < NPAIR) {
        const int kk = klk[r], ll = kll[r];
        v = x[(size_t)(n*NK + kk)*NTDS + dd0 + c] * x[(size_t)(n*NK + ll)*NTDS + dd0 + c];
      }
      At[r*65 + c] = v;
    }
    for (int idx = tid; idx < 8192; idx += 256) {
      const int r = idx >> 7, c = idx & 127;
      const int col = ct*128 + c;
      Bt[idx] = (col < NMM) ? Woff[(size_t)(dd0 + r)*NMM + col] : 0.f;
    }
    __syncthreads();
    for (int kk = 0; kk < 64; ++kk) {
      float av[4];
      av[0] = At[(r0+0)*65 + kk];
      av[1] = At[(r0+1)*65 + kk];
      av[2] = At[(r0+2)*65 + kk];
      av[3] = At[(r0+3)*65 + kk];
      const float4 b4 = *(const float4*)&Bt[kk*128 + c0];
      const float bb[4] = {b4.x, b4.y, b4.z, b4.w};
      #pragma unroll
      for (int qq = 0; qq < 4; ++qq)
        #pragma unroll
        for (int pp = 0; pp < 4; ++pp)
          acc[qq][pp] += av[qq]*bb[pp];
    }
    __syncthreads();
  }
  const float* hb = hnew + (size_t)n*NBB*NBB;
  float* Fb = Fout + (size_t)n*NBB*NBB;
  float* Ab = Acopy + (size_t)n*NBB*NBB;
  for (int qq = 0; qq < 4; ++qq) {
    const int pr = pt*32 + r0 + qq;
    if (pr >= NPAIR) continue;
    const int kk = klk[r0+qq], ll = kll[r0+qq];
    for (int pp = 0; pp < 4; ++pp) {
      const int m = ct*128 + c0 + pp;
      if (m >= NMM) continue;
      const float val = acc[qq][pp] + boff[m];
      const int a = m/26, b = m - a*26;
      const int P = kk*26 + a, Q = ll*26 + b;
      const size_t i1 = (size_t)P*NBB + Q;
      const float fo1 = Foff[i1], hv1 = hb[i1];
      const float Fv1 = (fabsf(hv1) > 1e-7f) ? (val*FSCALE + fo1) : fo1;
      Fb[i1] = Fv1; Ab[i1] = Fv1;
      const size_t i2 = (size_t)Q*NBB + P;
      const float fo2 = Foff[i2], hv2 = hb[i2];
      const float Fv2 = (fabsf(hv2) > 1e-7f) ? (val*FSCALE + fo2) : fo2;
      Fb[i2] = Fv2; Ab[i2] = Fv2;
    }
  }
}

// ---------------- multi-WG cooperative Householder tridiagonalization ----------------
// 16 WGs per matrix, interleaved row ownership (row r -> WG r%16).
// 2 device-scope barriers per step; deterministic cross-WG reductions via
// 16 partial slots summed in fixed order.
__device__ __forceinline__ void gbar(int* cnt, int target) {
  __syncthreads();                 // all threads' stores drained (compiler emits vmcnt(0) before s_barrier)
  if (threadIdx.x == 0) {
    __threadfence();               // release: L2 writeback to coherence point
    atomicAdd(cnt, 1);             // device-scope
    while (__hip_atomic_load(cnt, __ATOMIC_RELAXED, __HIP_MEMORY_SCOPE_AGENT) < target)
      __builtin_amdgcn_s_sleep(1);
    __threadfence();               // acquire: invalidate L1/L2 stale lines
  }
  __syncthreads();
}

__device__ __forceinline__ float wg_reduce(float v, float* sred) {
  #pragma unroll
  for (int off = 32; off > 0; off >>= 1) v += __shfl_down(v, off);
  const int tid = threadIdx.x;
  if ((tid & 63) == 0) sred[tid >> 6] = v;
  __syncthreads();
  const float r = sred[0] + sred[1] + sred[2] + sred[3];
  __syncthreads();
  return r;
}

__global__ __launch_bounds__(TPW) void k_tridiag_mw(float* __restrict__ Acopy,
                                                    float* __restrict__ dA,
                                                    float* __restrict__ subA,
                                                    float* __restrict__ tauA,
                                                    float* __restrict__ wbufA,
                                                    float* __restrict__ redwA,
                                                    int* __restrict__ barA) {
  const int g = blockIdx.x;          // WG index within matrix group
  const int n = blockIdx.y;          // matrix
  const int tid = threadIdx.x;
  const int lane = tid & 63, wv = tid >> 6;
  float* A     = Acopy + (size_t)n*NBB*NBB;
  float* wbuf  = wbufA + (size_t)n*NBB;
  float* normp = redwA + (size_t)n*2*GW;
  float* dotp  = normp + GW;
  int*   cnt   = barA + n;
  __shared__ float vsh[NBB];
  __shared__ float wsh[NBB];
  __shared__ float sred[4];
  int ep = 0;

  // initial norm of column 0 over rows >= 2 (own rows only)
  {
    float p = 0.f;
    for (int idx = tid; ; idx += TPW) {
      const int i = g + GW*idx;
      if (i >= NBB) break;
      if (i >= 2) { const float a = A[(size_t)i*NBB]; p += a*a; }
    }
    const float s = wg_reduce(p, sred);
    if (tid == 0) normp[g] = s;
  }
  ++ep; gbar(cnt, ep*GW);

  for (int k = 0; k < NBB-2; ++k) {
    const int m = NBB-1-k;
    // ---- phase A: scalars + load column k into LDS (v) ----
    float xn2 = 0.f;
    #pragma unroll
    for (int t = 0; t < GW; ++t) xn2 += normp[t];
    const float alpha = A[(size_t)(k+1)*NBB + k];
    float tau, scale;
    if (xn2 < 1e-26f) {
      tau = 0.f; scale = 0.f;
      if (g == 0 && tid == 0) { subA[n*NBB + k + 1] = alpha; tauA[n*NBB + k] = 0.f; }
    } else {
      const float beta = -copysignf(sqrtf(alpha*alpha + xn2), alpha);
      tau   = (beta - alpha) / beta;
      scale = 1.0f / (alpha - beta);
      if (g == 0 && tid == 0) { subA[n*NBB + k + 1] = beta; tauA[n*NBB + k] = tau; }
    }
    for (int i = k+1+tid; i < NBB; i += TPW)
      vsh[i-(k+1)] = (i == k+1) ? 1.0f : A[(size_t)i*NBB + k]*scale;
    __syncthreads();

    // first owned row >= k+1
    int rem = ((g - (k+1)) % GW + GW) % GW;
    const int r0 = k+1 + rem;

    if (tau != 0.f) {
      // ---- phase B: w_raw = A_trail * v for own rows; partial dot ----
      float dp = 0.f;
      for (int r = r0 + wv*GW; r < NBB; r += 4*GW) {
        const float* Ar = A + (size_t)r*NBB;
        float acc = 0.f;
        for (int c = k+1+lane; c < NBB; c += 64) acc += Ar[c]*vsh[c-(k+1)];
        #pragma unroll
        for (int off = 32; off > 0; off >>= 1) acc += __shfl_down(acc, off);
        if (lane == 0) { wbuf[r] = acc; dp += vsh[r-(k+1)]*acc; }
      }
      const float dsum = wg_reduce(dp, sred);
      if (tid == 0) dotp[g] = dsum;
      ++ep; gbar(cnt, ep*GW);

      // ---- phase C: finalize w, rank-2 update own rows, fuse next norm ----
      float dot = 0.f;
      #pragma unroll
      for (int t = 0; t < GW; ++t) dot += dotp[t];
      const float kc = 0.5f*tau*tau*dot;
      for (int j = tid; j < m; j += TPW) wsh[j] = tau*wbuf[k+1+j] - kc*vsh[j];
      __syncthreads();

      float np = 0.f;
      for (int r = r0 + wv*GW; r < NBB; r += 4*GW) {
        const float vr = vsh[r-(k+1)];
        const float wr = wsh[r-(k+1)];
        float* Ar = A + (size_t)r*NBB;
        for (int c = k+1+lane; c < NBB; c += 64) {
          const int ci = c-(k+1);
          const float nv = Ar[c] - (vr*wsh[ci] + wr*vsh[ci]);
          Ar[c] = nv;
          if (ci == 0 && r >= k+3) np += nv*nv;   // next-step column norm (col k+1)
        }
        if (lane == 0) Ar[k] = vr;                // store reflector
      }
      const float ns = wg_reduce(np, sred);
      if (tid == 0) normp[g] = ns;
      ++ep; gbar(cnt, ep*GW);
    } else {
      // tau == 0: trailing matrix unchanged; compute next norm directly
      float np = 0.f;
      for (int r = r0 + wv*GW; r < NBB; r += 4*GW) {
        if (lane == 0 && r >= k+3) { const float a = A[(size_t)r*NBB + k+1]; np += a*a; }
      }
      const float ns = wg_reduce(np, sred);
      if (tid == 0) normp[g] = ns;
      ++ep; gbar(cnt, ep*GW);
    }
  }

  // outputs: diagonal (own rows were updated by this WG -> self-visible)
  for (int idx = tid; ; idx += TPW) {
    const int i = g + GW*idx;
    if (i >= NBB) break;
    dA[n*NBB + i] = A[(size_t)i*NBB + i];
  }
  if (g == (NBB-1) % GW && tid == 0) subA[n*NBB + NBB-1] = A[(size_t)(NBB-1)*NBB + NBB-2];
  if (g == 0 && tid == 0) {
    subA[n*NBB + 0] = 0.f;
    tauA[n*NBB + NBB-2] = 0.f;
    tauA[n*NBB + NBB-1] = 0.f;
  }
}

// ---------------- all eigenvalues via bisection (Sturm counts) ----------------
__global__ __launch_bounds__(256) void k_bisect(const float* __restrict__ dA, const float* __restrict__ subA,
                                                float* __restrict__ eig, float* __restrict__ e_out) {
  const int n = blockIdx.y;
  const int i = blockIdx.x*256 + threadIdx.x;
  __shared__ float ds[NBB], ss[NBB];
  const float* dg = dA + n*NBB;
  const float* sg = subA + n*NBB;
  for (int j = threadIdx.x; j < NBB; j += 256) { ds[j] = dg[j]; ss[j] = sg[j]; }
  __syncthreads();
  if (i >= NBB) return;
  float lo = 1e30f, hi = -1e30f;
  for (int j = 0; j < NBB; ++j) {
    const float r = fabsf(ss[j]) + ((j+1 < NBB) ? fabsf(ss[j+1]) : 0.f);
    lo = fminf(lo, ds[j]-r); hi = fmaxf(hi, ds[j]+r);
  }
  const float pad = 1e-3f*(hi-lo) + 1e-3f;
  lo -= pad; hi += pad;
  for (int it = 0; it < 38; ++it) {
    const float mid = 0.5f*(lo+hi);
    int cnt = 0;
    float qv = ds[0]-mid;
    if (qv < 0.f) cnt++;
    for (int j = 1; j < NBB; ++j) {
      const float e = ss[j];
      if (fabsf(qv) < 1e-20f) qv = -1e-20f;
      qv = ds[j]-mid - e*e/qv;
      if (qv < 0.f) cnt++;
    }
    if (cnt > i) hi = mid; else lo = mid;
  }
  const float lam = 0.5f*(lo+hi);
  eig[n*NBB + i] = lam;
  e_out[n*NBB + i] = lam;
}

// ---------------- inverse iteration on T for the 128 lowest ----------------
__global__ __launch_bounds__(64) void k_invit(const float* __restrict__ dA, const float* __restrict__ subA,
                                              const float* __restrict__ eig, float* __restrict__ Utri) {
  const int i = blockIdx.x, n = blockIdx.y;
  const int lane = threadIdx.x;
  __shared__ float ds[NBB], ss[NBB], ud[NBB], u1[NBB], u2[NBB], yv[NBB], xv[NBB];
  const float* dg = dA + n*NBB;
  const float* sg = subA + n*NBB;
  for (int j = lane; j < NBB; j += 64) { ds[j] = dg[j]; ss[j] = sg[j]; }
  const float lam = eig[n*NBB + i];
  for (int j = lane; j < NBB; j += 64) {
    uint32_t s = (uint32_t)(j*2654435761u) ^ (uint32_t)(i*40503u + 977u) ^ (uint32_t)(n*9973u);
    s ^= s >> 16; s *= 0x7feb352dU; s ^= s >> 15; s *= 0x846ca68bU; s ^= s >> 16;
    yv[j] = 0.5f + (float)(s & 0xFFFF) * (1.0f/65536.0f);
  }
  __syncthreads();
  const float PIV = 3e-6f;
  for (int pass = 0; pass < 2; ++pass) {
    if (lane == 0) {
      float cd = ds[0] - lam;
      float cu = ss[1];
      float cy = yv[0];
      for (int j = 0; j < NBB-1; ++j) {
        const float bl = ss[j+1];
        const float bd = ds[j+1] - lam;
        const float bu = (j+2 < NBB) ? ss[j+2] : 0.f;
        const float yb = yv[j+1];
        float tud, tu1, tu2, tm, ncd, ncu, ny;
        if (fabsf(bl) > fabsf(cd)) {
          tud = bl; tu1 = bd; tu2 = bu;
          if (fabsf(tud) < PIV) tud = (tud < 0.f) ? -PIV : PIV;
          tm  = cd / tud;
          ncd = cu - tm*bd;
          ncu = -tm*bu;
          ny  = cy - tm*yb;
          yv[j] = yb;
        } else {
          tud = cd; tu1 = cu; tu2 = 0.f;
          if (fabsf(tud) < PIV) tud = (tud < 0.f) ? -PIV : PIV;
          tm  = bl / tud;
          ncd = bd - tm*cu;
          ncu = bu;
          ny  = yb - tm*cy;
          yv[j] = cy;
        }
        ud[j] = tud; u1[j] = tu1; u2[j] = tu2;
        cd = ncd; cu = ncu; cy = ny;
      }
      if (fabsf(cd) < PIV) cd = (cd < 0.f) ? -PIV : PIV;
      ud[NBB-1] = cd; u1[NBB-1] = 0.f; u2[NBB-1] = 0.f; yv[NBB-1] = cy;
      float x2 = yv[NBB-1]/ud[NBB-1];
      xv[NBB-1] = x2;
      float x1 = (yv[NBB-2] - u1[NBB-2]*x2)/ud[NBB-2];
      xv[NBB-2] = x1;
      for (int j = NBB-3; j >= 0; --j) {
        const float xj = (yv[j] - u1[j]*x1 - u2[j]*x2)/ud[j];
        xv[j] = xj;
        x2 = x1; x1 = xj;
      }
    }
    __syncthreads();
    float p2 = 0.f;
    for (int j = lane; j < NBB; j += 64) { const float t = xv[j]; p2 += t*t; }
    #pragma unroll
    for (int off = 32; off > 0; off >>= 1) p2 += __shfl_xor(p2, off);
    const float rin = rsqrtf(p2);
    if (pass == 0) {
      for (int j = lane; j < NBB; j += 64) yv[j] = xv[j]*rin;
      __syncthreads();
    } else {
      float* Ub = Utri + ((size_t)n*NOCC2 + i)*NBB;
      for (int j = lane; j < NBB; j += 64) Ub[j] = xv[j]*rin;
    }
  }
}

// ---------------- back-transform: Uocc = H0...H829 * Utri (U register-resident) ----------------
#define RPT 208
__global__ __launch_bounds__(512, 2) void k_backxform(const float* __restrict__ Acopy,
                                                      const float* __restrict__ tauA,
                                                      const float* __restrict__ Utri,
                                                      float* __restrict__ Uocc) {
  const int n = blockIdx.x;
  const int tid = threadIdx.x;
  const int j = tid & 127, g = tid >> 7;
  __shared__ float vlds[NBB];
  __shared__ float sred[4*128];
  const float* A = Acopy + (size_t)n*NBB*NBB;
  float U[RPT];
  const float* Ut = Utri + ((size_t)n*NOCC2 + j)*NBB + g*RPT;
  #pragma unroll
  for (int rr = 0; rr < RPT; ++rr) U[rr] = Ut[rr];
  const int rbase = g*RPT;
  for (int k = NBB-3; k >= 0; --k) {
    const float tau = tauA[n*NBB + k];
    if (tau == 0.f) continue;
    const int m = NBB-1-k;
    for (int idx = tid; idx < m; idx += 512) vlds[idx] = A[(size_t)(k+1+idx)*NBB + k];
    __syncthreads();
    float part = 0.f;
    #pragma unroll
    for (int rr = 0; rr < RPT; ++rr) {
      const int r = rbase + rr;
      if (r > k) part += U[rr]*vlds[r-k-1];
    }
    sred[g*128 + j] = part;
    __syncthreads();
    const float s = tau*(sred[j] + sred[128+j] + sred[256+j] + sred[384+j]);
    #pragma unroll
    for (int rr = 0; rr < RPT; ++rr) {
      const int r = rbase + rr;
      if (r > k) U[rr] -= s*vlds[r-k-1];
    }
    __syncthreads();
  }
  float* Ub = Uocc + (size_t)n*NBB*NOCC2;
  #pragma unroll
  for (int rr = 0; rr < RPT; ++rr) Ub[(size_t)(rbase+rr)*NOCC2 + j] = U[rr];
}

// ---------------- C = h_new * Uocc  (832x832 @ 832x128 per batch) ----------------
__global__ __launch_bounds__(256) void k_gemmC(const float* __restrict__ h,
                                               const float* __restrict__ Uocc,
                                               float* __restrict__ C) {
  const int rt = blockIdx.x, n = blockIdx.y;
  const int tid = threadIdx.x;
  __shared__ __align__(16) float hT[64*33];
  __shared__ __align__(16) float Ut[32*128];
  const int ty = tid >> 5, tx = tid & 31;
  float acc[8][4] = {};
  const float* hb = h + (size_t)n*NBB*NBB + (size_t)rt*64*NBB;
  const float* Ub = Uocc + (size_t)n*NBB*NOCC2;
  for (int k0 = 0; k0 < NBB; k0 += 32) {
    for (int idx = tid; idx < 64*32; idx += 256) {
      const int r = idx >> 5, c = idx & 31;
      hT[r*33 + c] = hb[(size_t)r*NBB + k0 + c];
    }
    for (int idx = tid; idx < 32*128; idx += 256) {
      const int r = idx >> 7, c = idx & 127;
      Ut[idx] = Ub[(size_t)(k0 + r)*NOCC2 + c];
    }
    __syncthreads();
    for (int kk = 0; kk < 32; ++kk) {
      const float4 b4 = *(const float4*)&Ut[kk*128 + tx*4];
      #pragma unroll
      for (int q = 0; q < 8; ++q) {
        const float a = hT[(ty*8 + q)*33 + kk];
        acc[q][0] += a*b4.x; acc[q][1] += a*b4.y; acc[q][2] += a*b4.z; acc[q][3] += a*b4.w;
      }
    }
    __syncthreads();
  }
  float* Cb = C + (size_t)n*NBB*NOCC2;
  #pragma unroll
  for (int q = 0; q < 8; ++q)
    #pragma unroll
    for (int p = 0; p < 4; ++p)
      Cb[(size_t)(rt*64 + ty*8 + q)*NOCC2 + tx*4 + p] = acc[q][p];
}

// ---------------- E = sum(e_occ) + Tr(Uocc^T h Uocc) + nuc ----------------
__global__ __launch_bounds__(256) void k_final(const float* __restrict__ eig,
                                               const float* __restrict__ Uocc, const float* __restrict__ C,
                                               const float* __restrict__ pos, const int* __restrict__ numbers,
                                               float* __restrict__ E_out) {
  const int n = blockIdx.x, tid = threadIdx.x;
  __shared__ float rb[256];
  float local = 0.f;
  for (int i = tid; i < NOCC2; i += 256) local += eig[n*NBB + i];
  const float* Ub = Uocc + (size_t)n*NBB*NOCC2;
  const float* Cb = C + (size_t)n*NBB*NOCC2;
  for (int idx = tid; idx < NBB*NOCC2; idx += 256) local += Ub[idx]*Cb[idx];
  float ln = 0.f;
  for (int t = tid; t < NPAIR; t += 256) {
    int kk, ll;
    pair_decode(t, kk, ll);
    const float dx = pos[(n*NK + kk)*3 + 0] - pos[(n*NK + ll)*3 + 0];
    const float dy = pos[(n*NK + kk)*3 + 1] - pos[(n*NK + ll)*3 + 1];
    const float dz = pos[(n*NK + kk)*3 + 2] - pos[(n*NK + ll)*3 + 2];
    const float d2 = dx*dx + dy*dy + dz*dz;
    const float Z = (float)(numbers[kk]*numbers[ll]);
    ln += Z / sqrtf(d2);
  }
  local += ln * A0C;
  rb[tid] = local;
  __syncthreads();
  for (int s = 128; s > 0; s >>= 1) {
    if (tid < s) rb[tid] += rb[tid + s];
    __syncthreads();
  }
  if (tid == 0) E_out[n] = rb[0];
}

extern "C" void kernel_launch(void* const* d_in, const int* in_sizes, int n_in,
                              void* d_out, int out_size, void* d_ws, size_t ws_size,
                              hipStream_t stream) {
  (void)in_sizes; (void)n_in; (void)out_size; (void)ws_size;
  const float* mu      = (const float*)d_in[0];
  const float* hnew    = (const float*)d_in[1];
  const float* pos     = (const float*)d_in[2];
  const float* Foff    = (const float*)d_in[3];
  const float* tW      = (const float*)d_in[4];
  const float* tb      = (const float*)d_in[5];
  const float* Won     = (const float*)d_in[6];
  const float* bon     = (const float*)d_in[7];
  const float* Woff    = (const float*)d_in[8];
  const float* boff    = (const float*)d_in[9];
  const int*   numbers = (const int*)d_in[10];

  float* out   = (float*)d_out;
  float* Fout  = out;                               // [16][832][832]
  float* e_out = out + (size_t)NBATCH*NBB*NBB;      // [16][832]
  float* E_out = e_out + (size_t)NBATCH*NBB;        // [16]

  float* ws    = (float*)d_ws;
  float* Acopy = ws + OFF_ACOPY;
  float* xbuf  = ws + OFF_X;
  float* Sbuf  = ws + OFF_S;
  float* dA    = ws + OFF_D;
  float* subA  = ws + OFF_SUB;
  float* tauA  = ws + OFF_TAU;
  float* eig   = ws + OFF_EIG;
  float* Utri  = ws + OFF_UTRI;
  float* Uocc  = ws + OFF_UOCC;
  float* Cbuf  = ws + OFF_C;    // overlays Utri
  float* wbufA = ws + OFF_WBUF; // overlays Utri (dead until k_invit)
  float* redwA = ws + OFF_REDW;
  int*   barA  = (int*)(ws + OFF_BAR);

  // zero the per-matrix barrier counters (graph-captured; runs every replay)
  hipMemsetAsync((void*)barA, 0, NBATCH*sizeof(int), stream);

  k_x<<<dim3(NK, NBATCH), dim3(256), 0, stream>>>(mu, tW, tb, xbuf);
  k_S<<<dim3(NBATCH), dim3(256), 0, stream>>>(xbuf, Sbuf);
  k_diag<<<dim3(NK, NBATCH), dim3(256), 0, stream>>>(xbuf, Sbuf, Won, bon, hnew, Foff, Fout, Acopy);
  k_off<<<dim3(6, 16, NBATCH), dim3(256), 0, stream>>>(xbuf, Woff, boff, hnew, Foff, Fout, Acopy);
  k_tridiag_mw<<<dim3(GW, NBATCH), dim3(TPW), 0, stream>>>(Acopy, dA, subA, tauA, wbufA, redwA, barA);
  k_bisect<<<dim3(4, NBATCH), dim3(256), 0, stream>>>(dA, subA, eig, e_out);
  k_invit<<<dim3(NOCC2, NBATCH), dim3(64), 0, stream>>>(dA, subA, eig, Utri);
  k_backxform<<<dim3(NBATCH), dim3(512), 0, stream>>>(Acopy, tauA, Utri, Uocc);
  k_gemmC<<<dim3(13, NBATCH), dim3(256), 0, stream>>>(hnew, Uocc, Cbuf);
  k_final<<<dim3(NBATCH), dim3(256), 0, stream>>>(eig, Uocc, Cbuf, pos, numbers, E_out);
}

// Round 3
// 83686.633 us; speedup vs baseline: 1.3902x; 1.2049x over previous
//
#include <hip/hip_runtime.h>
#include <math.h>
#include <stdint.h>

// Problem constants
#define NBATCH 16
#define NK     32
#define NTDS   768      // 3*DS
#define NMM    676      // BM*BM
#define NBM    26
#define NBB    832      // B = K*BM
#define NOCC2  128
#define NPAIR  496      // K*(K-1)/2
#define FSCALE 1.0e-4f
#define A0C    0.5291772f

// ---------------- workspace layout (in floats) ----------------
#define OFF_ACOPY 0ull
#define SZ_ACOPY  (16ull*832*832)
#define OFF_X     (OFF_ACOPY + SZ_ACOPY)
#define SZ_X      (16ull*32*768)
#define OFF_S     (OFF_X + SZ_X)
#define SZ_S      (16ull*768)
#define OFF_D     (OFF_S + SZ_S)
#define OFF_SUB   (OFF_D   + 16ull*832)
#define OFF_TAU   (OFF_SUB + 16ull*832)
#define OFF_EIG   (OFF_TAU + 16ull*832)
#define OFF_UTRI  (OFF_EIG + 16ull*832)
#define SZ_UTRI   (16ull*128*832)
#define OFF_UOCC  (OFF_UTRI + SZ_UTRI)
#define OFF_C     OFF_UTRI   /* C overlays Utri (dead after backxform) */
// tridiag scratch overlays the Utri region (Utri written only later by k_invit)
#define PB   32   // panel width
#define GW   16   // workgroups per matrix
#define TPW  512  // threads per workgroup
#define QMAX 52   // max own rows per WG (832/16)
#define SLOTSTR 1088
#define OFF_WPAN  OFF_UTRI                        /* 16*832*32 = 425,984 */
#define OFF_CBUF  (OFF_WPAN + 16ull*832*32)       /* 16*832 */
#define OFF_SLOT  (OFF_CBUF + 16ull*832)          /* 16*1088 */
#define OFF_BARC  (OFF_SLOT + 16ull*SLOTSTR)      /* 16 ints */

__device__ __forceinline__ void pair_decode(int t, int& k, int& l) {
  int kk = (int)((1.0f + sqrtf(1.0f + 8.0f*(float)t)) * 0.5f);
  while (kk*(kk-1)/2 > t) --kk;
  while ((kk+1)*kk/2 <= t) ++kk;
  k = kk; l = t - kk*(kk-1)/2;
}

// ---------------- x = mu @ transfer_W + b ----------------
__global__ __launch_bounds__(256) void k_x(const float* __restrict__ mu,
                                           const float* __restrict__ tW,
                                           const float* __restrict__ tb,
                                           float* __restrict__ x) {
  const int k = blockIdx.x, n = blockIdx.y, tid = threadIdx.x;
  __shared__ float mus[384];
  const float* mub = mu + (size_t)(n*NK + k)*384;
  for (int i = tid; i < 384; i += 256) mus[i] = mub[i];
  __syncthreads();
  float* xb = x + (size_t)(n*NK + k)*NTDS;
  for (int oo = tid; oo < NTDS; oo += 256) {
    const int d = oo >> 8, i = oo & 255;
    float acc = tb[i];
    const float* mrow = &mus[d*128];
    for (int a = 0; a < 128; ++a) acc += mrow[a]*tW[a*256 + i];
    xb[oo] = acc;
  }
}

// ---------------- S[n][dd] = sum_k x[n][k][dd] ----------------
__global__ __launch_bounds__(256) void k_S(const float* __restrict__ x, float* __restrict__ S) {
  const int n = blockIdx.x, tid = threadIdx.x;
  for (int dd = tid; dd < NTDS; dd += 256) {
    float s = 0.f;
    for (int k = 0; k < NK; ++k) s += x[(size_t)(n*NK + k)*NTDS + dd];
    S[n*NTDS + dd] = s;
  }
}

// ---------------- diagonal blocks ----------------
__global__ __launch_bounds__(256) void k_diag(const float* __restrict__ x, const float* __restrict__ S,
                                              const float* __restrict__ Won, const float* __restrict__ bon,
                                              const float* __restrict__ hnew, const float* __restrict__ Foff,
                                              float* __restrict__ Fout, float* __restrict__ Acopy) {
  const int k = blockIdx.x, n = blockIdx.y, tid = threadIdx.x;
  __shared__ float q[NTDS];
  __shared__ float M[NMM];
  const float* xb = x + (size_t)(n*NK + k)*NTDS;
  const float* Sb = S + n*NTDS;
  for (int i = tid; i < NTDS; i += 256) q[i] = xb[i]*Sb[i];
  __syncthreads();
  for (int m = tid; m < NMM; m += 256) {
    float acc = 32.0f * bon[m];
    for (int dd = 0; dd < NTDS; ++dd) acc += q[dd]*Won[(size_t)dd*NMM + m];
    M[m] = acc;
  }
  __syncthreads();
  const float* hb = hnew + (size_t)n*NBB*NBB;
  float* Fb = Fout + (size_t)n*NBB*NBB;
  float* Ab = Acopy + (size_t)n*NBB*NBB;
  for (int m = tid; m < NMM; m += 256) {
    const int a = m/26, b = m - a*26;
    const float val = 0.5f*(M[m] + M[b*26 + a]);
    const int P = k*26 + a, Q = k*26 + b;
    const size_t idx = (size_t)P*NBB + Q;
    const float fo = Foff[idx];
    const float hv = hb[idx];
    const float Fv = (fabsf(hv) > 1e-7f) ? (val*FSCALE + fo) : fo;
    Fb[idx] = Fv; Ab[idx] = Fv;
  }
}

// ---------------- off-diagonal blocks: GEMM over pairs ----------------
__global__ __launch_bounds__(256) void k_off(const float* __restrict__ x,
                                             const float* __restrict__ Woff, const float* __restrict__ boff,
                                             const float* __restrict__ hnew, const float* __restrict__ Foff,
                                             float* __restrict__ Fout, float* __restrict__ Acopy) {
  const int ct = blockIdx.x, pt = blockIdx.y, n = blockIdx.z;
  const int tid = threadIdx.x;
  __shared__ __align__(16) float At[32*65];
  __shared__ __align__(16) float Bt[64*128];
  __shared__ int klk[32], kll[32];
  if (tid < 32) {
    int pr = pt*32 + tid, kk = 1, ll = 0;
    if (pr < NPAIR) pair_decode(pr, kk, ll);
    klk[tid] = kk; kll[tid] = ll;
  }
  __syncthreads();
  const int ty = tid >> 5, tx = tid & 31;
  const int r0 = ty*4, c0 = tx*4;
  float acc[4][4] = {};
  for (int dd0 = 0; dd0 < NTDS; dd0 += 64) {
    for (int idx = tid; idx < 2048; idx += 256) {
      const int r = idx >> 6, c = idx & 63;
      const int pr = pt*32 + r;
      float v = 0.f;
      if (pr < NPAIR) {
        const int kk = klk[r], ll = kll[r];
        v = x[(size_t)(n*NK + kk)*NTDS + dd0 + c] * x[(size_t)(n*NK + ll)*NTDS + dd0 + c];
      }
      At[r*65 + c] = v;
    }
    for (int idx = tid; idx < 8192; idx += 256) {
      const int r = idx >> 7, c = idx & 127;
      const int col = ct*128 + c;
      Bt[idx] = (col < NMM) ? Woff[(size_t)(dd0 + r)*NMM + col] : 0.f;
    }
    __syncthreads();
    for (int kk = 0; kk < 64; ++kk) {
      float av[4];
      av[0] = At[(r0+0)*65 + kk];
      av[1] = At[(r0+1)*65 + kk];
      av[2] = At[(r0+2)*65 + kk];
      av[3] = At[(r0+3)*65 + kk];
      const float4 b4 = *(const float4*)&Bt[kk*128 + c0];
      const float bb[4] = {b4.x, b4.y, b4.z, b4.w};
      #pragma unroll
      for (int qq = 0; qq < 4; ++qq)
        #pragma unroll
        for (int pp = 0; pp < 4; ++pp)
          acc[qq][pp] += av[qq]*bb[pp];
    }
    __syncthreads();
  }
  const float* hb = hnew + (size_t)n*NBB*NBB;
  float* Fb = Fout + (size_t)n*NBB*NBB;
  float* Ab = Acopy + (size_t)n*NBB*NBB;
  for (int qq = 0; qq < 4; ++qq) {
    const int pr = pt*32 + r0 + qq;
    if (pr >= NPAIR) continue;
    const int kk = klk[r0+qq], ll = kll[r0+qq];
    for (int pp = 0; pp < 4; ++pp) {
      const int m = ct*128 + c0 + pp;
      if (m >= NMM) continue;
      const float val = acc[qq][pp] + boff[m];
      const int a = m/26, b = m - a*26;
      const int P = kk*26 + a, Q = ll*26 + b;
      const size_t i1 = (size_t)P*NBB + Q;
      const float fo1 = Foff[i1], hv1 = hb[i1];
      const float Fv1 = (fabsf(hv1) > 1e-7f) ? (val*FSCALE + fo1) : fo1;
      Fb[i1] = Fv1; Ab[i1] = Fv1;
      const size_t i2 = (size_t)Q*NBB + P;
      const float fo2 = Foff[i2], hv2 = hb[i2];
      const float Fv2 = (fabsf(hv2) > 1e-7f) ? (val*FSCALE + fo2) : fo2;
      Fb[i2] = Fv2; Ab[i2] = Fv2;
    }
  }
}

// ================= blocked (latrd) multi-WG tridiagonalization =================
// 16 WGs x 512 threads per matrix; row r owned by WG r%16.
// Within a panel the trailing matrix is READ-ONLY (stays cached in L2);
// rank-2*PB syr2k applied once per panel. 2 device barriers per column.
// Reflectors stored TRANSPOSED: v of column k lives in A[k][k+1..] (upper tri).
__device__ __forceinline__ void gbar(int* cnt, int target) {
  __syncthreads();
  if (threadIdx.x == 0) {
    __threadfence();               // release (wbl2)
    atomicAdd(cnt, 1);
    while (__hip_atomic_load(cnt, __ATOMIC_RELAXED, __HIP_MEMORY_SCOPE_AGENT) < target)
      __builtin_amdgcn_s_sleep(1);
    __threadfence();               // acquire (inv)
  }
  __syncthreads();
}

__device__ __forceinline__ float wg_reduce8(float v, volatile float* sred) {
  #pragma unroll
  for (int off = 32; off > 0; off >>= 1) v += __shfl_down(v, off);
  const int tid = threadIdx.x;
  if ((tid & 63) == 0) sred[tid >> 6] = v;
  __syncthreads();
  float r = 0.f;
  #pragma unroll
  for (int t = 0; t < 8; ++t) r += sred[t];
  __syncthreads();
  return r;
}

__global__ __launch_bounds__(TPW) void k_tridiag_panel(float* __restrict__ Acopy,
                                                       float* __restrict__ dA,
                                                       float* __restrict__ subA,
                                                       float* __restrict__ tauA,
                                                       float* __restrict__ Wpan,
                                                       float* __restrict__ cbufA,
                                                       float* __restrict__ slotA,
                                                       int* __restrict__ barA) {
  const int g = blockIdx.x;          // WG within matrix
  const int n = blockIdx.y;          // matrix
  const int tid = threadIdx.x;
  const int lane = tid & 63, wv = tid >> 6;
  float* A    = Acopy + (size_t)n*NBB*NBB;
  float* Wbuf = Wpan  + (size_t)n*NBB*PB;
  float* cbuf = cbufA + (size_t)n*NBB;
  float* slot = slotA + (size_t)n*SLOTSTR;
  float* normp = slot;          // [16]
  float* vavp  = slot + 16;     // [16]
  float* alphaS= slot + 32;     // [1]
  float* ynextS= slot + 33;     // [1]
  float* d1pA  = slot + 64;     // [16][32]
  float* d2pA  = slot + 576;    // [16][32]
  int*   cnt   = barA + n;

  __shared__ float vsh[NBB];
  __shared__ float yloc[QMAX];
  __shared__ float Vloc[QMAX*33];
  __shared__ float Wloc[QMAX*33];
  __shared__ float Vt[64*33];
  __shared__ float Wt[64*33];
  __shared__ float d1s[PB], d2s[PB], Vk1s[PB], Wk1s[PB];
  __shared__ float sred[8];
  __shared__ float s_tau, s_scale, s_vav, s_ynext;
  int ep = 0;

  // ---- prologue: c = A[:,0], norm partials, alpha ----
  {
    const int q0p = (16 - g) >> 4;   // first q with 16q+g >= 1
    float np = 0.f;
    const int q = q0p + tid;
    if (q < QMAX) {
      const int j = 16*q + g;
      const float cv = A[(size_t)j*NBB];
      cbuf[j] = cv;
      if (j >= 2) np = cv*cv;
      if (j == 1) alphaS[0] = cv;
    }
    const float s = wg_reduce8(np, sred);
    if (tid == 0) normp[g] = s;
  }
  ++ep; gbar(cnt, ep*GW);

  for (int k0 = 0; k0 < NBB-2; k0 += PB) {
    const int ilim = (NBB-2-k0 < PB) ? (NBB-2-k0) : PB;
    for (int i = 0; i < ilim; ++i) {
      const int k = k0 + i;
      const int m = NBB-1-k;
      const int q0 = (k + 16 - g) >> 4;   // first q with 16q+g >= k+1

      // ================= Epoch X =================
      if (tid == 0) {
        float xn2 = 0.f;
        #pragma unroll
        for (int t = 0; t < GW; ++t) xn2 += normp[t];
        const float alpha = alphaS[0];
        float tau, scale, beta;
        if (xn2 < 1e-26f) {
          beta = alpha; tau = 0.f; scale = 0.f;
        } else {
          beta  = -copysignf(sqrtf(alpha*alpha + xn2), alpha);
          tau   = (beta - alpha) / beta;
          scale = 1.0f / (alpha - beta);
        }
        s_tau = tau; s_scale = scale;
        if (g == 0) { subA[n*NBB + k + 1] = beta; tauA[n*NBB + k] = tau; }
      }
      __syncthreads();
      const float tau = s_tau, scale = s_scale;
      // build full v in LDS
      for (int idx = tid; idx < m; idx += TPW)
        vsh[idx] = (idx == 0) ? 1.0f : cbuf[k+1+idx]*scale;
      __syncthreads();
      // store v (own entries) into row k (transposed reflector) + Vloc
      {
        const int q = q0 + tid;
        if (q < QMAX) {
          const int j = 16*q + g;
          const float val = vsh[j-(k+1)];
          A[(size_t)k*NBB + j] = val;
          Vloc[q*33 + i] = val;
        }
      }
      // d1/d2 partials over own rows (p < i)
      for (int p = wv; p < i; p += 8) {
        float a1 = 0.f, a2 = 0.f;
        const int q = q0 + lane;
        if (q < QMAX) {
          const int j = 16*q + g;
          const float vj = vsh[j-(k+1)];
          a1 = Vloc[q*33 + p]*vj;
          a2 = Wloc[q*33 + p]*vj;
        }
        #pragma unroll
        for (int off = 32; off > 0; off >>= 1) { a1 += __shfl_down(a1, off); a2 += __shfl_down(a2, off); }
        if (lane == 0) { d1pA[g*PB + p] = a1; d2pA[g*PB + p] = a2; }
      }
      // matvec y = A0 v over own rows; vav partial; ynext
      float vavl = 0.f;
      for (int q = q0 + wv; q < QMAX; q += 8) {
        const int j = 16*q + g;
        const float* Ar = A + (size_t)j*NBB;
        float acc = 0.f;
        for (int c = k+1+lane; c < NBB; c += 64) acc += Ar[c]*vsh[c-(k+1)];
        #pragma unroll
        for (int off = 32; off > 0; off >>= 1) acc += __shfl_down(acc, off);
        if (lane == 0) {
          yloc[q] = acc;
          vavl += vsh[j-(k+1)]*acc;
          if (j == k+1) ynextS[0] = acc;
        }
      }
      const float vv = wg_reduce8(vavl, sred);
      if (tid == 0) vavp[g] = vv;
      ++ep; gbar(cnt, ep*GW);

      // ================= Epoch Y =================
      if (tid < i) {
        float s1 = 0.f, s2 = 0.f;
        #pragma unroll
        for (int g2 = 0; g2 < GW; ++g2) { s1 += d1pA[g2*PB + tid]; s2 += d2pA[g2*PB + tid]; }
        d1s[tid] = s1; d2s[tid] = s2;
        Vk1s[tid] = A[(size_t)(k0+tid)*NBB + (k+1)];
        Wk1s[tid] = Wbuf[(size_t)(k+1)*PB + tid];
      }
      if (tid == TPW-1) {
        float sv = 0.f;
        #pragma unroll
        for (int t = 0; t < GW; ++t) sv += vavp[t];
        s_vav = sv; s_ynext = ynextS[0];
      }
      __syncthreads();
      // redundant scalars
      float s12 = 0.f, wk1acc = 0.f;
      for (int p = 0; p < i; ++p) { s12 += d1s[p]*d2s[p]; wk1acc += Vk1s[p]*d2s[p] + Wk1s[p]*d1s[p]; }
      const float corr = 0.5f*tau*tau*(s_vav - 2.f*s12);
      const float wk1 = tau*(s_ynext - wk1acc) - corr;
      // own-row w, then c' for column k+1
      {
        const int q = q0 + tid;
        float np = 0.f;
        if (q < QMAX) {
          const int j = 16*q + g;
          float wacc = 0.f;
          for (int p = 0; p < i; ++p) wacc += Vloc[q*33 + p]*d2s[p] + Wloc[q*33 + p]*d1s[p];
          const float vj = vsh[j-(k+1)];
          const float wj = tau*(yloc[q] - wacc) - corr*vj;
          Wloc[q*33 + i] = wj;
          Wbuf[(size_t)j*PB + i] = wj;
          if (j >= k+2) {
            float cacc = 0.f;
            for (int p = 0; p < i; ++p) cacc += Vloc[q*33 + p]*Wk1s[p] + Wloc[q*33 + p]*Vk1s[p];
            cacc += vj*wk1 + wj;   // p = i term (V[k+1,i] = 1)
            const float cp = A[(size_t)j*NBB + (k+1)] - cacc;
            cbuf[j] = cp;
            if (j >= k+3) np = cp*cp;
            if (j == k+2) alphaS[0] = cp;
          }
        }
        const float ns = wg_reduce8(np, sred);
        if (tid == 0) normp[g] = ns;
      }
      // diagonal extraction d[k]
      if (g == (k & 15) && tid == 0) {
        float dk = A[(size_t)k*NBB + k];
        for (int p = 0; p < i; ++p)
          dk -= 2.f * A[(size_t)(k0+p)*NBB + k] * Wbuf[(size_t)k*PB + p];
        dA[n*NBB + k] = dk;
      }
      ++ep; gbar(cnt, ep*GW);
    }

    // ================= syr2k: A22 -= V W^T + W V^T =================
    if (k0 + PB < NBB-2) {
      const int kp = k0 + PB;
      const int q0s = (kp + 15 - g) >> 4;   // first q with 16q+g >= kp
      for (int c0 = kp+1; c0 < NBB; c0 += 64) {
        const int nc = (NBB - c0 < 64) ? (NBB - c0) : 64;
        for (int r = 0; r < 4; ++r) {
          const int idx = r*TPW + tid;
          { const int p = idx >> 6, cc = idx & 63;
            Vt[cc*33 + p] = (cc < nc) ? A[(size_t)(k0+p)*NBB + c0 + cc] : 0.f; }
          { const int p = idx & 31, cc = (idx >> 5) & 63;
            Wt[cc*33 + p] = (cc < nc) ? Wbuf[(size_t)(c0+cc)*PB + p] : 0.f; }
        }
        __syncthreads();
        for (int q = q0s + wv; q < QMAX; q += 8) {
          const int j = 16*q + g;
          if (lane < nc) {
            const int c = c0 + lane;
            float acc = 0.f;
            #pragma unroll
            for (int p = 0; p < PB; ++p)
              acc += Vloc[q*33 + p]*Wt[lane*33 + p] + Wloc[q*33 + p]*Vt[lane*33 + p];
            A[(size_t)j*NBB + c] -= acc;
          }
        }
        __syncthreads();
      }
      // diagonal entry [kp][kp]
      if (g == (kp & 15) && tid == 0) {
        const int qd = kp >> 4;
        float acc = 0.f;
        #pragma unroll
        for (int p = 0; p < PB; ++p) acc += Vloc[qd*33 + p]*Wloc[qd*33 + p];
        A[(size_t)kp*NBB + kp] -= 2.f*acc;
      }
      ++ep; gbar(cnt, ep*GW);
    }
  }

  // ---- epilogue ----
  if (g == 0 && tid == 0) {
    const int k0l = ((NBB-3)/PB)*PB;       // 800
    const int np_ = NBB-2-k0l;             // 30
    float dm2 = A[(size_t)(NBB-2)*NBB + (NBB-2)];
    float dm1 = A[(size_t)(NBB-1)*NBB + (NBB-1)];
    for (int p = 0; p < np_; ++p) {
      dm2 -= 2.f * A[(size_t)(k0l+p)*NBB + (NBB-2)] * Wbuf[(size_t)(NBB-2)*PB + p];
      dm1 -= 2.f * A[(size_t)(k0l+p)*NBB + (NBB-1)] * Wbuf[(size_t)(NBB-1)*PB + p];
    }
    dA[n*NBB + NBB-2] = dm2;
    dA[n*NBB + NBB-1] = dm1;
    subA[n*NBB + NBB-1] = alphaS[0];
    subA[n*NBB + 0] = 0.f;
    tauA[n*NBB + NBB-2] = 0.f;
    tauA[n*NBB + NBB-1] = 0.f;
  }
}

// ---------------- all eigenvalues via bisection (Sturm counts) ----------------
__global__ __launch_bounds__(256) void k_bisect(const float* __restrict__ dA, const float* __restrict__ subA,
                                                float* __restrict__ eig, float* __restrict__ e_out) {
  const int n = blockIdx.y;
  const int i = blockIdx.x*256 + threadIdx.x;
  __shared__ float ds[NBB], ss[NBB];
  const float* dg = dA + n*NBB;
  const float* sg = subA + n*NBB;
  for (int j = threadIdx.x; j < NBB; j += 256) { ds[j] = dg[j]; ss[j] = sg[j]; }
  __syncthreads();
  if (i >= NBB) return;
  float lo = 1e30f, hi = -1e30f;
  for (int j = 0; j < NBB; ++j) {
    const float r = fabsf(ss[j]) + ((j+1 < NBB) ? fabsf(ss[j+1]) : 0.f);
    lo = fminf(lo, ds[j]-r); hi = fmaxf(hi, ds[j]+r);
  }
  const float pad = 1e-3f*(hi-lo) + 1e-3f;
  lo -= pad; hi += pad;
  for (int it = 0; it < 38; ++it) {
    const float mid = 0.5f*(lo+hi);
    int cnt = 0;
    float qv = ds[0]-mid;
    if (qv < 0.f) cnt++;
    for (int j = 1; j < NBB; ++j) {
      const float e = ss[j];
      if (fabsf(qv) < 1e-20f) qv = -1e-20f;
      qv = ds[j]-mid - e*e/qv;
      if (qv < 0.f) cnt++;
    }
    if (cnt > i) hi = mid; else lo = mid;
  }
  const float lam = 0.5f*(lo+hi);
  eig[n*NBB + i] = lam;
  e_out[n*NBB + i] = lam;
}

// ---------------- inverse iteration on T for the 128 lowest ----------------
__global__ __launch_bounds__(64) void k_invit(const float* __restrict__ dA, const float* __restrict__ subA,
                                              const float* __restrict__ eig, float* __restrict__ Utri) {
  const int i = blockIdx.x, n = blockIdx.y;
  const int lane = threadIdx.x;
  __shared__ float ds[NBB], ss[NBB], ud[NBB], u1[NBB], u2[NBB], yv[NBB], xv[NBB];
  const float* dg = dA + n*NBB;
  const float* sg = subA + n*NBB;
  for (int j = lane; j < NBB; j += 64) { ds[j] = dg[j]; ss[j] = sg[j]; }
  const float lam = eig[n*NBB + i];
  for (int j = lane; j < NBB; j += 64) {
    uint32_t s = (uint32_t)(j*2654435761u) ^ (uint32_t)(i*40503u + 977u) ^ (uint32_t)(n*9973u);
    s ^= s >> 16; s *= 0x7feb352dU; s ^= s >> 15; s *= 0x846ca68bU; s ^= s >> 16;
    yv[j] = 0.5f + (float)(s & 0xFFFF) * (1.0f/65536.0f);
  }
  __syncthreads();
  const float PIV = 3e-6f;
  for (int pass = 0; pass < 2; ++pass) {
    if (lane == 0) {
      float cd = ds[0] - lam;
      float cu = ss[1];
      float cy = yv[0];
      for (int j = 0; j < NBB-1; ++j) {
        const float bl = ss[j+1];
        const float bd = ds[j+1] - lam;
        const float bu = (j+2 < NBB) ? ss[j+2] : 0.f;
        const float yb = yv[j+1];
        float tud, tu1, tu2, tm, ncd, ncu, ny;
        if (fabsf(bl) > fabsf(cd)) {
          tud = bl; tu1 = bd; tu2 = bu;
          if (fabsf(tud) < PIV) tud = (tud < 0.f) ? -PIV : PIV;
          tm  = cd / tud;
          ncd = cu - tm*bd;
          ncu = -tm*bu;
          ny  = cy - tm*yb;
          yv[j] = yb;
        } else {
          tud = cd; tu1 = cu; tu2 = 0.f;
          if (fabsf(tud) < PIV) tud = (tud < 0.f) ? -PIV : PIV;
          tm  = bl / tud;
          ncd = bd - tm*cu;
          ncu = bu;
          ny  = yb - tm*cy;
          yv[j] = cy;
        }
        ud[j] = tud; u1[j] = tu1; u2[j] = tu2;
        cd = ncd; cu = ncu; cy = ny;
      }
      if (fabsf(cd) < PIV) cd = (cd < 0.f) ? -PIV : PIV;
      ud[NBB-1] = cd; u1[NBB-1] = 0.f; u2[NBB-1] = 0.f; yv[NBB-1] = cy;
      float x2 = yv[NBB-1]/ud[NBB-1];
      xv[NBB-1] = x2;
      float x1 = (yv[NBB-2] - u1[NBB-2]*x2)/ud[NBB-2];
      xv[NBB-2] = x1;
      for (int j = NBB-3; j >= 0; --j) {
        const float xj = (yv[j] - u1[j]*x1 - u2[j]*x2)/ud[j];
        xv[j] = xj;
        x2 = x1; x1 = xj;
      }
    }
    __syncthreads();
    float p2 = 0.f;
    for (int j = lane; j < NBB; j += 64) { const float t = xv[j]; p2 += t*t; }
    #pragma unroll
    for (int off = 32; off > 0; off >>= 1) p2 += __shfl_xor(p2, off);
    const float rin = rsqrtf(p2);
    if (pass == 0) {
      for (int j = lane; j < NBB; j += 64) yv[j] = xv[j]*rin;
      __syncthreads();
    } else {
      float* Ub = Utri + ((size_t)n*NOCC2 + i)*NBB;
      for (int j = lane; j < NBB; j += 64) Ub[j] = xv[j]*rin;
    }
  }
}

// ---------------- back-transform: Uocc = H0...H829 * Utri (U register-resident) ----------------
#define RPT 208
__global__ __launch_bounds__(512, 2) void k_backxform(const float* __restrict__ Acopy,
                                                      const float* __restrict__ tauA,
                                                      const float* __restrict__ Utri,
                                                      float* __restrict__ Uocc) {
  const int n = blockIdx.x;
  const int tid = threadIdx.x;
  const int j = tid & 127, g = tid >> 7;
  __shared__ float vlds[NBB];
  __shared__ float sred[4*128];
  const float* A = Acopy + (size_t)n*NBB*NBB;
  float U[RPT];
  const float* Ut = Utri + ((size_t)n*NOCC2 + j)*NBB + g*RPT;
  #pragma unroll
  for (int rr = 0; rr < RPT; ++rr) U[rr] = Ut[rr];
  const int rbase = g*RPT;
  for (int k = NBB-3; k >= 0; --k) {
    const float tau = tauA[n*NBB + k];
    if (tau == 0.f) continue;
    const int m = NBB-1-k;
    // transposed reflector storage: v lives in row k, cols k+1..
    for (int idx = tid; idx < m; idx += 512) vlds[idx] = A[(size_t)k*NBB + (k+1+idx)];
    __syncthreads();
    float part = 0.f;
    #pragma unroll
    for (int rr = 0; rr < RPT; ++rr) {
      const int r = rbase + rr;
      if (r > k) part += U[rr]*vlds[r-k-1];
    }
    sred[g*128 + j] = part;
    __syncthreads();
    const float s = tau*(sred[j] + sred[128+j] + sred[256+j] + sred[384+j]);
    #pragma unroll
    for (int rr = 0; rr < RPT; ++rr) {
      const int r = rbase + rr;
      if (r > k) U[rr] -= s*vlds[r-k-1];
    }
    __syncthreads();
  }
  float* Ub = Uocc + (size_t)n*NBB*NOCC2;
  #pragma unroll
  for (int rr = 0; rr < RPT; ++rr) Ub[(size_t)(rbase+rr)*NOCC2 + j] = U[rr];
}

// ---------------- C = h_new * Uocc  (832x832 @ 832x128 per batch) ----------------
__global__ __launch_bounds__(256) void k_gemmC(const float* __restrict__ h,
                                               const float* __restrict__ Uocc,
                                               float* __restrict__ C) {
  const int rt = blockIdx.x, n = blockIdx.y;
  const int tid = threadIdx.x;
  __shared__ __align__(16) float hT[64*33];
  __shared__ __align__(16) float Ut[32*128];
  const int ty = tid >> 5, tx = tid & 31;
  float acc[8][4] = {};
  const float* hb = h + (size_t)n*NBB*NBB + (size_t)rt*64*NBB;
  const float* Ub = Uocc + (size_t)n*NBB*NOCC2;
  for (int k0 = 0; k0 < NBB; k0 += 32) {
    for (int idx = tid; idx < 64*32; idx += 256) {
      const int r = idx >> 5, c = idx & 31;
      hT[r*33 + c] = hb[(size_t)r*NBB + k0 + c];
    }
    for (int idx = tid; idx < 32*128; idx += 256) {
      const int r = idx >> 7, c = idx & 127;
      Ut[idx] = Ub[(size_t)(k0 + r)*NOCC2 + c];
    }
    __syncthreads();
    for (int kk = 0; kk < 32; ++kk) {
      const float4 b4 = *(const float4*)&Ut[kk*128 + tx*4];
      #pragma unroll
      for (int q = 0; q < 8; ++q) {
        const float a = hT[(ty*8 + q)*33 + kk];
        acc[q][0] += a*b4.x; acc[q][1] += a*b4.y; acc[q][2] += a*b4.z; acc[q][3] += a*b4.w;
      }
    }
    __syncthreads();
  }
  float* Cb = C + (size_t)n*NBB*NOCC2;
  #pragma unroll
  for (int q = 0; q < 8; ++q)
    #pragma unroll
    for (int p = 0; p < 4; ++p)
      Cb[(size_t)(rt*64 + ty*8 + q)*NOCC2 + tx*4 + p] = acc[q][p];
}

// ---------------- E = sum(e_occ) + Tr(Uocc^T h Uocc) + nuc ----------------
__global__ __launch_bounds__(256) void k_final(const float* __restrict__ eig,
                                               const float* __restrict__ Uocc, const float* __restrict__ C,
                                               const float* __restrict__ pos, const int* __restrict__ numbers,
                                               float* __restrict__ E_out) {
  const int n = blockIdx.x, tid = threadIdx.x;
  __shared__ float rb[256];
  float local = 0.f;
  for (int i = tid; i < NOCC2; i += 256) local += eig[n*NBB + i];
  const float* Ub = Uocc + (size_t)n*NBB*NOCC2;
  const float* Cb = C + (size_t)n*NBB*NOCC2;
  for (int idx = tid; idx < NBB*NOCC2; idx += 256) local += Ub[idx]*Cb[idx];
  float ln = 0.f;
  for (int t = tid; t < NPAIR; t += 256) {
    int kk, ll;
    pair_decode(t, kk, ll);
    const float dx = pos[(n*NK + kk)*3 + 0] - pos[(n*NK + ll)*3 + 0];
    const float dy = pos[(n*NK + kk)*3 + 1] - pos[(n*NK + ll)*3 + 1];
    const float dz = pos[(n*NK + kk)*3 + 2] - pos[(n*NK + ll)*3 + 2];
    const float d2 = dx*dx + dy*dy + dz*dz;
    const float Z = (float)(numbers[kk]*numbers[ll]);
    ln += Z / sqrtf(d2);
  }
  local += ln * A0C;
  rb[tid] = local;
  __syncthreads();
  for (int s = 128; s > 0; s >>= 1) {
    if (tid < s) rb[tid] += rb[tid + s];
    __syncthreads();
  }
  if (tid == 0) E_out[n] = rb[0];
}

extern "C" void kernel_launch(void* const* d_in, const int* in_sizes, int n_in,
                              void* d_out, int out_size, void* d_ws, size_t ws_size,
                              hipStream_t stream) {
  (void)in_sizes; (void)n_in; (void)out_size; (void)ws_size;
  const float* mu      = (const float*)d_in[0];
  const float* hnew    = (const float*)d_in[1];
  const float* pos     = (const float*)d_in[2];
  const float* Foff    = (const float*)d_in[3];
  const float* tW      = (const float*)d_in[4];
  const float* tb      = (const float*)d_in[5];
  const float* Won     = (const float*)d_in[6];
  const float* bon     = (const float*)d_in[7];
  const float* Woff    = (const float*)d_in[8];
  const float* boff    = (const float*)d_in[9];
  const int*   numbers = (const int*)d_in[10];

  float* out   = (float*)d_out;
  float* Fout  = out;                               // [16][832][832]
  float* e_out = out + (size_t)NBATCH*NBB*NBB;      // [16][832]
  float* E_out = e_out + (size_t)NBATCH*NBB;        // [16]

  float* ws    = (float*)d_ws;
  float* Acopy = ws + OFF_ACOPY;
  float* xbuf  = ws + OFF_X;
  float* Sbuf  = ws + OFF_S;
  float* dA    = ws + OFF_D;
  float* subA  = ws + OFF_SUB;
  float* tauA  = ws + OFF_TAU;
  float* eig   = ws + OFF_EIG;
  float* Utri  = ws + OFF_UTRI;
  float* Uocc  = ws + OFF_UOCC;
  float* Cbuf  = ws + OFF_C;     // overlays Utri
  float* Wpan  = ws + OFF_WPAN;  // overlays Utri (dead until k_invit)
  float* cbufA = ws + OFF_CBUF;
  float* slotA = ws + OFF_SLOT;
  int*   barA  = (int*)(ws + OFF_BARC);

  // zero the per-matrix barrier counters (graph-captured; runs every replay)
  hipMemsetAsync((void*)barA, 0, NBATCH*sizeof(int), stream);

  k_x<<<dim3(NK, NBATCH), dim3(256), 0, stream>>>(mu, tW, tb, xbuf);
  k_S<<<dim3(NBATCH), dim3(256), 0, stream>>>(xbuf, Sbuf);
  k_diag<<<dim3(NK, NBATCH), dim3(256), 0, stream>>>(xbuf, Sbuf, Won, bon, hnew, Foff, Fout, Acopy);
  k_off<<<dim3(6, 16, NBATCH), dim3(256), 0, stream>>>(xbuf, Woff, boff, hnew, Foff, Fout, Acopy);
  k_tridiag_panel<<<dim3(GW, NBATCH), dim3(TPW), 0, stream>>>(Acopy, dA, subA, tauA, Wpan, cbufA, slotA, barA);
  k_bisect<<<dim3(4, NBATCH), dim3(256), 0, stream>>>(dA, subA, eig, e_out);
  k_invit<<<dim3(NOCC2, NBATCH), dim3(64), 0, stream>>>(dA, subA, eig, Utri);
  k_backxform<<<dim3(NBATCH), dim3(512), 0, stream>>>(Acopy, tauA, Utri, Uocc);
  k_gemmC<<<dim3(13, NBATCH), dim3(256), 0, stream>>>(hnew, Uocc, Cbuf);
  k_final<<<dim3(NBATCH), dim3(256), 0, stream>>>(eig, Uocc, Cbuf, pos, numbers, E_out);
}

// Round 5
// 65318.817 us; speedup vs baseline: 1.7811x; 1.2812x over previous
//
#include <hip/hip_runtime.h>
#include <math.h>
#include <stdint.h>

// Problem constants
#define NBATCH 16
#define NK     32
#define NTDS   768      // 3*DS
#define NMM    676      // BM*BM
#define NBM    26
#define NBB    832      // B = K*BM
#define NOCC2  128
#define NPAIR  496      // K*(K-1)/2
#define FSCALE 1.0e-4f
#define A0C    0.5291772f

// ---------------- workspace layout (in floats) ----------------
#define OFF_ACOPY 0ull
#define SZ_ACOPY  (16ull*832*832)
#define OFF_X     (OFF_ACOPY + SZ_ACOPY)
#define SZ_X      (16ull*32*768)
#define OFF_S     (OFF_X + SZ_X)
#define SZ_S      (16ull*768)
#define OFF_D     (OFF_S + SZ_S)
#define OFF_SUB   (OFF_D   + 16ull*832)
#define OFF_TAU   (OFF_SUB + 16ull*832)
#define OFF_EIG   (OFF_TAU + 16ull*832)
#define OFF_UTRI  (OFF_EIG + 16ull*832)
#define SZ_UTRI   (16ull*128*832)
#define OFF_UOCC  (OFF_UTRI + SZ_UTRI)
#define OFF_C     OFF_UTRI   /* C overlays Utri (dead after backxform) */
// tridiag scratch overlays the Utri region (Utri written only later by k_invit)
#define PB   32   // panel width
#define GW   16   // workgroups per matrix
#define TPW  512  // threads per workgroup
#define QMAX 52   // max own rows per WG (832/16)
#define SLOTSTR 1088
#define OFF_WPAN  OFF_UTRI                        /* 16*832*32 = 425,984 */
#define OFF_CBUF  (OFF_WPAN + 16ull*832*32)       /* 16*832 */
#define OFF_SLOT  (OFF_CBUF + 16ull*832)          /* 16*1088 */
#define OFF_BARC  (OFF_SLOT + 16ull*SLOTSTR)      /* 16 ints */

__device__ __forceinline__ void pair_decode(int t, int& k, int& l) {
  int kk = (int)((1.0f + sqrtf(1.0f + 8.0f*(float)t)) * 0.5f);
  while (kk*(kk-1)/2 > t) --kk;
  while ((kk+1)*kk/2 <= t) ++kk;
  k = kk; l = t - kk*(kk-1)/2;
}

// ---------------- x = mu @ transfer_W + b ----------------
__global__ __launch_bounds__(256) void k_x(const float* __restrict__ mu,
                                           const float* __restrict__ tW,
                                           const float* __restrict__ tb,
                                           float* __restrict__ x) {
  const int k = blockIdx.x, n = blockIdx.y, tid = threadIdx.x;
  __shared__ float mus[384];
  const float* mub = mu + (size_t)(n*NK + k)*384;
  for (int i = tid; i < 384; i += 256) mus[i] = mub[i];
  __syncthreads();
  float* xb = x + (size_t)(n*NK + k)*NTDS;
  for (int oo = tid; oo < NTDS; oo += 256) {
    const int d = oo >> 8, i = oo & 255;
    float acc = tb[i];
    const float* mrow = &mus[d*128];
    for (int a = 0; a < 128; ++a) acc += mrow[a]*tW[a*256 + i];
    xb[oo] = acc;
  }
}

// ---------------- S[n][dd] = sum_k x[n][k][dd] ----------------
__global__ __launch_bounds__(256) void k_S(const float* __restrict__ x, float* __restrict__ S) {
  const int n = blockIdx.x, tid = threadIdx.x;
  for (int dd = tid; dd < NTDS; dd += 256) {
    float s = 0.f;
    for (int k = 0; k < NK; ++k) s += x[(size_t)(n*NK + k)*NTDS + dd];
    S[n*NTDS + dd] = s;
  }
}

// ---------------- diagonal blocks ----------------
__global__ __launch_bounds__(256) void k_diag(const float* __restrict__ x, const float* __restrict__ S,
                                              const float* __restrict__ Won, const float* __restrict__ bon,
                                              const float* __restrict__ hnew, const float* __restrict__ Foff,
                                              float* __restrict__ Fout, float* __restrict__ Acopy) {
  const int k = blockIdx.x, n = blockIdx.y, tid = threadIdx.x;
  __shared__ float q[NTDS];
  __shared__ float M[NMM];
  const float* xb = x + (size_t)(n*NK + k)*NTDS;
  const float* Sb = S + n*NTDS;
  for (int i = tid; i < NTDS; i += 256) q[i] = xb[i]*Sb[i];
  __syncthreads();
  for (int m = tid; m < NMM; m += 256) {
    float acc = 32.0f * bon[m];
    for (int dd = 0; dd < NTDS; ++dd) acc += q[dd]*Won[(size_t)dd*NMM + m];
    M[m] = acc;
  }
  __syncthreads();
  const float* hb = hnew + (size_t)n*NBB*NBB;
  float* Fb = Fout + (size_t)n*NBB*NBB;
  float* Ab = Acopy + (size_t)n*NBB*NBB;
  for (int m = tid; m < NMM; m += 256) {
    const int a = m/26, b = m - a*26;
    const float val = 0.5f*(M[m] + M[b*26 + a]);
    const int P = k*26 + a, Q = k*26 + b;
    const size_t idx = (size_t)P*NBB + Q;
    const float fo = Foff[idx];
    const float hv = hb[idx];
    const float Fv = (fabsf(hv) > 1e-7f) ? (val*FSCALE + fo) : fo;
    Fb[idx] = Fv; Ab[idx] = Fv;
  }
}

// ---------------- off-diagonal blocks: GEMM over pairs ----------------
__global__ __launch_bounds__(256) void k_off(const float* __restrict__ x,
                                             const float* __restrict__ Woff, const float* __restrict__ boff,
                                             const float* __restrict__ hnew, const float* __restrict__ Foff,
                                             float* __restrict__ Fout, float* __restrict__ Acopy) {
  const int ct = blockIdx.x, pt = blockIdx.y, n = blockIdx.z;
  const int tid = threadIdx.x;
  __shared__ __align__(16) float At[32*65];
  __shared__ __align__(16) float Bt[64*128];
  __shared__ int klk[32], kll[32];
  if (tid < 32) {
    int pr = pt*32 + tid, kk = 1, ll = 0;
    if (pr < NPAIR) pair_decode(pr, kk, ll);
    klk[tid] = kk; kll[tid] = ll;
  }
  __syncthreads();
  const int ty = tid >> 5, tx = tid & 31;
  const int r0 = ty*4, c0 = tx*4;
  float acc[4][4] = {};
  for (int dd0 = 0; dd0 < NTDS; dd0 += 64) {
    for (int idx = tid; idx < 2048; idx += 256) {
      const int r = idx >> 6, c = idx & 63;
      const int pr = pt*32 + r;
      float v = 0.f;
      if (pr < NPAIR) {
        const int kk = klk[r], ll = kll[r];
        v = x[(size_t)(n*NK + kk)*NTDS + dd0 + c] * x[(size_t)(n*NK + ll)*NTDS + dd0 + c];
      }
      At[r*65 + c] = v;
    }
    for (int idx = tid; idx < 8192; idx += 256) {
      const int r = idx >> 7, c = idx & 127;
      const int col = ct*128 + c;
      Bt[idx] = (col < NMM) ? Woff[(size_t)(dd0 + r)*NMM + col] : 0.f;
    }
    __syncthreads();
    for (int kk = 0; kk < 64; ++kk) {
      float av[4];
      av[0] = At[(r0+0)*65 + kk];
      av[1] = At[(r0+1)*65 + kk];
      av[2] = At[(r0+2)*65 + kk];
      av[3] = At[(r0+3)*65 + kk];
      const float4 b4 = *(const float4*)&Bt[kk*128 + c0];
      const float bb[4] = {b4.x, b4.y, b4.z, b4.w};
      #pragma unroll
      for (int qq = 0; qq < 4; ++qq)
        #pragma unroll
        for (int pp = 0; pp < 4; ++pp)
          acc[qq][pp] += av[qq]*bb[pp];
    }
    __syncthreads();
  }
  const float* hb = hnew + (size_t)n*NBB*NBB;
  float* Fb = Fout + (size_t)n*NBB*NBB;
  float* Ab = Acopy + (size_t)n*NBB*NBB;
  for (int qq = 0; qq < 4; ++qq) {
    const int pr = pt*32 + r0 + qq;
    if (pr >= NPAIR) continue;
    const int kk = klk[r0+qq], ll = kll[r0+qq];
    for (int pp = 0; pp < 4; ++pp) {
      const int m = ct*128 + c0 + pp;
      if (m >= NMM) continue;
      const float val = acc[qq][pp] + boff[m];
      const int a = m/26, b = m - a*26;
      const int P = kk*26 + a, Q = ll*26 + b;
      const size_t i1 = (size_t)P*NBB + Q;
      const float fo1 = Foff[i1], hv1 = hb[i1];
      const float Fv1 = (fabsf(hv1) > 1e-7f) ? (val*FSCALE + fo1) : fo1;
      Fb[i1] = Fv1; Ab[i1] = Fv1;
      const size_t i2 = (size_t)Q*NBB + P;
      const float fo2 = Foff[i2], hv2 = hb[i2];
      const float Fv2 = (fabsf(hv2) > 1e-7f) ? (val*FSCALE + fo2) : fo2;
      Fb[i2] = Fv2; Ab[i2] = Fv2;
    }
  }
}

// ================= blocked (latrd) multi-WG tridiagonalization =================
// PROVEN-COHERENCE scheme (R3): plain cached accesses everywhere + full
// threadfence (wbl2 release / inv acquire) barriers. Cross-XCD visibility is
// guaranteed by the release-writeback of dirty L2 lines before the flag
// increment and the acquire-invalidate after the poll. Do NOT weaken this —
// the relaxed-atomic variant (R4) raced on real HW and produced NaNs.
__device__ __forceinline__ void gbar(int* cnt, int target) {
  __syncthreads();
  if (threadIdx.x == 0) {
    __threadfence();               // release: L2 writeback to coherence point
    atomicAdd(cnt, 1);             // device-scope
    while (__hip_atomic_load(cnt, __ATOMIC_RELAXED, __HIP_MEMORY_SCOPE_AGENT) < target)
      __builtin_amdgcn_s_sleep(1);
    __threadfence();               // acquire: invalidate stale lines
  }
  __syncthreads();
}

__device__ __forceinline__ float wg_reduce8(float v, volatile float* sred) {
  #pragma unroll
  for (int off = 32; off > 0; off >>= 1) v += __shfl_down(v, off);
  const int tid = threadIdx.x;
  if ((tid & 63) == 0) sred[tid >> 6] = v;
  __syncthreads();
  float r = 0.f;
  #pragma unroll
  for (int t = 0; t < 8; ++t) r += sred[t];
  __syncthreads();
  return r;
}

__global__ __launch_bounds__(TPW) void k_tridiag_panel(float* __restrict__ Acopy,
                                                       float* __restrict__ dA,
                                                       float* __restrict__ subA,
                                                       float* __restrict__ tauA,
                                                       float* __restrict__ Wpan,
                                                       float* __restrict__ cbufA,
                                                       float* __restrict__ slotA,
                                                       int* __restrict__ barA) {
  const int g = blockIdx.x;          // WG within matrix
  const int n = blockIdx.y;          // matrix
  const int tid = threadIdx.x;
  const int lane = tid & 63, wv = tid >> 6;
  float* A    = Acopy + (size_t)n*NBB*NBB;
  float* Wbuf = Wpan  + (size_t)n*NBB*PB;
  float* cbuf = cbufA + (size_t)n*NBB;
  float* slot = slotA + (size_t)n*SLOTSTR;
  float* normp = slot;          // [16]
  float* vavp  = slot + 16;     // [16]
  float* alphaS= slot + 32;     // [1]
  float* ynextS= slot + 33;     // [1]
  float* d1pA  = slot + 64;     // [16][32]
  float* d2pA  = slot + 576;    // [16][32]
  int*   cnt   = barA + n;

  __shared__ float vsh[NBB];
  __shared__ float yloc[QMAX];
  __shared__ float Vloc[QMAX*33];
  __shared__ float Wloc[QMAX*33];
  __shared__ float Vt[64*33];
  __shared__ float Wt[64*33];
  __shared__ float d1s[PB], d2s[PB], Vk1s[PB], Wk1s[PB];
  __shared__ float sred[8];
  __shared__ float s_tau, s_scale, s_vav, s_ynext;
  int ep = 0;

  // ---- prologue: c = A[:,0], norm partials, alpha ----
  {
    const int q0p = (16 - g) >> 4;   // first q with 16q+g >= 1
    float np = 0.f;
    const int q = q0p + tid;
    if (q < QMAX) {
      const int j = 16*q + g;
      const float cv = A[(size_t)j*NBB];
      cbuf[j] = cv;
      if (j >= 2) np = cv*cv;
      if (j == 1) alphaS[0] = cv;
    }
    const float s = wg_reduce8(np, sred);
    if (tid == 0) normp[g] = s;
  }
  ++ep; gbar(cnt, ep*GW);

  for (int k0 = 0; k0 < NBB-2; k0 += PB) {
    const int ilim = (NBB-2-k0 < PB) ? (NBB-2-k0) : PB;
    for (int i = 0; i < ilim; ++i) {
      const int k = k0 + i;
      const int m = NBB-1-k;
      const int q0 = (k + 16 - g) >> 4;   // first q with 16q+g >= k+1

      // ================= Epoch X =================
      if (tid == 0) {
        float xn2 = 0.f;
        #pragma unroll
        for (int t = 0; t < GW; ++t) xn2 += normp[t];
        const float alpha = alphaS[0];
        float tau, scale, beta;
        if (xn2 < 1e-26f) {
          beta = alpha; tau = 0.f; scale = 0.f;
        } else {
          beta  = -copysignf(sqrtf(alpha*alpha + xn2), alpha);
          tau   = (beta - alpha) / beta;
          scale = 1.0f / (alpha - beta);
        }
        s_tau = tau; s_scale = scale;
        if (g == 0) { subA[n*NBB + k + 1] = beta; tauA[n*NBB + k] = tau; }
      }
      __syncthreads();
      const float tau = s_tau, scale = s_scale;
      // build full v in LDS
      for (int idx = tid; idx < m; idx += TPW)
        vsh[idx] = (idx == 0) ? 1.0f : cbuf[k+1+idx]*scale;
      __syncthreads();
      // store v (own entries) into row k (transposed reflector) + Vloc
      {
        const int q = q0 + tid;
        if (q < QMAX) {
          const int j = 16*q + g;
          const float val = vsh[j-(k+1)];
          A[(size_t)k*NBB + j] = val;
          Vloc[q*33 + i] = val;
        }
      }
      // d1/d2 partials over own rows (p < i)
      for (int p = wv; p < i; p += 8) {
        float a1 = 0.f, a2 = 0.f;
        const int q = q0 + lane;
        if (q < QMAX) {
          const int j = 16*q + g;
          const float vj = vsh[j-(k+1)];
          a1 = Vloc[q*33 + p]*vj;
          a2 = Wloc[q*33 + p]*vj;
        }
        #pragma unroll
        for (int off = 32; off > 0; off >>= 1) { a1 += __shfl_down(a1, off); a2 += __shfl_down(a2, off); }
        if (lane == 0) { d1pA[g*PB + p] = a1; d2pA[g*PB + p] = a2; }
      }
      // matvec y = A0 v over own rows; vav partial; ynext
      float vavl = 0.f;
      for (int q = q0 + wv; q < QMAX; q += 8) {
        const int j = 16*q + g;
        const float* Ar = A + (size_t)j*NBB;
        float acc = 0.f;
        for (int c = k+1+lane; c < NBB; c += 64) acc += Ar[c]*vsh[c-(k+1)];
        #pragma unroll
        for (int off = 32; off > 0; off >>= 1) acc += __shfl_down(acc, off);
        if (lane == 0) {
          yloc[q] = acc;
          vavl += vsh[j-(k+1)]*acc;
          if (j == k+1) ynextS[0] = acc;
        }
      }
      const float vv = wg_reduce8(vavl, sred);
      if (tid == 0) vavp[g] = vv;
      ++ep; gbar(cnt, ep*GW);

      // ================= Epoch Y =================
      if (tid < i) {
        float s1 = 0.f, s2 = 0.f;
        #pragma unroll
        for (int g2 = 0; g2 < GW; ++g2) { s1 += d1pA[g2*PB + tid]; s2 += d2pA[g2*PB + tid]; }
        d1s[tid] = s1; d2s[tid] = s2;
        Vk1s[tid] = A[(size_t)(k0+tid)*NBB + (k+1)];
        Wk1s[tid] = Wbuf[(size_t)(k+1)*PB + tid];
      }
      if (tid == TPW-1) {
        float sv = 0.f;
        #pragma unroll
        for (int t = 0; t < GW; ++t) sv += vavp[t];
        s_vav = sv; s_ynext = ynextS[0];
      }
      __syncthreads();
      // redundant scalars
      float s12 = 0.f, wk1acc = 0.f;
      for (int p = 0; p < i; ++p) { s12 += d1s[p]*d2s[p]; wk1acc += Vk1s[p]*d2s[p] + Wk1s[p]*d1s[p]; }
      const float corr = 0.5f*tau*tau*(s_vav - 2.f*s12);
      const float wk1 = tau*(s_ynext - wk1acc) - corr;
      // own-row w, then c' for column k+1
      {
        const int q = q0 + tid;
        float np = 0.f;
        if (q < QMAX) {
          const int j = 16*q + g;
          float wacc = 0.f;
          for (int p = 0; p < i; ++p) wacc += Vloc[q*33 + p]*d2s[p] + Wloc[q*33 + p]*d1s[p];
          const float vj = vsh[j-(k+1)];
          const float wj = tau*(yloc[q] - wacc) - corr*vj;
          Wloc[q*33 + i] = wj;
          Wbuf[(size_t)j*PB + i] = wj;
          if (j >= k+2) {
            float cacc = 0.f;
            for (int p = 0; p < i; ++p) cacc += Vloc[q*33 + p]*Wk1s[p] + Wloc[q*33 + p]*Vk1s[p];
            cacc += vj*wk1 + wj;   // p = i term (V[k+1,i] = 1)
            const float cp = A[(size_t)j*NBB + (k+1)] - cacc;
            cbuf[j] = cp;
            if (j >= k+3) np = cp*cp;
            if (j == k+2) alphaS[0] = cp;
          }
        }
        const float ns = wg_reduce8(np, sred);
        if (tid == 0) normp[g] = ns;
      }
      // diagonal extraction d[k]
      if (g == (k & 15) && tid == 0) {
        float dk = A[(size_t)k*NBB + k];
        for (int p = 0; p < i; ++p)
          dk -= 2.f * A[(size_t)(k0+p)*NBB + k] * Wbuf[(size_t)k*PB + p];
        dA[n*NBB + k] = dk;
      }
      ++ep; gbar(cnt, ep*GW);
    }

    // ================= syr2k: A22 -= V W^T + W V^T =================
    if (k0 + PB < NBB-2) {
      const int kp = k0 + PB;
      const int q0s = (kp + 15 - g) >> 4;   // first q with 16q+g >= kp
      for (int c0 = kp+1; c0 < NBB; c0 += 64) {
        const int nc = (NBB - c0 < 64) ? (NBB - c0) : 64;
        for (int r = 0; r < 4; ++r) {
          const int idx = r*TPW + tid;
          { const int p = idx >> 6, cc = idx & 63;
            Vt[cc*33 + p] = (cc < nc) ? A[(size_t)(k0+p)*NBB + c0 + cc] : 0.f; }
          { const int p = idx & 31, cc = (idx >> 5) & 63;
            Wt[cc*33 + p] = (cc < nc) ? Wbuf[(size_t)(c0+cc)*PB + p] : 0.f; }
        }
        __syncthreads();
        for (int q = q0s + wv; q < QMAX; q += 8) {
          const int j = 16*q + g;
          if (lane < nc) {
            const int c = c0 + lane;
            float acc = 0.f;
            #pragma unroll
            for (int p = 0; p < PB; ++p)
              acc += Vloc[q*33 + p]*Wt[lane*33 + p] + Wloc[q*33 + p]*Vt[lane*33 + p];
            A[(size_t)j*NBB + c] -= acc;
          }
        }
        __syncthreads();
      }
      // diagonal entry [kp][kp]
      if (g == (kp & 15) && tid == 0) {
        const int qd = kp >> 4;
        float acc = 0.f;
        #pragma unroll
        for (int p = 0; p < PB; ++p) acc += Vloc[qd*33 + p]*Wloc[qd*33 + p];
        A[(size_t)kp*NBB + kp] -= 2.f*acc;
      }
      ++ep; gbar(cnt, ep*GW);
    }
  }

  // ---- epilogue ----
  if (g == 0 && tid == 0) {
    const int k0l = ((NBB-3)/PB)*PB;       // 800
    const int np_ = NBB-2-k0l;             // 30
    float dm2 = A[(size_t)(NBB-2)*NBB + (NBB-2)];
    float dm1 = A[(size_t)(NBB-1)*NBB + (NBB-1)];
    for (int p = 0; p < np_; ++p) {
      dm2 -= 2.f * A[(size_t)(k0l+p)*NBB + (NBB-2)] * Wbuf[(size_t)(NBB-2)*PB + p];
      dm1 -= 2.f * A[(size_t)(k0l+p)*NBB + (NBB-1)] * Wbuf[(size_t)(NBB-1)*PB + p];
    }
    dA[n*NBB + NBB-2] = dm2;
    dA[n*NBB + NBB-1] = dm1;
    subA[n*NBB + NBB-1] = alphaS[0];
    subA[n*NBB + 0] = 0.f;
    tauA[n*NBB + NBB-2] = 0.f;
    tauA[n*NBB + NBB-1] = 0.f;
  }
}

// ---------------- all eigenvalues via bisection (Sturm counts) ----------------
__global__ __launch_bounds__(256) void k_bisect(const float* __restrict__ dA, const float* __restrict__ subA,
                                                float* __restrict__ eig, float* __restrict__ e_out) {
  const int n = blockIdx.y;
  const int i = blockIdx.x*256 + threadIdx.x;
  __shared__ float ds[NBB], ss[NBB];
  const float* dg = dA + n*NBB;
  const float* sg = subA + n*NBB;
  for (int j = threadIdx.x; j < NBB; j += 256) { ds[j] = dg[j]; ss[j] = sg[j]; }
  __syncthreads();
  if (i >= NBB) return;
  float lo = 1e30f, hi = -1e30f;
  for (int j = 0; j < NBB; ++j) {
    const float r = fabsf(ss[j]) + ((j+1 < NBB) ? fabsf(ss[j+1]) : 0.f);
    lo = fminf(lo, ds[j]-r); hi = fmaxf(hi, ds[j]+r);
  }
  const float pad = 1e-3f*(hi-lo) + 1e-3f;
  lo -= pad; hi += pad;
  for (int it = 0; it < 38; ++it) {
    const float mid = 0.5f*(lo+hi);
    int cnt = 0;
    float qv = ds[0]-mid;
    if (qv < 0.f) cnt++;
    for (int j = 1; j < NBB; ++j) {
      const float e = ss[j];
      if (fabsf(qv) < 1e-20f) qv = -1e-20f;
      qv = ds[j]-mid - e*e/qv;
      if (qv < 0.f) cnt++;
    }
    if (cnt > i) hi = mid; else lo = mid;
  }
  const float lam = 0.5f*(lo+hi);
  eig[n*NBB + i] = lam;
  e_out[n*NBB + i] = lam;
}

// ---------------- inverse iteration on T for the 128 lowest ----------------
__global__ __launch_bounds__(64) void k_invit(const float* __restrict__ dA, const float* __restrict__ subA,
                                              const float* __restrict__ eig, float* __restrict__ Utri) {
  const int i = blockIdx.x, n = blockIdx.y;
  const int lane = threadIdx.x;
  __shared__ float ds[NBB], ss[NBB], ud[NBB], u1[NBB], u2[NBB], yv[NBB], xv[NBB];
  const float* dg = dA + n*NBB;
  const float* sg = subA + n*NBB;
  for (int j = lane; j < NBB; j += 64) { ds[j] = dg[j]; ss[j] = sg[j]; }
  const float lam = eig[n*NBB + i];
  for (int j = lane; j < NBB; j += 64) {
    uint32_t s = (uint32_t)(j*2654435761u) ^ (uint32_t)(i*40503u + 977u) ^ (uint32_t)(n*9973u);
    s ^= s >> 16; s *= 0x7feb352dU; s ^= s >> 15; s *= 0x846ca68bU; s ^= s >> 16;
    yv[j] = 0.5f + (float)(s & 0xFFFF) * (1.0f/65536.0f);
  }
  __syncthreads();
  const float PIV = 3e-6f;
  for (int pass = 0; pass < 2; ++pass) {
    if (lane == 0) {
      float cd = ds[0] - lam;
      float cu = ss[1];
      float cy = yv[0];
      for (int j = 0; j < NBB-1; ++j) {
        const float bl = ss[j+1];
        const float bd = ds[j+1] - lam;
        const float bu = (j+2 < NBB) ? ss[j+2] : 0.f;
        const float yb = yv[j+1];
        float tud, tu1, tu2, tm, ncd, ncu, ny;
        if (fabsf(bl) > fabsf(cd)) {
          tud = bl; tu1 = bd; tu2 = bu;
          if (fabsf(tud) < PIV) tud = (tud < 0.f) ? -PIV : PIV;
          tm  = cd / tud;
          ncd = cu - tm*bd;
          ncu = -tm*bu;
          ny  = cy - tm*yb;
          yv[j] = yb;
        } else {
          tud = cd; tu1 = cu; tu2 = 0.f;
          if (fabsf(tud) < PIV) tud = (tud < 0.f) ? -PIV : PIV;
          tm  = bl / tud;
          ncd = bd - tm*cu;
          ncu = bu;
          ny  = yb - tm*cy;
          yv[j] = cy;
        }
        ud[j] = tud; u1[j] = tu1; u2[j] = tu2;
        cd = ncd; cu = ncu; cy = ny;
      }
      if (fabsf(cd) < PIV) cd = (cd < 0.f) ? -PIV : PIV;
      ud[NBB-1] = cd; u1[NBB-1] = 0.f; u2[NBB-1] = 0.f; yv[NBB-1] = cy;
      float x2 = yv[NBB-1]/ud[NBB-1];
      xv[NBB-1] = x2;
      float x1 = (yv[NBB-2] - u1[NBB-2]*x2)/ud[NBB-2];
      xv[NBB-2] = x1;
      for (int j = NBB-3; j >= 0; --j) {
        const float xj = (yv[j] - u1[j]*x1 - u2[j]*x2)/ud[j];
        xv[j] = xj;
        x2 = x1; x1 = xj;
      }
    }
    __syncthreads();
    float p2 = 0.f;
    for (int j = lane; j < NBB; j += 64) { const float t = xv[j]; p2 += t*t; }
    #pragma unroll
    for (int off = 32; off > 0; off >>= 1) p2 += __shfl_xor(p2, off);
    const float rin = rsqrtf(p2);
    if (pass == 0) {
      for (int j = lane; j < NBB; j += 64) yv[j] = xv[j]*rin;
      __syncthreads();
    } else {
      float* Ub = Utri + ((size_t)n*NOCC2 + i)*NBB;
      for (int j = lane; j < NBB; j += 64) Ub[j] = xv[j]*rin;
    }
  }
}

// ---------------- back-transform: Uocc = H0...H829 * Utri ----------------
// 2 WGs per matrix (64 columns each), 8 row-groups x 104 rows; U[104]/thread
// keeps VGPRs (~130) well under the 256 cap — the old U[208] variant sat at
// the spill cliff and is the suspected hidden ~25-30 ms cost of R1-R3.
#define RPT 104
__global__ __launch_bounds__(512, 2) void k_backxform(const float* __restrict__ Acopy,
                                                      const float* __restrict__ tauA,
                                                      const float* __restrict__ Utri,
                                                      float* __restrict__ Uocc) {
  const int cg = blockIdx.x;         // column half (0/1)
  const int n = blockIdx.y;
  const int tid = threadIdx.x;
  const int jc = tid & 63, g = tid >> 6;   // 8 row-groups x 104 rows
  const int col = cg*64 + jc;
  __shared__ float vlds[NBB];
  __shared__ float sred[8*64];
  const float* A = Acopy + (size_t)n*NBB*NBB;
  float U[RPT];
  const float* Ut = Utri + ((size_t)n*NOCC2 + col)*NBB + g*RPT;
  #pragma unroll
  for (int rr = 0; rr < RPT; ++rr) U[rr] = Ut[rr];
  const int rbase = g*RPT;
  for (int k = NBB-3; k >= 0; --k) {
    const float tau = tauA[n*NBB + k];
    if (tau == 0.f) continue;
    const int m = NBB-1-k;
    // transposed reflector storage: v lives in row k, cols k+1..
    for (int idx = tid; idx < m; idx += 512) vlds[idx] = A[(size_t)k*NBB + (k+1+idx)];
    __syncthreads();
    float part = 0.f;
    #pragma unroll
    for (int rr = 0; rr < RPT; ++rr) {
      const int r = rbase + rr;
      if (r > k) part += U[rr]*vlds[r-k-1];
    }
    sred[g*64 + jc] = part;
    __syncthreads();
    float ssum = 0.f;
    #pragma unroll
    for (int t = 0; t < 8; ++t) ssum += sred[t*64 + jc];
    const float s = tau*ssum;
    #pragma unroll
    for (int rr = 0; rr < RPT; ++rr) {
      const int r = rbase + rr;
      if (r > k) U[rr] -= s*vlds[r-k-1];
    }
    __syncthreads();
  }
  float* Ub = Uocc + (size_t)n*NBB*NOCC2;
  #pragma unroll
  for (int rr = 0; rr < RPT; ++rr) Ub[(size_t)(rbase+rr)*NOCC2 + col] = U[rr];
}

// ---------------- C = h_new * Uocc  (832x832 @ 832x128 per batch) ----------------
__global__ __launch_bounds__(256) void k_gemmC(const float* __restrict__ h,
                                               const float* __restrict__ Uocc,
                                               float* __restrict__ C) {
  const int rt = blockIdx.x, n = blockIdx.y;
  const int tid = threadIdx.x;
  __shared__ __align__(16) float hT[64*33];
  __shared__ __align__(16) float Ut[32*128];
  const int ty = tid >> 5, tx = tid & 31;
  float acc[8][4] = {};
  const float* hb = h + (size_t)n*NBB*NBB + (size_t)rt*64*NBB;
  const float* Ub = Uocc + (size_t)n*NBB*NOCC2;
  for (int k0 = 0; k0 < NBB; k0 += 32) {
    for (int idx = tid; idx < 64*32; idx += 256) {
      const int r = idx >> 5, c = idx & 31;
      hT[r*33 + c] = hb[(size_t)r*NBB + k0 + c];
    }
    for (int idx = tid; idx < 32*128; idx += 256) {
      const int r = idx >> 7, c = idx & 127;
      Ut[idx] = Ub[(size_t)(k0 + r)*NOCC2 + c];
    }
    __syncthreads();
    for (int kk = 0; kk < 32; ++kk) {
      const float4 b4 = *(const float4*)&Ut[kk*128 + tx*4];
      #pragma unroll
      for (int q = 0; q < 8; ++q) {
        const float a = hT[(ty*8 + q)*33 + kk];
        acc[q][0] += a*b4.x; acc[q][1] += a*b4.y; acc[q][2] += a*b4.z; acc[q][3] += a*b4.w;
      }
    }
    __syncthreads();
  }
  float* Cb = C + (size_t)n*NBB*NOCC2;
  #pragma unroll
  for (int q = 0; q < 8; ++q)
    #pragma unroll
    for (int p = 0; p < 4; ++p)
      Cb[(size_t)(rt*64 + ty*8 + q)*NOCC2 + tx*4 + p] = acc[q][p];
}

// ---------------- E = sum(e_occ) + Tr(Uocc^T h Uocc) + nuc ----------------
__global__ __launch_bounds__(256) void k_final(const float* __restrict__ eig,
                                               const float* __restrict__ Uocc, const float* __restrict__ C,
                                               const float* __restrict__ pos, const int* __restrict__ numbers,
                                               float* __restrict__ E_out) {
  const int n = blockIdx.x, tid = threadIdx.x;
  __shared__ float rb[256];
  float local = 0.f;
  for (int i = tid; i < NOCC2; i += 256) local += eig[n*NBB + i];
  const float* Ub = Uocc + (size_t)n*NBB*NOCC2;
  const float* Cb = C + (size_t)n*NBB*NOCC2;
  for (int idx = tid; idx < NBB*NOCC2; idx += 256) local += Ub[idx]*Cb[idx];
  float ln = 0.f;
  for (int t = tid; t < NPAIR; t += 256) {
    int kk, ll;
    pair_decode(t, kk, ll);
    const float dx = pos[(n*NK + kk)*3 + 0] - pos[(n*NK + ll)*3 + 0];
    const float dy = pos[(n*NK + kk)*3 + 1] - pos[(n*NK + ll)*3 + 1];
    const float dz = pos[(n*NK + kk)*3 + 2] - pos[(n*NK + ll)*3 + 2];
    const float d2 = dx*dx + dy*dy + dz*dz;
    const float Z = (float)(numbers[kk]*numbers[ll]);
    ln += Z / sqrtf(d2);
  }
  local += ln * A0C;
  rb[tid] = local;
  __syncthreads();
  for (int s = 128; s > 0; s >>= 1) {
    if (tid < s) rb[tid] += rb[tid + s];
    __syncthreads();
  }
  if (tid == 0) E_out[n] = rb[0];
}

extern "C" void kernel_launch(void* const* d_in, const int* in_sizes, int n_in,
                              void* d_out, int out_size, void* d_ws, size_t ws_size,
                              hipStream_t stream) {
  (void)in_sizes; (void)n_in; (void)out_size; (void)ws_size;
  const float* mu      = (const float*)d_in[0];
  const float* hnew    = (const float*)d_in[1];
  const float* pos     = (const float*)d_in[2];
  const float* Foff    = (const float*)d_in[3];
  const float* tW      = (const float*)d_in[4];
  const float* tb      = (const float*)d_in[5];
  const float* Won     = (const float*)d_in[6];
  const float* bon     = (const float*)d_in[7];
  const float* Woff    = (const float*)d_in[8];
  const float* boff    = (const float*)d_in[9];
  const int*   numbers = (const int*)d_in[10];

  float* out   = (float*)d_out;
  float* Fout  = out;                               // [16][832][832]
  float* e_out = out + (size_t)NBATCH*NBB*NBB;      // [16][832]
  float* E_out = e_out + (size_t)NBATCH*NBB;        // [16]

  float* ws    = (float*)d_ws;
  float* Acopy = ws + OFF_ACOPY;
  float* xbuf  = ws + OFF_X;
  float* Sbuf  = ws + OFF_S;
  float* dA    = ws + OFF_D;
  float* subA  = ws + OFF_SUB;
  float* tauA  = ws + OFF_TAU;
  float* eig   = ws + OFF_EIG;
  float* Utri  = ws + OFF_UTRI;
  float* Uocc  = ws + OFF_UOCC;
  float* Cbuf  = ws + OFF_C;     // overlays Utri
  float* Wpan  = ws + OFF_WPAN;  // overlays Utri (dead until k_invit)
  float* cbufA = ws + OFF_CBUF;
  float* slotA = ws + OFF_SLOT;
  int*   barA  = (int*)(ws + OFF_BARC);

  // zero the per-matrix barrier counters (graph-captured; runs every replay)
  hipMemsetAsync((void*)barA, 0, NBATCH*sizeof(int), stream);

  k_x<<<dim3(NK, NBATCH), dim3(256), 0, stream>>>(mu, tW, tb, xbuf);
  k_S<<<dim3(NBATCH), dim3(256), 0, stream>>>(xbuf, Sbuf);
  k_diag<<<dim3(NK, NBATCH), dim3(256), 0, stream>>>(xbuf, Sbuf, Won, bon, hnew, Foff, Fout, Acopy);
  k_off<<<dim3(6, 16, NBATCH), dim3(256), 0, stream>>>(xbuf, Woff, boff, hnew, Foff, Fout, Acopy);
  k_tridiag_panel<<<dim3(GW, NBATCH), dim3(TPW), 0, stream>>>(Acopy, dA, subA, tauA, Wpan, cbufA, slotA, barA);
  k_bisect<<<dim3(4, NBATCH), dim3(256), 0, stream>>>(dA, subA, eig, e_out);
  k_invit<<<dim3(NOCC2, NBATCH), dim3(64), 0, stream>>>(dA, subA, eig, Utri);
  k_backxform<<<dim3(2, NBATCH), dim3(512), 0, stream>>>(Acopy, tauA, Utri, Uocc);
  k_gemmC<<<dim3(13, NBATCH), dim3(256), 0, stream>>>(hnew, Uocc, Cbuf);
  k_final<<<dim3(NBATCH), dim3(256), 0, stream>>>(eig, Uocc, Cbuf, pos, numbers, E_out);
}

// Round 6
// 52364.539 us; speedup vs baseline: 2.2217x; 1.2474x over previous
//
#include <hip/hip_runtime.h>
#include <math.h>
#include <stdint.h>

// Problem constants
#define NBATCH 16
#define NK     32
#define NTDS   768      // 3*DS
#define NMM    676      // BM*BM
#define NBM    26
#define NBB    832      // B = K*BM
#define NOCC2  128
#define NPAIR  496      // K*(K-1)/2
#define FSCALE 1.0e-4f
#define A0C    0.5291772f

// ---------------- workspace layout (in floats) ----------------
#define OFF_ACOPY 0ull
#define SZ_ACOPY  (16ull*832*832)
#define OFF_X     (OFF_ACOPY + SZ_ACOPY)
#define SZ_X      (16ull*32*768)
#define OFF_S     (OFF_X + SZ_X)
#define SZ_S      (16ull*768)
#define OFF_D     (OFF_S + SZ_S)
#define OFF_SUB   (OFF_D   + 16ull*832)
#define OFF_TAU   (OFF_SUB + 16ull*832)
#define OFF_EIG   (OFF_TAU + 16ull*832)
#define OFF_UTRI  (OFF_EIG + 16ull*832)
#define SZ_UTRI   (16ull*128*832)
#define OFF_UOCC  (OFF_UTRI + SZ_UTRI)
#define OFF_C     OFF_UTRI   /* C overlays Utri (dead after backxform) */
// tridiag scratch overlays the Utri region (Utri written only later by k_invit)
#define PB   32   // panel width
#define GW   16   // workgroups per matrix
#define TPW  512  // threads per workgroup
#define QMAX 52   // max own rows per WG (832/16)
#define SLOTSTR 1088
#define OFF_WPAN  OFF_UTRI                        /* 16*832*32 = 425,984 */
#define OFF_CBUF  (OFF_WPAN + 16ull*832*32)       /* 16*832 */
#define OFF_SLOT  (OFF_CBUF + 16ull*832)          /* 16*1088 */
#define OFF_BARC  (OFF_SLOT + 16ull*SLOTSTR)      /* 16 ints */

__device__ __forceinline__ void pair_decode(int t, int& k, int& l) {
  int kk = (int)((1.0f + sqrtf(1.0f + 8.0f*(float)t)) * 0.5f);
  while (kk*(kk-1)/2 > t) --kk;
  while ((kk+1)*kk/2 <= t) ++kk;
  k = kk; l = t - kk*(kk-1)/2;
}

// Cross-WG READ: agent-scope bypass load (sc0/sc1) — reads through to the
// MALL (memory-side, unbypassable), so it observes everything released by a
// completed buffer_wbl2, with no acquire-inv needed and no stale L1/L2 risk.
__device__ __forceinline__ float gld(const float* p) {
  unsigned int u = __hip_atomic_load((const unsigned int*)p, __ATOMIC_RELAXED, __HIP_MEMORY_SCOPE_AGENT);
  return __uint_as_float(u);
}

// ---------------- x = mu @ transfer_W + b ----------------
__global__ __launch_bounds__(256) void k_x(const float* __restrict__ mu,
                                           const float* __restrict__ tW,
                                           const float* __restrict__ tb,
                                           float* __restrict__ x) {
  const int k = blockIdx.x, n = blockIdx.y, tid = threadIdx.x;
  __shared__ float mus[384];
  const float* mub = mu + (size_t)(n*NK + k)*384;
  for (int i = tid; i < 384; i += 256) mus[i] = mub[i];
  __syncthreads();
  float* xb = x + (size_t)(n*NK + k)*NTDS;
  for (int oo = tid; oo < NTDS; oo += 256) {
    const int d = oo >> 8, i = oo & 255;
    float acc = tb[i];
    const float* mrow = &mus[d*128];
    for (int a = 0; a < 128; ++a) acc += mrow[a]*tW[a*256 + i];
    xb[oo] = acc;
  }
}

// ---------------- S[n][dd] = sum_k x[n][k][dd] ----------------
__global__ __launch_bounds__(256) void k_S(const float* __restrict__ x, float* __restrict__ S) {
  const int n = blockIdx.x, tid = threadIdx.x;
  for (int dd = tid; dd < NTDS; dd += 256) {
    float s = 0.f;
    for (int k = 0; k < NK; ++k) s += x[(size_t)(n*NK + k)*NTDS + dd];
    S[n*NTDS + dd] = s;
  }
}

// ---------------- diagonal blocks ----------------
__global__ __launch_bounds__(256) void k_diag(const float* __restrict__ x, const float* __restrict__ S,
                                              const float* __restrict__ Won, const float* __restrict__ bon,
                                              const float* __restrict__ hnew, const float* __restrict__ Foff,
                                              float* __restrict__ Fout, float* __restrict__ Acopy) {
  const int k = blockIdx.x, n = blockIdx.y, tid = threadIdx.x;
  __shared__ float q[NTDS];
  __shared__ float M[NMM];
  const float* xb = x + (size_t)(n*NK + k)*NTDS;
  const float* Sb = S + n*NTDS;
  for (int i = tid; i < NTDS; i += 256) q[i] = xb[i]*Sb[i];
  __syncthreads();
  for (int m = tid; m < NMM; m += 256) {
    float acc = 32.0f * bon[m];
    for (int dd = 0; dd < NTDS; ++dd) acc += q[dd]*Won[(size_t)dd*NMM + m];
    M[m] = acc;
  }
  __syncthreads();
  const float* hb = hnew + (size_t)n*NBB*NBB;
  float* Fb = Fout + (size_t)n*NBB*NBB;
  float* Ab = Acopy + (size_t)n*NBB*NBB;
  for (int m = tid; m < NMM; m += 256) {
    const int a = m/26, b = m - a*26;
    const float val = 0.5f*(M[m] + M[b*26 + a]);
    const int P = k*26 + a, Q = k*26 + b;
    const size_t idx = (size_t)P*NBB + Q;
    const float fo = Foff[idx];
    const float hv = hb[idx];
    const float Fv = (fabsf(hv) > 1e-7f) ? (val*FSCALE + fo) : fo;
    Fb[idx] = Fv; Ab[idx] = Fv;
  }
}

// ---------------- off-diagonal blocks: GEMM over pairs ----------------
__global__ __launch_bounds__(256) void k_off(const float* __restrict__ x,
                                             const float* __restrict__ Woff, const float* __restrict__ boff,
                                             const float* __restrict__ hnew, const float* __restrict__ Foff,
                                             float* __restrict__ Fout, float* __restrict__ Acopy) {
  const int ct = blockIdx.x, pt = blockIdx.y, n = blockIdx.z;
  const int tid = threadIdx.x;
  __shared__ __align__(16) float At[32*65];
  __shared__ __align__(16) float Bt[64*128];
  __shared__ int klk[32], kll[32];
  if (tid < 32) {
    int pr = pt*32 + tid, kk = 1, ll = 0;
    if (pr < NPAIR) pair_decode(pr, kk, ll);
    klk[tid] = kk; kll[tid] = ll;
  }
  __syncthreads();
  const int ty = tid >> 5, tx = tid & 31;
  const int r0 = ty*4, c0 = tx*4;
  float acc[4][4] = {};
  for (int dd0 = 0; dd0 < NTDS; dd0 += 64) {
    for (int idx = tid; idx < 2048; idx += 256) {
      const int r = idx >> 6, c = idx & 63;
      const int pr = pt*32 + r;
      float v = 0.f;
      if (pr < NPAIR) {
        const int kk = klk[r], ll = kll[r];
        v = x[(size_t)(n*NK + kk)*NTDS + dd0 + c] * x[(size_t)(n*NK + ll)*NTDS + dd0 + c];
      }
      At[r*65 + c] = v;
    }
    for (int idx = tid; idx < 8192; idx += 256) {
      const int r = idx >> 7, c = idx & 127;
      const int col = ct*128 + c;
      Bt[idx] = (col < NMM) ? Woff[(size_t)(dd0 + r)*NMM + col] : 0.f;
    }
    __syncthreads();
    for (int kk = 0; kk < 64; ++kk) {
      float av[4];
      av[0] = At[(r0+0)*65 + kk];
      av[1] = At[(r0+1)*65 + kk];
      av[2] = At[(r0+2)*65 + kk];
      av[3] = At[(r0+3)*65 + kk];
      const float4 b4 = *(const float4*)&Bt[kk*128 + c0];
      const float bb[4] = {b4.x, b4.y, b4.z, b4.w};
      #pragma unroll
      for (int qq = 0; qq < 4; ++qq)
        #pragma unroll
        for (int pp = 0; pp < 4; ++pp)
          acc[qq][pp] += av[qq]*bb[pp];
    }
    __syncthreads();
  }
  const float* hb = hnew + (size_t)n*NBB*NBB;
  float* Fb = Fout + (size_t)n*NBB*NBB;
  float* Ab = Acopy + (size_t)n*NBB*NBB;
  for (int qq = 0; qq < 4; ++qq) {
    const int pr = pt*32 + r0 + qq;
    if (pr >= NPAIR) continue;
    const int kk = klk[r0+qq], ll = kll[r0+qq];
    for (int pp = 0; pp < 4; ++pp) {
      const int m = ct*128 + c0 + pp;
      if (m >= NMM) continue;
      const float val = acc[qq][pp] + boff[m];
      const int a = m/26, b = m - a*26;
      const int P = kk*26 + a, Q = ll*26 + b;
      const size_t i1 = (size_t)P*NBB + Q;
      const float fo1 = Foff[i1], hv1 = hb[i1];
      const float Fv1 = (fabsf(hv1) > 1e-7f) ? (val*FSCALE + fo1) : fo1;
      Fb[i1] = Fv1; Ab[i1] = Fv1;
      const size_t i2 = (size_t)Q*NBB + P;
      const float fo2 = Foff[i2], hv2 = hb[i2];
      const float Fv2 = (fabsf(hv2) > 1e-7f) ? (val*FSCALE + fo2) : fo2;
      Fb[i2] = Fv2; Ab[i2] = Fv2;
    }
  }
}

// ================= blocked (latrd) multi-WG tridiagonalization =================
// Coherence protocol (R6):
//   * cross-WG WRITES: plain cached stores, released by a release-fetch_add on
//     the barrier counter (lowers to waitcnt + buffer_wbl2 + atomic — the same
//     proven writeback path as R3's threadfence, minus the inv).
//   * cross-WG READS: gld() agent bypass loads — read through to the MALL, so
//     no acquire-invalidate is needed anywhere.
//   * WG-own trailing-matrix rows: plain cached, NEVER invalidated -> stay
//     L2-resident across the whole 32-column panel (the R3->R6 speedup).
// Do NOT replace the release-fetch_add with a relaxed one (R4 raced -> NaN).
__device__ __forceinline__ void gbar(int* cnt, int target) {
  __syncthreads();   // all waves' stores reached L2 (vmcnt drained)
  if (threadIdx.x == 0) {
    __hip_atomic_fetch_add(cnt, 1, __ATOMIC_RELEASE, __HIP_MEMORY_SCOPE_AGENT);
    while (__hip_atomic_load(cnt, __ATOMIC_RELAXED, __HIP_MEMORY_SCOPE_AGENT) < target)
      __builtin_amdgcn_s_sleep(1);
  }
  __syncthreads();
}

__device__ __forceinline__ float wg_reduce8(float v, volatile float* sred) {
  #pragma unroll
  for (int off = 32; off > 0; off >>= 1) v += __shfl_down(v, off);
  const int tid = threadIdx.x;
  if ((tid & 63) == 0) sred[tid >> 6] = v;
  __syncthreads();
  float r = 0.f;
  #pragma unroll
  for (int t = 0; t < 8; ++t) r += sred[t];
  __syncthreads();
  return r;
}

__global__ __launch_bounds__(TPW) void k_tridiag_panel(float* __restrict__ Acopy,
                                                       float* __restrict__ dA,
                                                       float* __restrict__ subA,
                                                       float* __restrict__ tauA,
                                                       float* __restrict__ Wpan,
                                                       float* __restrict__ cbufA,
                                                       float* __restrict__ slotA,
                                                       int* __restrict__ barA) {
  const int g = blockIdx.x;          // WG within matrix
  const int n = blockIdx.y;          // matrix
  const int tid = threadIdx.x;
  const int lane = tid & 63, wv = tid >> 6;
  float* A    = Acopy + (size_t)n*NBB*NBB;
  float* Wbuf = Wpan  + (size_t)n*NBB*PB;
  float* cbuf = cbufA + (size_t)n*NBB;
  float* slot = slotA + (size_t)n*SLOTSTR;
  float* normp = slot;          // [16]
  float* vavp  = slot + 16;     // [16]
  float* alphaS= slot + 32;     // [1]
  float* ynextS= slot + 33;     // [1]
  float* d1pA  = slot + 64;     // [16][32]
  float* d2pA  = slot + 576;    // [16][32]
  int*   cnt   = barA + n;

  __shared__ float vsh[NBB];
  __shared__ float yloc[QMAX];
  __shared__ float Vloc[QMAX*33];
  __shared__ float Wloc[QMAX*33];
  __shared__ float Vt[64*33];
  __shared__ float Wt[64*33];
  __shared__ float d1s[PB], d2s[PB], Vk1s[PB], Wk1s[PB];
  __shared__ float sred[8];
  __shared__ float s_tau, s_scale, s_vav, s_ynext;
  int ep = 0;

  // ---- prologue: c = A[:,0], norm partials, alpha ----
  {
    const int q0p = (16 - g) >> 4;   // first q with 16q+g >= 1
    float np = 0.f;
    const int q = q0p + tid;
    if (q < QMAX) {
      const int j = 16*q + g;
      const float cv = A[(size_t)j*NBB];   // own row (prior kernel, dispatch-acquire coherent)
      cbuf[j] = cv;
      if (j >= 2) np = cv*cv;
      if (j == 1) alphaS[0] = cv;
    }
    const float s = wg_reduce8(np, sred);
    if (tid == 0) normp[g] = s;
  }
  ++ep; gbar(cnt, ep*GW);

  for (int k0 = 0; k0 < NBB-2; k0 += PB) {
    const int ilim = (NBB-2-k0 < PB) ? (NBB-2-k0) : PB;
    for (int i = 0; i < ilim; ++i) {
      const int k = k0 + i;
      const int m = NBB-1-k;
      const int q0 = (k + 16 - g) >> 4;   // first q with 16q+g >= k+1

      // ================= Epoch X =================
      if (tid == 0) {
        float xn2 = 0.f;
        #pragma unroll
        for (int t = 0; t < GW; ++t) xn2 += gld(&normp[t]);
        const float alpha = gld(alphaS);
        float tau, scale, beta;
        if (xn2 < 1e-26f) {
          beta = alpha; tau = 0.f; scale = 0.f;
        } else {
          beta  = -copysignf(sqrtf(alpha*alpha + xn2), alpha);
          tau   = (beta - alpha) / beta;
          scale = 1.0f / (alpha - beta);
        }
        s_tau = tau; s_scale = scale;
        if (g == 0) { subA[n*NBB + k + 1] = beta; tauA[n*NBB + k] = tau; }
      }
      __syncthreads();
      const float tau = s_tau, scale = s_scale;
      // build full v in LDS (cbuf is cross-WG -> bypass loads)
      for (int idx = tid; idx < m; idx += TPW)
        vsh[idx] = (idx == 0) ? 1.0f : gld(&cbuf[k+1+idx])*scale;
      __syncthreads();
      // store v (own entries) into row k (transposed reflector) + Vloc
      {
        const int q = q0 + tid;
        if (q < QMAX) {
          const int j = 16*q + g;
          const float val = vsh[j-(k+1)];
          A[(size_t)k*NBB + j] = val;
          Vloc[q*33 + i] = val;
        }
      }
      // d1/d2 partials over own rows (p < i)
      for (int p = wv; p < i; p += 8) {
        float a1 = 0.f, a2 = 0.f;
        const int q = q0 + lane;
        if (q < QMAX) {
          const int j = 16*q + g;
          const float vj = vsh[j-(k+1)];
          a1 = Vloc[q*33 + p]*vj;
          a2 = Wloc[q*33 + p]*vj;
        }
        #pragma unroll
        for (int off = 32; off > 0; off >>= 1) { a1 += __shfl_down(a1, off); a2 += __shfl_down(a2, off); }
        if (lane == 0) { d1pA[g*PB + p] = a1; d2pA[g*PB + p] = a2; }
      }
      // matvec y = A0 v over own rows (plain cached -> L2-resident across panel)
      float vavl = 0.f;
      for (int q = q0 + wv; q < QMAX; q += 8) {
        const int j = 16*q + g;
        const float* Ar = A + (size_t)j*NBB;
        float acc = 0.f;
        for (int c = k+1+lane; c < NBB; c += 64) acc += Ar[c]*vsh[c-(k+1)];
        #pragma unroll
        for (int off = 32; off > 0; off >>= 1) acc += __shfl_down(acc, off);
        if (lane == 0) {
          yloc[q] = acc;
          vavl += vsh[j-(k+1)]*acc;
          if (j == k+1) ynextS[0] = acc;
        }
      }
      const float vv = wg_reduce8(vavl, sred);
      if (tid == 0) vavp[g] = vv;
      ++ep; gbar(cnt, ep*GW);

      // ================= Epoch Y =================
      if (tid < i) {
        float s1 = 0.f, s2 = 0.f;
        #pragma unroll
        for (int g2 = 0; g2 < GW; ++g2) { s1 += gld(&d1pA[g2*PB + tid]); s2 += gld(&d2pA[g2*PB + tid]); }
        d1s[tid] = s1; d2s[tid] = s2;
        Vk1s[tid] = gld(&A[(size_t)(k0+tid)*NBB + (k+1)]);
        Wk1s[tid] = gld(&Wbuf[(size_t)(k+1)*PB + tid]);
      }
      if (tid == TPW-1) {
        float sv = 0.f;
        #pragma unroll
        for (int t = 0; t < GW; ++t) sv += gld(&vavp[t]);
        s_vav = sv; s_ynext = gld(ynextS);
      }
      __syncthreads();
      // redundant scalars
      float s12 = 0.f, wk1acc = 0.f;
      for (int p = 0; p < i; ++p) { s12 += d1s[p]*d2s[p]; wk1acc += Vk1s[p]*d2s[p] + Wk1s[p]*d1s[p]; }
      const float corr = 0.5f*tau*tau*(s_vav - 2.f*s12);
      const float wk1 = tau*(s_ynext - wk1acc) - corr;
      // own-row w, then c' for column k+1
      {
        const int q = q0 + tid;
        float np = 0.f;
        if (q < QMAX) {
          const int j = 16*q + g;
          float wacc = 0.f;
          for (int p = 0; p < i; ++p) wacc += Vloc[q*33 + p]*d2s[p] + Wloc[q*33 + p]*d1s[p];
          const float vj = vsh[j-(k+1)];
          const float wj = tau*(yloc[q] - wacc) - corr*vj;
          Wloc[q*33 + i] = wj;
          Wbuf[(size_t)j*PB + i] = wj;
          if (j >= k+2) {
            float cacc = 0.f;
            for (int p = 0; p < i; ++p) cacc += Vloc[q*33 + p]*Wk1s[p] + Wloc[q*33 + p]*Vk1s[p];
            cacc += vj*wk1 + wj;   // p = i term (V[k+1,i] = 1)
            const float cp = A[(size_t)j*NBB + (k+1)] - cacc;   // own row, cached
            cbuf[j] = cp;
            if (j >= k+3) np = cp*cp;
            if (j == k+2) alphaS[0] = cp;
          }
        }
        const float ns = wg_reduce8(np, sred);
        if (tid == 0) normp[g] = ns;
      }
      // diagonal extraction d[k] (own rows plain; cross-WG reflector rows bypass)
      if (g == (k & 15) && tid == 0) {
        float dk = A[(size_t)k*NBB + k];
        for (int p = 0; p < i; ++p)
          dk -= 2.f * gld(&A[(size_t)(k0+p)*NBB + k]) * Wbuf[(size_t)k*PB + p];
        dA[n*NBB + k] = dk;
      }
      ++ep; gbar(cnt, ep*GW);
    }

    // ================= syr2k: A22 -= V W^T + W V^T =================
    if (k0 + PB < NBB-2) {
      const int kp = k0 + PB;
      const int q0s = (kp + 15 - g) >> 4;   // first q with 16q+g >= kp
      for (int c0 = kp+1; c0 < NBB; c0 += 64) {
        const int nc = (NBB - c0 < 64) ? (NBB - c0) : 64;
        for (int r = 0; r < 4; ++r) {
          const int idx = r*TPW + tid;
          { const int p = idx >> 6, cc = idx & 63;
            Vt[cc*33 + p] = (cc < nc) ? gld(&A[(size_t)(k0+p)*NBB + c0 + cc]) : 0.f; }
          { const int p = idx & 31, cc = (idx >> 5) & 63;
            Wt[cc*33 + p] = (cc < nc) ? gld(&Wbuf[(size_t)(c0+cc)*PB + p]) : 0.f; }
        }
        __syncthreads();
        for (int q = q0s + wv; q < QMAX; q += 8) {
          const int j = 16*q + g;
          if (lane < nc) {
            const int c = c0 + lane;
            float acc = 0.f;
            #pragma unroll
            for (int p = 0; p < PB; ++p)
              acc += Vloc[q*33 + p]*Wt[lane*33 + p] + Wloc[q*33 + p]*Vt[lane*33 + p];
            A[(size_t)j*NBB + c] -= acc;   // own row, cached
          }
        }
        __syncthreads();
      }
      // diagonal entry [kp][kp]
      if (g == (kp & 15) && tid == 0) {
        const int qd = kp >> 4;
        float acc = 0.f;
        #pragma unroll
        for (int p = 0; p < PB; ++p) acc += Vloc[qd*33 + p]*Wloc[qd*33 + p];
        A[(size_t)kp*NBB + kp] -= 2.f*acc;
      }
      ++ep; gbar(cnt, ep*GW);
    }
  }

  // ---- epilogue (cross-WG data via bypass loads) ----
  if (g == 0 && tid == 0) {
    const int k0l = ((NBB-3)/PB)*PB;       // 800
    const int np_ = NBB-2-k0l;             // 30
    float dm2 = gld(&A[(size_t)(NBB-2)*NBB + (NBB-2)]);
    float dm1 = gld(&A[(size_t)(NBB-1)*NBB + (NBB-1)]);
    for (int p = 0; p < np_; ++p) {
      dm2 -= 2.f * gld(&A[(size_t)(k0l+p)*NBB + (NBB-2)]) * gld(&Wbuf[(size_t)(NBB-2)*PB + p]);
      dm1 -= 2.f * gld(&A[(size_t)(k0l+p)*NBB + (NBB-1)]) * gld(&Wbuf[(size_t)(NBB-1)*PB + p]);
    }
    dA[n*NBB + NBB-2] = dm2;
    dA[n*NBB + NBB-1] = dm1;
    subA[n*NBB + NBB-1] = gld(alphaS);
    subA[n*NBB + 0] = 0.f;
    tauA[n*NBB + NBB-2] = 0.f;
    tauA[n*NBB + NBB-1] = 0.f;
  }
}

// ---------------- all eigenvalues via bisection (Sturm counts) ----------------
__global__ __launch_bounds__(256) void k_bisect(const float* __restrict__ dA, const float* __restrict__ subA,
                                                float* __restrict__ eig, float* __restrict__ e_out) {
  const int n = blockIdx.y;
  const int i = blockIdx.x*256 + threadIdx.x;
  __shared__ float ds[NBB], ss[NBB];
  const float* dg = dA + n*NBB;
  const float* sg = subA + n*NBB;
  for (int j = threadIdx.x; j < NBB; j += 256) { ds[j] = dg[j]; ss[j] = sg[j]; }
  __syncthreads();
  if (i >= NBB) return;
  float lo = 1e30f, hi = -1e30f;
  for (int j = 0; j < NBB; ++j) {
    const float r = fabsf(ss[j]) + ((j+1 < NBB) ? fabsf(ss[j+1]) : 0.f);
    lo = fminf(lo, ds[j]-r); hi = fmaxf(hi, ds[j]+r);
  }
  const float pad = 1e-3f*(hi-lo) + 1e-3f;
  lo -= pad; hi += pad;
  for (int it = 0; it < 38; ++it) {
    const float mid = 0.5f*(lo+hi);
    int cnt = 0;
    float qv = ds[0]-mid;
    if (qv < 0.f) cnt++;
    for (int j = 1; j < NBB; ++j) {
      const float e = ss[j];
      if (fabsf(qv) < 1e-20f) qv = -1e-20f;
      qv = ds[j]-mid - e*e/qv;
      if (qv < 0.f) cnt++;
    }
    if (cnt > i) hi = mid; else lo = mid;
  }
  const float lam = 0.5f*(lo+hi);
  eig[n*NBB + i] = lam;
  e_out[n*NBB + i] = lam;
}

// ---------------- inverse iteration on T for the 128 lowest ----------------
__global__ __launch_bounds__(64) void k_invit(const float* __restrict__ dA, const float* __restrict__ subA,
                                              const float* __restrict__ eig, float* __restrict__ Utri) {
  const int i = blockIdx.x, n = blockIdx.y;
  const int lane = threadIdx.x;
  __shared__ float ds[NBB], ss[NBB], ud[NBB], u1[NBB], u2[NBB], yv[NBB], xv[NBB];
  const float* dg = dA + n*NBB;
  const float* sg = subA + n*NBB;
  for (int j = lane; j < NBB; j += 64) { ds[j] = dg[j]; ss[j] = sg[j]; }
  const float lam = eig[n*NBB + i];
  for (int j = lane; j < NBB; j += 64) {
    uint32_t s = (uint32_t)(j*2654435761u) ^ (uint32_t)(i*40503u + 977u) ^ (uint32_t)(n*9973u);
    s ^= s >> 16; s *= 0x7feb352dU; s ^= s >> 15; s *= 0x846ca68bU; s ^= s >> 16;
    yv[j] = 0.5f + (float)(s & 0xFFFF) * (1.0f/65536.0f);
  }
  __syncthreads();
  const float PIV = 3e-6f;
  for (int pass = 0; pass < 2; ++pass) {
    if (lane == 0) {
      float cd = ds[0] - lam;
      float cu = ss[1];
      float cy = yv[0];
      for (int j = 0; j < NBB-1; ++j) {
        const float bl = ss[j+1];
        const float bd = ds[j+1] - lam;
        const float bu = (j+2 < NBB) ? ss[j+2] : 0.f;
        const float yb = yv[j+1];
        float tud, tu1, tu2, tm, ncd, ncu, ny;
        if (fabsf(bl) > fabsf(cd)) {
          tud = bl; tu1 = bd; tu2 = bu;
          if (fabsf(tud) < PIV) tud = (tud < 0.f) ? -PIV : PIV;
          tm  = cd / tud;
          ncd = cu - tm*bd;
          ncu = -tm*bu;
          ny  = cy - tm*yb;
          yv[j] = yb;
        } else {
          tud = cd; tu1 = cu; tu2 = 0.f;
          if (fabsf(tud) < PIV) tud = (tud < 0.f) ? -PIV : PIV;
          tm  = bl / tud;
          ncd = bd - tm*cu;
          ncu = bu;
          ny  = yb - tm*cy;
          yv[j] = cy;
        }
        ud[j] = tud; u1[j] = tu1; u2[j] = tu2;
        cd = ncd; cu = ncu; cy = ny;
      }
      if (fabsf(cd) < PIV) cd = (cd < 0.f) ? -PIV : PIV;
      ud[NBB-1] = cd; u1[NBB-1] = 0.f; u2[NBB-1] = 0.f; yv[NBB-1] = cy;
      float x2 = yv[NBB-1]/ud[NBB-1];
      xv[NBB-1] = x2;
      float x1 = (yv[NBB-2] - u1[NBB-2]*x2)/ud[NBB-2];
      xv[NBB-2] = x1;
      for (int j = NBB-3; j >= 0; --j) {
        const float xj = (yv[j] - u1[j]*x1 - u2[j]*x2)/ud[j];
        xv[j] = xj;
        x2 = x1; x1 = xj;
      }
    }
    __syncthreads();
    float p2 = 0.f;
    for (int j = lane; j < NBB; j += 64) { const float t = xv[j]; p2 += t*t; }
    #pragma unroll
    for (int off = 32; off > 0; off >>= 1) p2 += __shfl_xor(p2, off);
    const float rin = rsqrtf(p2);
    if (pass == 0) {
      for (int j = lane; j < NBB; j += 64) yv[j] = xv[j]*rin;
      __syncthreads();
    } else {
      float* Ub = Utri + ((size_t)n*NOCC2 + i)*NBB;
      for (int j = lane; j < NBB; j += 64) Ub[j] = xv[j]*rin;
    }
  }
}

// ---------------- back-transform: Uocc = H0...H829 * Utri ----------------
#define RPT 104
__global__ __launch_bounds__(512, 2) void k_backxform(const float* __restrict__ Acopy,
                                                      const float* __restrict__ tauA,
                                                      const float* __restrict__ Utri,
                                                      float* __restrict__ Uocc) {
  const int cg = blockIdx.x;         // column half (0/1)
  const int n = blockIdx.y;
  const int tid = threadIdx.x;
  const int jc = tid & 63, g = tid >> 6;   // 8 row-groups x 104 rows
  const int col = cg*64 + jc;
  __shared__ float vlds[NBB];
  __shared__ float sred[8*64];
  const float* A = Acopy + (size_t)n*NBB*NBB;
  float U[RPT];
  const float* Ut = Utri + ((size_t)n*NOCC2 + col)*NBB + g*RPT;
  #pragma unroll
  for (int rr = 0; rr < RPT; ++rr) U[rr] = Ut[rr];
  const int rbase = g*RPT;
  for (int k = NBB-3; k >= 0; --k) {
    const float tau = tauA[n*NBB + k];
    if (tau == 0.f) continue;
    const int m = NBB-1-k;
    // transposed reflector storage: v lives in row k, cols k+1..
    for (int idx = tid; idx < m; idx += 512) vlds[idx] = A[(size_t)k*NBB + (k+1+idx)];
    __syncthreads();
    float part = 0.f;
    #pragma unroll
    for (int rr = 0; rr < RPT; ++rr) {
      const int r = rbase + rr;
      if (r > k) part += U[rr]*vlds[r-k-1];
    }
    sred[g*64 + jc] = part;
    __syncthreads();
    float ssum = 0.f;
    #pragma unroll
    for (int t = 0; t < 8; ++t) ssum += sred[t*64 + jc];
    const float s = tau*ssum;
    #pragma unroll
    for (int rr = 0; rr < RPT; ++rr) {
      const int r = rbase + rr;
      if (r > k) U[rr] -= s*vlds[r-k-1];
    }
    __syncthreads();
  }
  float* Ub = Uocc + (size_t)n*NBB*NOCC2;
  #pragma unroll
  for (int rr = 0; rr < RPT; ++rr) Ub[(size_t)(rbase+rr)*NOCC2 + col] = U[rr];
}

// ---------------- C = h_new * Uocc  (832x832 @ 832x128 per batch) ----------------
__global__ __launch_bounds__(256) void k_gemmC(const float* __restrict__ h,
                                               const float* __restrict__ Uocc,
                                               float* __restrict__ C) {
  const int rt = blockIdx.x, n = blockIdx.y;
  const int tid = threadIdx.x;
  __shared__ __align__(16) float hT[64*33];
  __shared__ __align__(16) float Ut[32*128];
  const int ty = tid >> 5, tx = tid & 31;
  float acc[8][4] = {};
  const float* hb = h + (size_t)n*NBB*NBB + (size_t)rt*64*NBB;
  const float* Ub = Uocc + (size_t)n*NBB*NOCC2;
  for (int k0 = 0; k0 < NBB; k0 += 32) {
    for (int idx = tid; idx < 64*32; idx += 256) {
      const int r = idx >> 5, c = idx & 31;
      hT[r*33 + c] = hb[(size_t)r*NBB + k0 + c];
    }
    for (int idx = tid; idx < 32*128; idx += 256) {
      const int r = idx >> 7, c = idx & 127;
      Ut[idx] = Ub[(size_t)(k0 + r)*NOCC2 + c];
    }
    __syncthreads();
    for (int kk = 0; kk < 32; ++kk) {
      const float4 b4 = *(const float4*)&Ut[kk*128 + tx*4];
      #pragma unroll
      for (int q = 0; q < 8; ++q) {
        const float a = hT[(ty*8 + q)*33 + kk];
        acc[q][0] += a*b4.x; acc[q][1] += a*b4.y; acc[q][2] += a*b4.z; acc[q][3] += a*b4.w;
      }
    }
    __syncthreads();
  }
  float* Cb = C + (size_t)n*NBB*NOCC2;
  #pragma unroll
  for (int q = 0; q < 8; ++q)
    #pragma unroll
    for (int p = 0; p < 4; ++p)
      Cb[(size_t)(rt*64 + ty*8 + q)*NOCC2 + tx*4 + p] = acc[q][p];
}

// ---------------- E = sum(e_occ) + Tr(Uocc^T h Uocc) + nuc ----------------
__global__ __launch_bounds__(256) void k_final(const float* __restrict__ eig,
                                               const float* __restrict__ Uocc, const float* __restrict__ C,
                                               const float* __restrict__ pos, const int* __restrict__ numbers,
                                               float* __restrict__ E_out) {
  const int n = blockIdx.x, tid = threadIdx.x;
  __shared__ float rb[256];
  float local = 0.f;
  for (int i = tid; i < NOCC2; i += 256) local += eig[n*NBB + i];
  const float* Ub = Uocc + (size_t)n*NBB*NOCC2;
  const float* Cb = C + (size_t)n*NBB*NOCC2;
  for (int idx = tid; idx < NBB*NOCC2; idx += 256) local += Ub[idx]*Cb[idx];
  float ln = 0.f;
  for (int t = tid; t < NPAIR; t += 256) {
    int kk, ll;
    pair_decode(t, kk, ll);
    const float dx = pos[(n*NK + kk)*3 + 0] - pos[(n*NK + ll)*3 + 0];
    const float dy = pos[(n*NK + kk)*3 + 1] - pos[(n*NK + ll)*3 + 1];
    const float dz = pos[(n*NK + kk)*3 + 2] - pos[(n*NK + ll)*3 + 2];
    const float d2 = dx*dx + dy*dy + dz*dz;
    const float Z = (float)(numbers[kk]*numbers[ll]);
    ln += Z / sqrtf(d2);
  }
  local += ln * A0C;
  rb[tid] = local;
  __syncthreads();
  for (int s = 128; s > 0; s >>= 1) {
    if (tid < s) rb[tid] += rb[tid + s];
    __syncthreads();
  }
  if (tid == 0) E_out[n] = rb[0];
}

extern "C" void kernel_launch(void* const* d_in, const int* in_sizes, int n_in,
                              void* d_out, int out_size, void* d_ws, size_t ws_size,
                              hipStream_t stream) {
  (void)in_sizes; (void)n_in; (void)out_size; (void)ws_size;
  const float* mu      = (const float*)d_in[0];
  const float* hnew    = (const float*)d_in[1];
  const float* pos     = (const float*)d_in[2];
  const float* Foff    = (const float*)d_in[3];
  const float* tW      = (const float*)d_in[4];
  const float* tb      = (const float*)d_in[5];
  const float* Won     = (const float*)d_in[6];
  const float* bon     = (const float*)d_in[7];
  const float* Woff    = (const float*)d_in[8];
  const float* boff    = (const float*)d_in[9];
  const int*   numbers = (const int*)d_in[10];

  float* out   = (float*)d_out;
  float* Fout  = out;                               // [16][832][832]
  float* e_out = out + (size_t)NBATCH*NBB*NBB;      // [16][832]
  float* E_out = e_out + (size_t)NBATCH*NBB;        // [16]

  float* ws    = (float*)d_ws;
  float* Acopy = ws + OFF_ACOPY;
  float* xbuf  = ws + OFF_X;
  float* Sbuf  = ws + OFF_S;
  float* dA    = ws + OFF_D;
  float* subA  = ws + OFF_SUB;
  float* tauA  = ws + OFF_TAU;
  float* eig   = ws + OFF_EIG;
  float* Utri  = ws + OFF_UTRI;
  float* Uocc  = ws + OFF_UOCC;
  float* Cbuf  = ws + OFF_C;     // overlays Utri
  float* Wpan  = ws + OFF_WPAN;  // overlays Utri (dead until k_invit)
  float* cbufA = ws + OFF_CBUF;
  float* slotA = ws + OFF_SLOT;
  int*   barA  = (int*)(ws + OFF_BARC);

  // zero the per-matrix barrier counters (graph-captured; runs every replay)
  hipMemsetAsync((void*)barA, 0, NBATCH*sizeof(int), stream);

  k_x<<<dim3(NK, NBATCH), dim3(256), 0, stream>>>(mu, tW, tb, xbuf);
  k_S<<<dim3(NBATCH), dim3(256), 0, stream>>>(xbuf, Sbuf);
  k_diag<<<dim3(NK, NBATCH), dim3(256), 0, stream>>>(xbuf, Sbuf, Won, bon, hnew, Foff, Fout, Acopy);
  k_off<<<dim3(6, 16, NBATCH), dim3(256), 0, stream>>>(xbuf, Woff, boff, hnew, Foff, Fout, Acopy);
  k_tridiag_panel<<<dim3(GW, NBATCH), dim3(TPW), 0, stream>>>(Acopy, dA, subA, tauA, Wpan, cbufA, slotA, barA);
  k_bisect<<<dim3(4, NBATCH), dim3(256), 0, stream>>>(dA, subA, eig, e_out);
  k_invit<<<dim3(NOCC2, NBATCH), dim3(64), 0, stream>>>(dA, subA, eig, Utri);
  k_backxform<<<dim3(2, NBATCH), dim3(512), 0, stream>>>(Acopy, tauA, Utri, Uocc);
  k_gemmC<<<dim3(13, NBATCH), dim3(256), 0, stream>>>(hnew, Uocc, Cbuf);
  k_final<<<dim3(NBATCH), dim3(256), 0, stream>>>(eig, Uocc, Cbuf, pos, numbers, E_out);
}

// Round 7
// 41717.276 us; speedup vs baseline: 2.7887x; 1.2552x over previous
//
#include <hip/hip_runtime.h>
#include <math.h>
#include <stdint.h>

// Problem constants
#define NBATCH 16
#define NK     32
#define NTDS   768      // 3*DS
#define NMM    676      // BM*BM
#define NBM    26
#define NBB    832      // B = K*BM
#define NOCC2  128
#define NPAIR  496      // K*(K-1)/2
#define FSCALE 1.0e-4f
#define A0C    0.5291772f

// ---------------- workspace layout (in floats) ----------------
#define OFF_ACOPY 0ull
#define SZ_ACOPY  (16ull*832*832)
#define OFF_X     (OFF_ACOPY + SZ_ACOPY)
#define SZ_X      (16ull*32*768)
#define OFF_S     (OFF_X + SZ_X)
#define SZ_S      (16ull*768)
#define OFF_D     (OFF_S + SZ_S)
#define OFF_SUB   (OFF_D   + 16ull*832)
#define OFF_TAU   (OFF_SUB + 16ull*832)
#define OFF_EIG   (OFF_TAU + 16ull*832)
#define OFF_UTRI  (OFF_EIG + 16ull*832)
#define SZ_UTRI   (16ull*128*832)
#define OFF_UOCC  (OFF_UTRI + SZ_UTRI)
#define OFF_C     OFF_UTRI   /* C overlays Utri (dead after backxform) */
// tridiag scratch overlays the Utri region (Utri written only later by k_invit)
#define PB   32   // panel width
#define GW   16   // workgroups per matrix
#define TPW  512  // threads per workgroup
#define QMAX 52   // max own rows per WG (832/16)
#define SLOTSTR 1088
#define OFF_WPAN  OFF_UTRI                        /* 16*832*32 = 425,984 */
#define OFF_CBUF  (OFF_WPAN + 16ull*832*32)       /* 16*832 */
#define OFF_SLOT  (OFF_CBUF + 16ull*832)          /* 16*1088 */
#define OFF_BARC  (OFF_SLOT + 16ull*SLOTSTR)      /* 16 ints */

__device__ __forceinline__ void pair_decode(int t, int& k, int& l) {
  int kk = (int)((1.0f + sqrtf(1.0f + 8.0f*(float)t)) * 0.5f);
  while (kk*(kk-1)/2 > t) --kk;
  while ((kk+1)*kk/2 <= t) ++kk;
  k = kk; l = t - kk*(kk-1)/2;
}

// Cross-WG READ: agent-scope bypass load (sc0 sc1) — reads through to the MALL
// (memory-side, unbypassable), so it observes completed bypass stores and
// wbl2-released cached stores with no acquire-invalidate.
__device__ __forceinline__ float gld(const float* p) {
  unsigned int u = __hip_atomic_load((const unsigned int*)p, __ATOMIC_RELAXED, __HIP_MEMORY_SCOPE_AGENT);
  return __uint_as_float(u);
}
// Cross-WG WRITE: agent-scope bypass store (sc0 sc1) — write-through to MALL.
// vmcnt retirement (drained by __syncthreads before the barrier flag bump)
// means the value is at the MALL before any other WG can observe the flag.
__device__ __forceinline__ void gst(float* p, float v) {
  __hip_atomic_store((unsigned int*)p, __float_as_uint(v), __ATOMIC_RELAXED, __HIP_MEMORY_SCOPE_AGENT);
}

// ---------------- x = mu @ transfer_W + b ----------------
__global__ __launch_bounds__(256) void k_x(const float* __restrict__ mu,
                                           const float* __restrict__ tW,
                                           const float* __restrict__ tb,
                                           float* __restrict__ x) {
  const int k = blockIdx.x, n = blockIdx.y, tid = threadIdx.x;
  __shared__ float mus[384];
  const float* mub = mu + (size_t)(n*NK + k)*384;
  for (int i = tid; i < 384; i += 256) mus[i] = mub[i];
  __syncthreads();
  float* xb = x + (size_t)(n*NK + k)*NTDS;
  for (int oo = tid; oo < NTDS; oo += 256) {
    const int d = oo >> 8, i = oo & 255;
    float acc = tb[i];
    const float* mrow = &mus[d*128];
    for (int a = 0; a < 128; ++a) acc += mrow[a]*tW[a*256 + i];
    xb[oo] = acc;
  }
}

// ---------------- S[n][dd] = sum_k x[n][k][dd] ----------------
__global__ __launch_bounds__(256) void k_S(const float* __restrict__ x, float* __restrict__ S) {
  const int n = blockIdx.x, tid = threadIdx.x;
  for (int dd = tid; dd < NTDS; dd += 256) {
    float s = 0.f;
    for (int k = 0; k < NK; ++k) s += x[(size_t)(n*NK + k)*NTDS + dd];
    S[n*NTDS + dd] = s;
  }
}

// ---------------- diagonal blocks ----------------
__global__ __launch_bounds__(256) void k_diag(const float* __restrict__ x, const float* __restrict__ S,
                                              const float* __restrict__ Won, const float* __restrict__ bon,
                                              const float* __restrict__ hnew, const float* __restrict__ Foff,
                                              float* __restrict__ Fout, float* __restrict__ Acopy) {
  const int k = blockIdx.x, n = blockIdx.y, tid = threadIdx.x;
  __shared__ float q[NTDS];
  __shared__ float M[NMM];
  const float* xb = x + (size_t)(n*NK + k)*NTDS;
  const float* Sb = S + n*NTDS;
  for (int i = tid; i < NTDS; i += 256) q[i] = xb[i]*Sb[i];
  __syncthreads();
  for (int m = tid; m < NMM; m += 256) {
    float acc = 32.0f * bon[m];
    for (int dd = 0; dd < NTDS; ++dd) acc += q[dd]*Won[(size_t)dd*NMM + m];
    M[m] = acc;
  }
  __syncthreads();
  const float* hb = hnew + (size_t)n*NBB*NBB;
  float* Fb = Fout + (size_t)n*NBB*NBB;
  float* Ab = Acopy + (size_t)n*NBB*NBB;
  for (int m = tid; m < NMM; m += 256) {
    const int a = m/26, b = m - a*26;
    const float val = 0.5f*(M[m] + M[b*26 + a]);
    const int P = k*26 + a, Q = k*26 + b;
    const size_t idx = (size_t)P*NBB + Q;
    const float fo = Foff[idx];
    const float hv = hb[idx];
    const float Fv = (fabsf(hv) > 1e-7f) ? (val*FSCALE + fo) : fo;
    Fb[idx] = Fv; Ab[idx] = Fv;
  }
}

// ---------------- off-diagonal blocks: GEMM over pairs ----------------
__global__ __launch_bounds__(256) void k_off(const float* __restrict__ x,
                                             const float* __restrict__ Woff, const float* __restrict__ boff,
                                             const float* __restrict__ hnew, const float* __restrict__ Foff,
                                             float* __restrict__ Fout, float* __restrict__ Acopy) {
  const int ct = blockIdx.x, pt = blockIdx.y, n = blockIdx.z;
  const int tid = threadIdx.x;
  __shared__ __align__(16) float At[32*65];
  __shared__ __align__(16) float Bt[64*128];
  __shared__ int klk[32], kll[32];
  if (tid < 32) {
    int pr = pt*32 + tid, kk = 1, ll = 0;
    if (pr < NPAIR) pair_decode(pr, kk, ll);
    klk[tid] = kk; kll[tid] = ll;
  }
  __syncthreads();
  const int ty = tid >> 5, tx = tid & 31;
  const int r0 = ty*4, c0 = tx*4;
  float acc[4][4] = {};
  for (int dd0 = 0; dd0 < NTDS; dd0 += 64) {
    for (int idx = tid; idx < 2048; idx += 256) {
      const int r = idx >> 6, c = idx & 63;
      const int pr = pt*32 + r;
      float v = 0.f;
      if (pr < NPAIR) {
        const int kk = klk[r], ll = kll[r];
        v = x[(size_t)(n*NK + kk)*NTDS + dd0 + c] * x[(size_t)(n*NK + ll)*NTDS + dd0 + c];
      }
      At[r*65 + c] = v;
    }
    for (int idx = tid; idx < 8192; idx += 256) {
      const int r = idx >> 7, c = idx & 127;
      const int col = ct*128 + c;
      Bt[idx] = (col < NMM) ? Woff[(size_t)(dd0 + r)*NMM + col] : 0.f;
    }
    __syncthreads();
    for (int kk = 0; kk < 64; ++kk) {
      float av[4];
      av[0] = At[(r0+0)*65 + kk];
      av[1] = At[(r0+1)*65 + kk];
      av[2] = At[(r0+2)*65 + kk];
      av[3] = At[(r0+3)*65 + kk];
      const float4 b4 = *(const float4*)&Bt[kk*128 + c0];
      const float bb[4] = {b4.x, b4.y, b4.z, b4.w};
      #pragma unroll
      for (int qq = 0; qq < 4; ++qq)
        #pragma unroll
        for (int pp = 0; pp < 4; ++pp)
          acc[qq][pp] += av[qq]*bb[pp];
    }
    __syncthreads();
  }
  const float* hb = hnew + (size_t)n*NBB*NBB;
  float* Fb = Fout + (size_t)n*NBB*NBB;
  float* Ab = Acopy + (size_t)n*NBB*NBB;
  for (int qq = 0; qq < 4; ++qq) {
    const int pr = pt*32 + r0 + qq;
    if (pr >= NPAIR) continue;
    const int kk = klk[r0+qq], ll = kll[r0+qq];
    for (int pp = 0; pp < 4; ++pp) {
      const int m = ct*128 + c0 + pp;
      if (m >= NMM) continue;
      const float val = acc[qq][pp] + boff[m];
      const int a = m/26, b = m - a*26;
      const int P = kk*26 + a, Q = ll*26 + b;
      const size_t i1 = (size_t)P*NBB + Q;
      const float fo1 = Foff[i1], hv1 = hb[i1];
      const float Fv1 = (fabsf(hv1) > 1e-7f) ? (val*FSCALE + fo1) : fo1;
      Fb[i1] = Fv1; Ab[i1] = Fv1;
      const size_t i2 = (size_t)Q*NBB + P;
      const float fo2 = Foff[i2], hv2 = hb[i2];
      const float Fv2 = (fabsf(hv2) > 1e-7f) ? (val*FSCALE + fo2) : fo2;
      Fb[i2] = Fv2; Ab[i2] = Fv2;
    }
  }
}

// ================= blocked (latrd) multi-WG tridiagonalization =================
// Coherence protocol (R7):
//   * ALL cross-WG-communicated data (cbuf, Wbuf, slots, reflector entries in
//     A's upper triangle) is written ONLY via gst (bypass, write-through to
//     MALL) and read ONLY via gld (bypass). No cached copy of these lines is
//     ever dirty anywhere.
//   * Trailing-matrix rows are WG-private: plain cached reads (L2-resident
//     within a panel); plain cached writes ONLY in syr2k.
//   * Column barriers are RELAXED (no wbl2): __syncthreads drains vmcnt, so
//     all bypass stores are MALL-complete before the flag bump.
//   * Panel-boundary barriers (after syr2k) are RELEASE (wbl2): they clean the
//     syr2k-dirtied rows BEFORE the next panel gst-writes reflectors into
//     them. R4's NaN was exactly this clobber (dirty cached lines evicted over
//     gst-written reflector data because nothing ever flushed them).
__device__ __forceinline__ void rbar(int* cnt, int target) {
  __syncthreads();   // emits s_waitcnt vmcnt(0) before s_barrier: bypass stores MALL-complete
  if (threadIdx.x == 0) {
    asm volatile("" ::: "memory");
    __hip_atomic_fetch_add(cnt, 1, __ATOMIC_RELAXED, __HIP_MEMORY_SCOPE_AGENT);
    while (__hip_atomic_load(cnt, __ATOMIC_RELAXED, __HIP_MEMORY_SCOPE_AGENT) < target)
      __builtin_amdgcn_s_sleep(1);
    asm volatile("" ::: "memory");
  }
  __syncthreads();
}
__device__ __forceinline__ void gbar(int* cnt, int target) {
  __syncthreads();
  if (threadIdx.x == 0) {
    __hip_atomic_fetch_add(cnt, 1, __ATOMIC_RELEASE, __HIP_MEMORY_SCOPE_AGENT);  // wbl2
    while (__hip_atomic_load(cnt, __ATOMIC_RELAXED, __HIP_MEMORY_SCOPE_AGENT) < target)
      __builtin_amdgcn_s_sleep(1);
  }
  __syncthreads();
}

__device__ __forceinline__ float wg_reduce8(float v, volatile float* sred) {
  #pragma unroll
  for (int off = 32; off > 0; off >>= 1) v += __shfl_down(v, off);
  const int tid = threadIdx.x;
  if ((tid & 63) == 0) sred[tid >> 6] = v;
  __syncthreads();
  float r = 0.f;
  #pragma unroll
  for (int t = 0; t < 8; ++t) r += sred[t];
  __syncthreads();
  return r;
}

__global__ __launch_bounds__(TPW) void k_tridiag_panel(float* __restrict__ Acopy,
                                                       float* __restrict__ dA,
                                                       float* __restrict__ subA,
                                                       float* __restrict__ tauA,
                                                       float* __restrict__ Wpan,
                                                       float* __restrict__ cbufA,
                                                       float* __restrict__ slotA,
                                                       int* __restrict__ barA) {
  const int g = blockIdx.x;          // WG within matrix
  const int n = blockIdx.y;          // matrix
  const int tid = threadIdx.x;
  const int lane = tid & 63, wv = tid >> 6;
  float* A    = Acopy + (size_t)n*NBB*NBB;
  float* Wbuf = Wpan  + (size_t)n*NBB*PB;
  float* cbuf = cbufA + (size_t)n*NBB;
  float* slot = slotA + (size_t)n*SLOTSTR;
  float* normp = slot;          // [16]
  float* vavp  = slot + 16;     // [16]
  float* alphaS= slot + 32;     // [1]
  float* ynextS= slot + 33;     // [1]
  float* d1pA  = slot + 64;     // [16][32]
  float* d2pA  = slot + 576;    // [16][32]
  int*   cnt   = barA + n;

  __shared__ float vsh[NBB];
  __shared__ float yloc[QMAX];
  __shared__ float Vloc[QMAX*33];
  __shared__ float Wloc[QMAX*33];
  __shared__ float Vt[64*33];
  __shared__ float Wt[64*33];
  __shared__ float d1s[PB], d2s[PB], Vk1s[PB], Wk1s[PB];
  __shared__ float sred[8];
  __shared__ float s_tau, s_scale, s_vav, s_ynext;
  int ep = 0;

  // ---- prologue: c = A[:,0], norm partials, alpha (all comms via gst) ----
  {
    const int q0p = (16 - g) >> 4;   // first q with 16q+g >= 1
    float np = 0.f;
    const int q = q0p + tid;
    if (q < QMAX) {
      const int j = 16*q + g;
      const float cv = A[(size_t)j*NBB];   // own row (prior kernel, dispatch-coherent)
      gst(&cbuf[j], cv);
      if (j >= 2) np = cv*cv;
      if (j == 1) gst(alphaS, cv);
    }
    const float s = wg_reduce8(np, sred);
    if (tid == 0) gst(&normp[g], s);
  }
  ++ep; gbar(cnt, ep*GW);

  for (int k0 = 0; k0 < NBB-2; k0 += PB) {
    const int ilim = (NBB-2-k0 < PB) ? (NBB-2-k0) : PB;
    for (int i = 0; i < ilim; ++i) {
      const int k = k0 + i;
      const int m = NBB-1-k;
      const int q0 = (k + 16 - g) >> 4;   // first q with 16q+g >= k+1

      // ================= Epoch X =================
      if (tid == 0) {
        float xn2 = 0.f;
        #pragma unroll
        for (int t = 0; t < GW; ++t) xn2 += gld(&normp[t]);
        const float alpha = gld(alphaS);
        float tau, scale, beta;
        if (xn2 < 1e-26f) {
          beta = alpha; tau = 0.f; scale = 0.f;
        } else {
          beta  = -copysignf(sqrtf(alpha*alpha + xn2), alpha);
          tau   = (beta - alpha) / beta;
          scale = 1.0f / (alpha - beta);
        }
        s_tau = tau; s_scale = scale;
        if (g == 0) { subA[n*NBB + k + 1] = beta; tauA[n*NBB + k] = tau; }
      }
      __syncthreads();
      const float tau = s_tau, scale = s_scale;
      // build full v in LDS (cbuf is cross-WG -> bypass loads)
      for (int idx = tid; idx < m; idx += TPW)
        vsh[idx] = (idx == 0) ? 1.0f : gld(&cbuf[k+1+idx])*scale;
      __syncthreads();
      // store v (own entries) into row k (transposed reflector, BYPASS) + Vloc
      {
        const int q = q0 + tid;
        if (q < QMAX) {
          const int j = 16*q + g;
          const float val = vsh[j-(k+1)];
          gst(&A[(size_t)k*NBB + j], val);
          Vloc[q*33 + i] = val;
        }
      }
      // d1/d2 partials over own rows (p < i)
      for (int p = wv; p < i; p += 8) {
        float a1 = 0.f, a2 = 0.f;
        const int q = q0 + lane;
        if (q < QMAX) {
          const int j = 16*q + g;
          const float vj = vsh[j-(k+1)];
          a1 = Vloc[q*33 + p]*vj;
          a2 = Wloc[q*33 + p]*vj;
        }
        #pragma unroll
        for (int off = 32; off > 0; off >>= 1) { a1 += __shfl_down(a1, off); a2 += __shfl_down(a2, off); }
        if (lane == 0) { gst(&d1pA[g*PB + p], a1); gst(&d2pA[g*PB + p], a2); }
      }
      // matvec y = A0 v over own rows (plain cached, clean -> L2-resident)
      float vavl = 0.f;
      for (int q = q0 + wv; q < QMAX; q += 8) {
        const int j = 16*q + g;
        const float* Ar = A + (size_t)j*NBB;
        float acc = 0.f;
        for (int c = k+1+lane; c < NBB; c += 64) acc += Ar[c]*vsh[c-(k+1)];
        #pragma unroll
        for (int off = 32; off > 0; off >>= 1) acc += __shfl_down(acc, off);
        if (lane == 0) {
          yloc[q] = acc;
          vavl += vsh[j-(k+1)]*acc;
          if (j == k+1) gst(ynextS, acc);
        }
      }
      const float vv = wg_reduce8(vavl, sred);
      if (tid == 0) gst(&vavp[g], vv);
      ++ep; rbar(cnt, ep*GW);

      // ================= Epoch Y =================
      if (tid < i) {
        float s1 = 0.f, s2 = 0.f;
        #pragma unroll
        for (int g2 = 0; g2 < GW; ++g2) { s1 += gld(&d1pA[g2*PB + tid]); s2 += gld(&d2pA[g2*PB + tid]); }
        d1s[tid] = s1; d2s[tid] = s2;
        Vk1s[tid] = gld(&A[(size_t)(k0+tid)*NBB + (k+1)]);
        Wk1s[tid] = gld(&Wbuf[(size_t)(k+1)*PB + tid]);
      }
      if (tid == TPW-1) {
        float sv = 0.f;
        #pragma unroll
        for (int t = 0; t < GW; ++t) sv += gld(&vavp[t]);
        s_vav = sv; s_ynext = gld(ynextS);
      }
      __syncthreads();
      // redundant scalars
      float s12 = 0.f, wk1acc = 0.f;
      for (int p = 0; p < i; ++p) { s12 += d1s[p]*d2s[p]; wk1acc += Vk1s[p]*d2s[p] + Wk1s[p]*d1s[p]; }
      const float corr = 0.5f*tau*tau*(s_vav - 2.f*s12);
      const float wk1 = tau*(s_ynext - wk1acc) - corr;
      // own-row w, then c' for column k+1
      {
        const int q = q0 + tid;
        float np = 0.f;
        if (q < QMAX) {
          const int j = 16*q + g;
          float wacc = 0.f;
          for (int p = 0; p < i; ++p) wacc += Vloc[q*33 + p]*d2s[p] + Wloc[q*33 + p]*d1s[p];
          const float vj = vsh[j-(k+1)];
          const float wj = tau*(yloc[q] - wacc) - corr*vj;
          Wloc[q*33 + i] = wj;
          gst(&Wbuf[(size_t)j*PB + i], wj);
          if (j >= k+2) {
            float cacc = 0.f;
            for (int p = 0; p < i; ++p) cacc += Vloc[q*33 + p]*Wk1s[p] + Wloc[q*33 + p]*Vk1s[p];
            cacc += vj*wk1 + wj;   // p = i term (V[k+1,i] = 1)
            const float cp = A[(size_t)j*NBB + (k+1)] - cacc;   // own row, clean cached
            gst(&cbuf[j], cp);
            if (j >= k+3) np = cp*cp;
            if (j == k+2) gst(alphaS, cp);
          }
        }
        const float ns = wg_reduce8(np, sred);
        if (tid == 0) gst(&normp[g], ns);
      }
      // diagonal extraction d[k] (own row plain; cross-WG data via bypass)
      if (g == (k & 15) && tid == 0) {
        float dk = A[(size_t)k*NBB + k];
        for (int p = 0; p < i; ++p)
          dk -= 2.f * gld(&A[(size_t)(k0+p)*NBB + k]) * gld(&Wbuf[(size_t)k*PB + p]);
        dA[n*NBB + k] = dk;
      }
      ++ep; rbar(cnt, ep*GW);
    }

    // ================= syr2k: A22 -= V W^T + W V^T =================
    if (k0 + PB < NBB-2) {
      const int kp = k0 + PB;
      const int q0s = (kp + 15 - g) >> 4;   // first q with 16q+g >= kp
      for (int c0 = kp+1; c0 < NBB; c0 += 64) {
        const int nc = (NBB - c0 < 64) ? (NBB - c0) : 64;
        for (int r = 0; r < 4; ++r) {
          const int idx = r*TPW + tid;
          { const int p = idx >> 6, cc = idx & 63;
            Vt[cc*33 + p] = (cc < nc) ? gld(&A[(size_t)(k0+p)*NBB + c0 + cc]) : 0.f; }
          { const int p = idx & 31, cc = (idx >> 5) & 63;
            Wt[cc*33 + p] = (cc < nc) ? gld(&Wbuf[(size_t)(c0+cc)*PB + p]) : 0.f; }
        }
        __syncthreads();
        for (int q = q0s + wv; q < QMAX; q += 8) {
          const int j = 16*q + g;
          if (lane < nc) {
            const int c = c0 + lane;
            float acc = 0.f;
            #pragma unroll
            for (int p = 0; p < PB; ++p)
              acc += Vloc[q*33 + p]*Wt[lane*33 + p] + Wloc[q*33 + p]*Vt[lane*33 + p];
            A[(size_t)j*NBB + c] -= acc;   // own row, cached (dirtied; cleaned below)
          }
        }
        __syncthreads();
      }
      // diagonal entry [kp][kp]
      if (g == (kp & 15) && tid == 0) {
        const int qd = kp >> 4;
        float acc = 0.f;
        #pragma unroll
        for (int p = 0; p < PB; ++p) acc += Vloc[qd*33 + p]*Wloc[qd*33 + p];
        A[(size_t)kp*NBB + kp] -= 2.f*acc;
      }
      ++ep; gbar(cnt, ep*GW);   // RELEASE: clean syr2k dirt before next panel's gst reflectors
    }
  }

  // ---- epilogue (cross-WG data via bypass loads) ----
  if (g == 0 && tid == 0) {
    const int k0l = ((NBB-3)/PB)*PB;       // 800
    const int np_ = NBB-2-k0l;             // 30
    float dm2 = gld(&A[(size_t)(NBB-2)*NBB + (NBB-2)]);
    float dm1 = gld(&A[(size_t)(NBB-1)*NBB + (NBB-1)]);
    for (int p = 0; p < np_; ++p) {
      dm2 -= 2.f * gld(&A[(size_t)(k0l+p)*NBB + (NBB-2)]) * gld(&Wbuf[(size_t)(NBB-2)*PB + p]);
      dm1 -= 2.f * gld(&A[(size_t)(k0l+p)*NBB + (NBB-1)]) * gld(&Wbuf[(size_t)(NBB-1)*PB + p]);
    }
    dA[n*NBB + NBB-2] = dm2;
    dA[n*NBB + NBB-1] = dm1;
    subA[n*NBB + NBB-1] = gld(alphaS);
    subA[n*NBB + 0] = 0.f;
    tauA[n*NBB + NBB-2] = 0.f;
    tauA[n*NBB + NBB-1] = 0.f;
  }
}

// ---------------- all eigenvalues via bisection (Sturm counts) ----------------
__global__ __launch_bounds__(256) void k_bisect(const float* __restrict__ dA, const float* __restrict__ subA,
                                                float* __restrict__ eig, float* __restrict__ e_out) {
  const int n = blockIdx.y;
  const int i = blockIdx.x*256 + threadIdx.x;
  __shared__ float ds[NBB], ss[NBB];
  const float* dg = dA + n*NBB;
  const float* sg = subA + n*NBB;
  for (int j = threadIdx.x; j < NBB; j += 256) { ds[j] = dg[j]; ss[j] = sg[j]; }
  __syncthreads();
  if (i >= NBB) return;
  float lo = 1e30f, hi = -1e30f;
  for (int j = 0; j < NBB; ++j) {
    const float r = fabsf(ss[j]) + ((j+1 < NBB) ? fabsf(ss[j+1]) : 0.f);
    lo = fminf(lo, ds[j]-r); hi = fmaxf(hi, ds[j]+r);
  }
  const float pad = 1e-3f*(hi-lo) + 1e-3f;
  lo -= pad; hi += pad;
  for (int it = 0; it < 38; ++it) {
    const float mid = 0.5f*(lo+hi);
    int cnt = 0;
    float qv = ds[0]-mid;
    if (qv < 0.f) cnt++;
    for (int j = 1; j < NBB; ++j) {
      const float e = ss[j];
      if (fabsf(qv) < 1e-20f) qv = -1e-20f;
      qv = ds[j]-mid - e*e/qv;
      if (qv < 0.f) cnt++;
    }
    if (cnt > i) hi = mid; else lo = mid;
  }
  const float lam = 0.5f*(lo+hi);
  eig[n*NBB + i] = lam;
  e_out[n*NBB + i] = lam;
}

// ---------------- inverse iteration on T for the 128 lowest ----------------
__global__ __launch_bounds__(64) void k_invit(const float* __restrict__ dA, const float* __restrict__ subA,
                                              const float* __restrict__ eig, float* __restrict__ Utri) {
  const int i = blockIdx.x, n = blockIdx.y;
  const int lane = threadIdx.x;
  __shared__ float ds[NBB], ss[NBB], ud[NBB], u1[NBB], u2[NBB], yv[NBB], xv[NBB];
  const float* dg = dA + n*NBB;
  const float* sg = subA + n*NBB;
  for (int j = lane; j < NBB; j += 64) { ds[j] = dg[j]; ss[j] = sg[j]; }
  const float lam = eig[n*NBB + i];
  for (int j = lane; j < NBB; j += 64) {
    uint32_t s = (uint32_t)(j*2654435761u) ^ (uint32_t)(i*40503u + 977u) ^ (uint32_t)(n*9973u);
    s ^= s >> 16; s *= 0x7feb352dU; s ^= s >> 15; s *= 0x846ca68bU; s ^= s >> 16;
    yv[j] = 0.5f + (float)(s & 0xFFFF) * (1.0f/65536.0f);
  }
  __syncthreads();
  const float PIV = 3e-6f;
  for (int pass = 0; pass < 2; ++pass) {
    if (lane == 0) {
      float cd = ds[0] - lam;
      float cu = ss[1];
      float cy = yv[0];
      for (int j = 0; j < NBB-1; ++j) {
        const float bl = ss[j+1];
        const float bd = ds[j+1] - lam;
        const float bu = (j+2 < NBB) ? ss[j+2] : 0.f;
        const float yb = yv[j+1];
        float tud, tu1, tu2, tm, ncd, ncu, ny;
        if (fabsf(bl) > fabsf(cd)) {
          tud = bl; tu1 = bd; tu2 = bu;
          if (fabsf(tud) < PIV) tud = (tud < 0.f) ? -PIV : PIV;
          tm  = cd / tud;
          ncd = cu - tm*bd;
          ncu = -tm*bu;
          ny  = cy - tm*yb;
          yv[j] = yb;
        } else {
          tud = cd; tu1 = cu; tu2 = 0.f;
          if (fabsf(tud) < PIV) tud = (tud < 0.f) ? -PIV : PIV;
          tm  = bl / tud;
          ncd = bd - tm*cu;
          ncu = bu;
          ny  = yb - tm*cy;
          yv[j] = cy;
        }
        ud[j] = tud; u1[j] = tu1; u2[j] = tu2;
        cd = ncd; cu = ncu; cy = ny;
      }
      if (fabsf(cd) < PIV) cd = (cd < 0.f) ? -PIV : PIV;
      ud[NBB-1] = cd; u1[NBB-1] = 0.f; u2[NBB-1] = 0.f; yv[NBB-1] = cy;
      float x2 = yv[NBB-1]/ud[NBB-1];
      xv[NBB-1] = x2;
      float x1 = (yv[NBB-2] - u1[NBB-2]*x2)/ud[NBB-2];
      xv[NBB-2] = x1;
      for (int j = NBB-3; j >= 0; --j) {
        const float xj = (yv[j] - u1[j]*x1 - u2[j]*x2)/ud[j];
        xv[j] = xj;
        x2 = x1; x1 = xj;
      }
    }
    __syncthreads();
    float p2 = 0.f;
    for (int j = lane; j < NBB; j += 64) { const float t = xv[j]; p2 += t*t; }
    #pragma unroll
    for (int off = 32; off > 0; off >>= 1) p2 += __shfl_xor(p2, off);
    const float rin = rsqrtf(p2);
    if (pass == 0) {
      for (int j = lane; j < NBB; j += 64) yv[j] = xv[j]*rin;
      __syncthreads();
    } else {
      float* Ub = Utri + ((size_t)n*NOCC2 + i)*NBB;
      for (int j = lane; j < NBB; j += 64) Ub[j] = xv[j]*rin;
    }
  }
}

// ---------------- back-transform: Uocc = H0...H829 * Utri ----------------
#define RPT 104
__global__ __launch_bounds__(512, 2) void k_backxform(const float* __restrict__ Acopy,
                                                      const float* __restrict__ tauA,
                                                      const float* __restrict__ Utri,
                                                      float* __restrict__ Uocc) {
  const int cg = blockIdx.x;         // column half (0/1)
  const int n = blockIdx.y;
  const int tid = threadIdx.x;
  const int jc = tid & 63, g = tid >> 6;   // 8 row-groups x 104 rows
  const int col = cg*64 + jc;
  __shared__ float vlds[NBB];
  __shared__ float sred[8*64];
  const float* A = Acopy + (size_t)n*NBB*NBB;
  float U[RPT];
  const float* Ut = Utri + ((size_t)n*NOCC2 + col)*NBB + g*RPT;
  #pragma unroll
  for (int rr = 0; rr < RPT; ++rr) U[rr] = Ut[rr];
  const int rbase = g*RPT;
  for (int k = NBB-3; k >= 0; --k) {
    const float tau = tauA[n*NBB + k];
    if (tau == 0.f) continue;
    const int m = NBB-1-k;
    // transposed reflector storage: v lives in row k, cols k+1..
    for (int idx = tid; idx < m; idx += 512) vlds[idx] = A[(size_t)k*NBB + (k+1+idx)];
    __syncthreads();
    float part = 0.f;
    #pragma unroll
    for (int rr = 0; rr < RPT; ++rr) {
      const int r = rbase + rr;
      if (r > k) part += U[rr]*vlds[r-k-1];
    }
    sred[g*64 + jc] = part;
    __syncthreads();
    float ssum = 0.f;
    #pragma unroll
    for (int t = 0; t < 8; ++t) ssum += sred[t*64 + jc];
    const float s = tau*ssum;
    #pragma unroll
    for (int rr = 0; rr < RPT; ++rr) {
      const int r = rbase + rr;
      if (r > k) U[rr] -= s*vlds[r-k-1];
    }
    __syncthreads();
  }
  float* Ub = Uocc + (size_t)n*NBB*NOCC2;
  #pragma unroll
  for (int rr = 0; rr < RPT; ++rr) Ub[(size_t)(rbase+rr)*NOCC2 + col] = U[rr];
}

// ---------------- C = h_new * Uocc  (832x832 @ 832x128 per batch) ----------------
__global__ __launch_bounds__(256) void k_gemmC(const float* __restrict__ h,
                                               const float* __restrict__ Uocc,
                                               float* __restrict__ C) {
  const int rt = blockIdx.x, n = blockIdx.y;
  const int tid = threadIdx.x;
  __shared__ __align__(16) float hT[64*33];
  __shared__ __align__(16) float Ut[32*128];
  const int ty = tid >> 5, tx = tid & 31;
  float acc[8][4] = {};
  const float* hb = h + (size_t)n*NBB*NBB + (size_t)rt*64*NBB;
  const float* Ub = Uocc + (size_t)n*NBB*NOCC2;
  for (int k0 = 0; k0 < NBB; k0 += 32) {
    for (int idx = tid; idx < 64*32; idx += 256) {
      const int r = idx >> 5, c = idx & 31;
      hT[r*33 + c] = hb[(size_t)r*NBB + k0 + c];
    }
    for (int idx = tid; idx < 32*128; idx += 256) {
      const int r = idx >> 7, c = idx & 127;
      Ut[idx] = Ub[(size_t)(k0 + r)*NOCC2 + c];
    }
    __syncthreads();
    for (int kk = 0; kk < 32; ++kk) {
      const float4 b4 = *(const float4*)&Ut[kk*128 + tx*4];
      #pragma unroll
      for (int q = 0; q < 8; ++q) {
        const float a = hT[(ty*8 + q)*33 + kk];
        acc[q][0] += a*b4.x; acc[q][1] += a*b4.y; acc[q][2] += a*b4.z; acc[q][3] += a*b4.w;
      }
    }
    __syncthreads();
  }
  float* Cb = C + (size_t)n*NBB*NOCC2;
  #pragma unroll
  for (int q = 0; q < 8; ++q)
    #pragma unroll
    for (int p = 0; p < 4; ++p)
      Cb[(size_t)(rt*64 + ty*8 + q)*NOCC2 + tx*4 + p] = acc[q][p];
}

// ---------------- E = sum(e_occ) + Tr(Uocc^T h Uocc) + nuc ----------------
__global__ __launch_bounds__(256) void k_final(const float* __restrict__ eig,
                                               const float* __restrict__ Uocc, const float* __restrict__ C,
                                               const float* __restrict__ pos, const int* __restrict__ numbers,
                                               float* __restrict__ E_out) {
  const int n = blockIdx.x, tid = threadIdx.x;
  __shared__ float rb[256];
  float local = 0.f;
  for (int i = tid; i < NOCC2; i += 256) local += eig[n*NBB + i];
  const float* Ub = Uocc + (size_t)n*NBB*NOCC2;
  const float* Cb = C + (size_t)n*NBB*NOCC2;
  for (int idx = tid; idx < NBB*NOCC2; idx += 256) local += Ub[idx]*Cb[idx];
  float ln = 0.f;
  for (int t = tid; t < NPAIR; t += 256) {
    int kk, ll;
    pair_decode(t, kk, ll);
    const float dx = pos[(n*NK + kk)*3 + 0] - pos[(n*NK + ll)*3 + 0];
    const float dy = pos[(n*NK + kk)*3 + 1] - pos[(n*NK + ll)*3 + 1];
    const float dz = pos[(n*NK + kk)*3 + 2] - pos[(n*NK + ll)*3 + 2];
    const float d2 = dx*dx + dy*dy + dz*dz;
    const float Z = (float)(numbers[kk]*numbers[ll]);
    ln += Z / sqrtf(d2);
  }
  local += ln * A0C;
  rb[tid] = local;
  __syncthreads();
  for (int s = 128; s > 0; s >>= 1) {
    if (tid < s) rb[tid] += rb[tid + s];
    __syncthreads();
  }
  if (tid == 0) E_out[n] = rb[0];
}

extern "C" void kernel_launch(void* const* d_in, const int* in_sizes, int n_in,
                              void* d_out, int out_size, void* d_ws, size_t ws_size,
                              hipStream_t stream) {
  (void)in_sizes; (void)n_in; (void)out_size; (void)ws_size;
  const float* mu      = (const float*)d_in[0];
  const float* hnew    = (const float*)d_in[1];
  const float* pos     = (const float*)d_in[2];
  const float* Foff    = (const float*)d_in[3];
  const float* tW      = (const float*)d_in[4];
  const float* tb      = (const float*)d_in[5];
  const float* Won     = (const float*)d_in[6];
  const float* bon     = (const float*)d_in[7];
  const float* Woff    = (const float*)d_in[8];
  const float* boff    = (const float*)d_in[9];
  const int*   numbers = (const int*)d_in[10];

  float* out   = (float*)d_out;
  float* Fout  = out;                               // [16][832][832]
  float* e_out = out + (size_t)NBATCH*NBB*NBB;      // [16][832]
  float* E_out = e_out + (size_t)NBATCH*NBB;        // [16]

  float* ws    = (float*)d_ws;
  float* Acopy = ws + OFF_ACOPY;
  float* xbuf  = ws + OFF_X;
  float* Sbuf  = ws + OFF_S;
  float* dA    = ws + OFF_D;
  float* subA  = ws + OFF_SUB;
  float* tauA  = ws + OFF_TAU;
  float* eig   = ws + OFF_EIG;
  float* Utri  = ws + OFF_UTRI;
  float* Uocc  = ws + OFF_UOCC;
  float* Cbuf  = ws + OFF_C;     // overlays Utri
  float* Wpan  = ws + OFF_WPAN;  // overlays Utri (dead until k_invit)
  float* cbufA = ws + OFF_CBUF;
  float* slotA = ws + OFF_SLOT;
  int*   barA  = (int*)(ws + OFF_BARC);

  // zero the per-matrix barrier counters (graph-captured; runs every replay)
  hipMemsetAsync((void*)barA, 0, NBATCH*sizeof(int), stream);

  k_x<<<dim3(NK, NBATCH), dim3(256), 0, stream>>>(mu, tW, tb, xbuf);
  k_S<<<dim3(NBATCH), dim3(256), 0, stream>>>(xbuf, Sbuf);
  k_diag<<<dim3(NK, NBATCH), dim3(256), 0, stream>>>(xbuf, Sbuf, Won, bon, hnew, Foff, Fout, Acopy);
  k_off<<<dim3(6, 16, NBATCH), dim3(256), 0, stream>>>(xbuf, Woff, boff, hnew, Foff, Fout, Acopy);
  k_tridiag_panel<<<dim3(GW, NBATCH), dim3(TPW), 0, stream>>>(Acopy, dA, subA, tauA, Wpan, cbufA, slotA, barA);
  k_bisect<<<dim3(4, NBATCH), dim3(256), 0, stream>>>(dA, subA, eig, e_out);
  k_invit<<<dim3(NOCC2, NBATCH), dim3(64), 0, stream>>>(dA, subA, eig, Utri);
  k_backxform<<<dim3(2, NBATCH), dim3(512), 0, stream>>>(Acopy, tauA, Utri, Uocc);
  k_gemmC<<<dim3(13, NBATCH), dim3(256), 0, stream>>>(hnew, Uocc, Cbuf);
  k_final<<<dim3(NBATCH), dim3(256), 0, stream>>>(eig, Uocc, Cbuf, pos, numbers, E_out);
}